// Round 17
// baseline (302.829 us; speedup 1.0000x reference)
//
#include <hip/hip_runtime.h>
#include <math.h>

#define NHD 8
#define HD 32
#define NREF 30
#define RB 4
#define NWIN 144
#define NTOK 64
#define IMG_H (NWIN*NTOK)        /* 9216  */
#define LN_CNT (IMG_H*NREF)      /* 276480 */
#define SCALE 0.1767766952966369f
#define LN_EPS 1e-5f

typedef __attribute__((ext_vector_type(8))) short bf8_t;   // 8 x bf16
typedef __attribute__((ext_vector_type(4))) float f4_t;    // MFMA acc

__device__ __forceinline__ float gelu_f(float v) {
    return 0.5f * v * (1.0f + erff(v * 0.7071067811865476f));
}

__device__ __forceinline__ short f2bf(float f) {           // fp32 -> bf16 RNE
    union { float f; unsigned u; } v; v.f = f;
    unsigned r = v.u + 0x7fffu + ((v.u >> 16) & 1u);
    return (short)(r >> 16);
}

__device__ __forceinline__ float bf2f(unsigned short u) {
    union { unsigned u; float f; } v; v.u = ((unsigned)u) << 16;
    return v.f;
}

// ---------------- fp32 -> bf16 bulk convert (8 elems/iter) ----------------
__global__ __launch_bounds__(256) void k_cvt(
    const float* __restrict__ src, unsigned short* __restrict__ dst, int n8) {
    const int stride = gridDim.x * blockDim.x;
    for (int i = blockIdx.x * blockDim.x + threadIdx.x; i < n8; i += stride) {
        const float* s = src + (size_t)i * 8;
        float4 a = *reinterpret_cast<const float4*>(s);
        float4 b = *reinterpret_cast<const float4*>(s + 4);
        bf8_t p;
        p[0] = f2bf(a.x); p[1] = f2bf(a.y); p[2] = f2bf(a.z); p[3] = f2bf(a.w);
        p[4] = f2bf(b.x); p[5] = f2bf(b.y); p[6] = f2bf(b.z); p[7] = f2bf(b.w);
        *reinterpret_cast<bf8_t*>(dst + (size_t)i * 8) = p;
    }
}

// ---------------- ref_q / ref_v prep (tiny) ----------------
__global__ __launch_bounds__(256) void k_refprep(
    const float* __restrict__ x_ref, const float* __restrict__ rw,
    const float* __restrict__ rbias, const float* __restrict__ dmu,
    const float* __restrict__ dls, float* __restrict__ ref_q,
    float* __restrict__ ref_v) {
    __shared__ float Wl[60][NREF];
    __shared__ float Bl[60];
    const int rb = blockIdx.x;
    const int t = threadIdx.x;
    for (int i = t; i < 60 * NREF; i += 256) Wl[i / NREF][i % NREF] = rw[i];
    if (t < 60) Bl[t] = rbias[t];
    __syncthreads();
    const int d = t;                       // 0..255
    float xr[NREF];
#pragma unroll
    for (int r = 0; r < NREF; ++r) xr[r] = x_ref[(rb * 256 + d) * NREF + r];
    const int h = d >> 5, hd = d & 31;
    const float mu = dmu[d], sg = expf(dls[d]);
    for (int j = 0; j < 60; ++j) {
        float acc = Bl[j];
#pragma unroll
        for (int r = 0; r < NREF; ++r) acc += xr[r] * Wl[j][r];
        if (j < NREF)
            ref_q[((rb * NHD + h) * NREF + j) * HD + hd] = mu + sg * acc;
        else
            ref_v[((rb * NHD + h) * NREF + (j - NREF)) * HD + hd] = acc;
    }
}

// ---------------- bias+mask table, transposed: bmt[w][h][m][n] ----------------
__global__ __launch_bounds__(256) void k_bm(
    const float* __restrict__ mask, const float* __restrict__ bias_table,
    const int* __restrict__ rel_index, float* __restrict__ bmt) {
    const int wh = blockIdx.x;             // w*8 + h
    const int w = wh >> 3, h = wh & 7;
    for (int u = threadIdx.x; u < 4096; u += 256) {
        const int m = u >> 6, n = u & 63;
        bmt[(size_t)wh * 4096 + u] = mask[(size_t)w * 4096 + n * 64 + m]
                                   + bias_table[rel_index[n * 64 + m] * NHD + h];
    }
}

// ------- qkv GEMM via bf16 MFMA: 128x128 tile, BK=64, 4 waves x (4x4 frags) ---
__global__ __launch_bounds__(256) void k_qkv_mfma(
    const unsigned short* __restrict__ xb, const unsigned short* __restrict__ wb,
    const float* __restrict__ bias, unsigned short* __restrict__ qb,
    unsigned short* __restrict__ kb, unsigned short* __restrict__ vb) {
    __shared__ __align__(16) char As[128 * 128];
    __shared__ __align__(16) char Bs[128 * 128];
    const int t = threadIdx.x;
    const int bid = blockIdx.x;
    const int swz = (bid & 7) * (1728 / 8) + (bid >> 3);
    const int r0 = (swz / 6) * 128;
    const int c0 = (swz % 6) * 128;
    const int wid = t >> 6, l = t & 63;
    const int wr = wid >> 1, wc = wid & 1;
    const int lr = l & 15, lg = l >> 4;
    f4_t acc[4][4] = {};
#pragma unroll 1
    for (int ks = 0; ks < 4; ++ks) {
        const int k0 = ks * 64;
        if (ks) __syncthreads();           // LDS reuse guard
#pragma unroll
        for (int i = 0; i < 4; ++i) {
            const int u = t + 256 * i;
            const int row = u >> 3, c8 = u & 7;
            bf8_t pa = *reinterpret_cast<const bf8_t*>(&xb[(size_t)(r0 + row) * 256 + k0 + c8 * 8]);
            *reinterpret_cast<bf8_t*>(As + row * 128 + ((c8 * 16) ^ ((row & 7) << 4))) = pa;
            bf8_t pb = *reinterpret_cast<const bf8_t*>(&wb[(size_t)(c0 + row) * 256 + k0 + c8 * 8]);
            *reinterpret_cast<bf8_t*>(Bs + row * 128 + ((c8 * 16) ^ ((row & 7) << 4))) = pb;
        }
        __syncthreads();
#pragma unroll
        for (int kk = 0; kk < 2; ++kk) {
            bf8_t a[4], b[4];
#pragma unroll
            for (int mt = 0; mt < 4; ++mt) {
                const int row = wr * 64 + mt * 16 + lr;
                a[mt] = *reinterpret_cast<const bf8_t*>(
                    As + row * 128 + ((kk * 64 + lg * 16) ^ ((row & 7) << 4)));
            }
#pragma unroll
            for (int nt = 0; nt < 4; ++nt) {
                const int row = wc * 64 + nt * 16 + lr;
                b[nt] = *reinterpret_cast<const bf8_t*>(
                    Bs + row * 128 + ((kk * 64 + lg * 16) ^ ((row & 7) << 4)));
            }
#pragma unroll
            for (int mt = 0; mt < 4; ++mt)
#pragma unroll
                for (int nt = 0; nt < 4; ++nt)
                    acc[mt][nt] = __builtin_amdgcn_mfma_f32_16x16x32_bf16(a[mt], b[nt], acc[mt][nt], 0, 0, 0);
        }
    }
#pragma unroll
    for (int nt = 0; nt < 4; ++nt) {
        const int gc = c0 + wc * 64 + nt * 16 + lr;
        const int i3 = gc >> 8, rem = gc & 255;
        const int h = rem >> 5, hd = rem & 31;
        const float bv = bias[gc];
        unsigned short* dst = (i3 == 0) ? qb : (i3 == 1) ? kb : vb;
#pragma unroll
        for (int mt = 0; mt < 4; ++mt)
#pragma unroll
            for (int j = 0; j < 4; ++j) {
                const int gr = r0 + wr * 64 + mt * 16 + lg * 4 + j;
                const int bb = gr >> 6, n = gr & 63;
                dst[(size_t)((bb * NHD + h) * NTOK + n) * HD + hd] =
                    (unsigned short)f2bf(acc[mt][nt][j] + bv);
            }
    }
}

// ------- proj GEMM via bf16 MFMA: 128x128 tile, BK=64 (same structure) --------
__global__ __launch_bounds__(256) void k_proj_mfma(
    const unsigned short* __restrict__ A, const unsigned short* __restrict__ w,
    const float* __restrict__ bias, float* __restrict__ out) {
    __shared__ __align__(16) char As[128 * 128];
    __shared__ __align__(16) char Bs[128 * 128];
    const int t = threadIdx.x;
    const int bid = blockIdx.x;
    const int swz = (bid & 7) * (576 / 8) + (bid >> 3);
    const int r0 = (swz / 2) * 128;
    const int c0 = (swz % 2) * 128;
    const int wid = t >> 6, l = t & 63;
    const int wr = wid >> 1, wc = wid & 1;
    const int lr = l & 15, lg = l >> 4;
    f4_t acc[4][4] = {};
#pragma unroll 1
    for (int ks = 0; ks < 4; ++ks) {
        const int k0 = ks * 64;
        if (ks) __syncthreads();
#pragma unroll
        for (int i = 0; i < 4; ++i) {
            const int u = t + 256 * i;
            const int row = u >> 3, c8 = u & 7;
            bf8_t pa = *reinterpret_cast<const bf8_t*>(&A[(size_t)(r0 + row) * 256 + k0 + c8 * 8]);
            *reinterpret_cast<bf8_t*>(As + row * 128 + ((c8 * 16) ^ ((row & 7) << 4))) = pa;
            bf8_t pb = *reinterpret_cast<const bf8_t*>(&w[(size_t)(c0 + row) * 256 + k0 + c8 * 8]);
            *reinterpret_cast<bf8_t*>(Bs + row * 128 + ((c8 * 16) ^ ((row & 7) << 4))) = pb;
        }
        __syncthreads();
#pragma unroll
        for (int kk = 0; kk < 2; ++kk) {
            bf8_t a[4], b[4];
#pragma unroll
            for (int mt = 0; mt < 4; ++mt) {
                const int row = wr * 64 + mt * 16 + lr;
                a[mt] = *reinterpret_cast<const bf8_t*>(
                    As + row * 128 + ((kk * 64 + lg * 16) ^ ((row & 7) << 4)));
            }
#pragma unroll
            for (int nt = 0; nt < 4; ++nt) {
                const int row = wc * 64 + nt * 16 + lr;
                b[nt] = *reinterpret_cast<const bf8_t*>(
                    Bs + row * 128 + ((kk * 64 + lg * 16) ^ ((row & 7) << 4)));
            }
#pragma unroll
            for (int mt = 0; mt < 4; ++mt)
#pragma unroll
                for (int nt = 0; nt < 4; ++nt)
                    acc[mt][nt] = __builtin_amdgcn_mfma_f32_16x16x32_bf16(a[mt], b[nt], acc[mt][nt], 0, 0, 0);
        }
    }
#pragma unroll
    for (int nt = 0; nt < 4; ++nt) {
        const int gc = c0 + wc * 64 + nt * 16 + lr;
        const float bv = bias[gc];
#pragma unroll
        for (int mt = 0; mt < 4; ++mt)
#pragma unroll
            for (int j = 0; j < 4; ++j) {
                const int gr = r0 + wr * 64 + mt * 16 + lg * 4 + j;
                out[(size_t)gr * 256 + gc] = acc[mt][nt][j] + bv;
            }
    }
}

// -------- ref scores, 4 windows/block: q(bf16) . ref_q -> scores --------------
__global__ __launch_bounds__(256) void k_scores(
    const unsigned short* __restrict__ qbuf, const float* __restrict__ ref_q,
    float* __restrict__ scores) {
    const int bid = blockIdx.x;            // ((rb*8+h)*36 + wg)
    const int wg = bid % 36;
    const int rh = bid / 36;
    const int h = rh % NHD, rb = rh / NHD;
    __shared__ __align__(16) float rs[NREF][32];
    __shared__ float outb[4][64 * NREF];
    const int t = threadIdx.x;
    const int wv = t >> 6, n = t & 63;
    const float* rsrc = &ref_q[(size_t)rh * NREF * HD];
    for (int u = t; u < NREF * 8; u += 256) {
        const int row = u >> 3, c4 = u & 7;
        *reinterpret_cast<float4*>(&rs[row][c4 * 4]) =
            *reinterpret_cast<const float4*>(&rsrc[u * 4]);
    }
    __syncthreads();
    const int w = wg * 4 + wv;
    const unsigned short* qsrc = &qbuf[(size_t)((rb * NWIN + w) * NHD + h) * NTOK * HD + n * 32];
    float q[32];
#pragma unroll
    for (int c8 = 0; c8 < 4; ++c8) {
        bf8_t v = *reinterpret_cast<const bf8_t*>(&qsrc[c8 * 8]);
#pragma unroll
        for (int j = 0; j < 8; ++j)
            q[c8 * 8 + j] = bf2f((unsigned short)v[j]);
    }
    for (int r = 0; r < NREF; ++r) {
        float acc = 0.f;
#pragma unroll
        for (int d = 0; d < 32; ++d) acc += q[d] * rs[r][d];
        outb[wv][n * NREF + r] = acc;
    }
    float* dst = &scores[(size_t)((rb * NHD + h) * IMG_H + w * 64) * NREF];
    for (int u = n; u < 64 * NREF; u += 64) dst[u] = outb[wv][u];
}

// ---------------- conv 3x3 via MFMA (implicit GEMM), 32-row chunks ------------
// 1152 blocks, At[34][32][8] bf16 17.9KB + Dt[8][968] 15.5KB (still 4 blk/CU).
// M = 16 pixels, N = 16 (8 co used), K = 96. A-frag = one ds_read_b128;
// B = 3 preloaded frags. D results go to Dt (LDS planar), then a cooperative
// pass writes each channel's 32x30 chunk (CONTIGUOUS in updOut: row stride 30)
// as coalesced b128 stores -- replaces ~60 fully-scattered u16 stores/wave.
// FUSED: staging applies sc + gelu(LN(upd)), writes scOut for own rows.
template<int FUSED>
__global__ __launch_bounds__(256) void k_conv_mfma(
    const float* __restrict__ scPrev, const unsigned short* __restrict__ updPrev,
    const float* __restrict__ stPrev, const float* __restrict__ conv_w,
    const float* __restrict__ conv_b, float* __restrict__ scOut,
    unsigned short* __restrict__ updOut, float* __restrict__ stats) {
    const int bid = blockIdx.x;            // rb*288 + ychunk
    const int rb = bid / 288;
    const int y0 = (bid % 288) * 32;
    __shared__ __align__(16) unsigned short At[34][32][8];
    __shared__ __align__(16) unsigned short Dt[8][968];   // pad 968: bank-spread
    __shared__ float red[4][8][2];
    __shared__ float lmean[8], lrsig[8];
    const int t = threadIdx.x;
    if (FUSED) {
        if (t < 8) {
            const float s0 = stPrev[(rb * NHD + t) * 2];
            const float s1 = stPrev[(rb * NHD + t) * 2 + 1];
            const float m = s0 * (1.f / LN_CNT);
            const float v = s1 * (1.f / LN_CNT) - m * m;
            lmean[t] = m;
            lrsig[t] = rsqrtf(v + LN_EPS);
        }
        __syncthreads();
    }
    // zero pad columns sx = 0 and 31
    for (int f = t; f < 34 * 2; f += 256) {
        const int yy = f >> 1, side = (f & 1) ? 31 : 0;
        bf8_t z;
#pragma unroll
        for (int j = 0; j < 8; ++j) z[j] = 0;
        *reinterpret_cast<bf8_t*>(&At[yy][side][0]) = z;
    }
    // stage: pixel (yy, xc) -> 8 channel loads -> one b128 write
    for (int ps = t; ps < 34 * 30; ps += 256) {
        const int yy = ps / 30, xc = ps % 30;
        const int y = y0 - 1 + yy;
        bf8_t pk;
#pragma unroll
        for (int j = 0; j < 8; ++j) pk[j] = 0;
        if (y >= 0 && y < IMG_H) {
#pragma unroll
            for (int ci = 0; ci < 8; ++ci) {
                const size_t idx = (size_t)((rb * NHD + ci) * IMG_H + y) * NREF + xc;
                float val;
                if (FUSED) {
                    const float u = bf2f(updPrev[idx]);
                    val = scPrev[idx] + gelu_f((u - lmean[ci]) * lrsig[ci]);
                    if (yy >= 1 && yy <= 32) scOut[idx] = val;
                } else {
                    val = scPrev[idx];
                }
                pk[ci] = f2bf(val);
            }
        }
        *reinterpret_cast<bf8_t*>(&At[yy][xc + 1][0]) = pk;
    }
    // weight B-fragments: lane (lr=co, lg) holds k-slice [tap=kg*4+lg][ci 0..7]
    const int l = t & 63, wv = t >> 6;
    const int lr = l & 15, lg = l >> 4;
    bf8_t wf[3];
#pragma unroll
    for (int kg = 0; kg < 3; ++kg) {
        const int tap = kg * 4 + lg;
        bf8_t wq;
#pragma unroll
        for (int j = 0; j < 8; ++j) wq[j] = 0;
        if (lr < 8 && tap < 9) {
            const int dy = tap / 3, dx = tap % 3;
#pragma unroll
            for (int ci = 0; ci < 8; ++ci)
                wq[ci] = f2bf(conv_w[lr * 72 + ci * 9 + dy * 3 + dx]);
        }
        wf[kg] = wq;
    }
    const float cb = (lr < 8) ? conv_b[lr] : 0.f;
    __syncthreads();
    float ls = 0.f, lss = 0.f;
    // 60 M-tiles of 16 pixels; wave wv owns tiles [wv*15, wv*15+15)
#pragma unroll 3
    for (int ti = 0; ti < 15; ++ti) {
        const int tile = wv * 15 + ti;
        const int pA = tile * 16 + lr;     // A-side pixel for this lane
        const int ylA = pA / 30, xA = pA % 30;
        f4_t o;
        o[0] = cb; o[1] = cb; o[2] = cb; o[3] = cb;
#pragma unroll
        for (int kg = 0; kg < 3; ++kg) {
            const int tap = kg * 4 + lg;
            const int dy = (tap < 9) ? tap / 3 : 0;
            const int dx = (tap < 9) ? tap % 3 : 0;
            bf8_t a = *reinterpret_cast<const bf8_t*>(&At[ylA + dy][xA + dx][0]);
            o = __builtin_amdgcn_mfma_f32_16x16x32_bf16(a, wf[kg], o, 0, 0, 0);
        }
        if (lr < 8) {
#pragma unroll
            for (int j = 0; j < 4; ++j) {
                const int pD = tile * 16 + lg * 4 + j;
                Dt[lr][pD] = (unsigned short)f2bf(o[j]);
                ls += o[j];
                lss += o[j] * o[j];
            }
        }
    }
    ls += __shfl_xor(ls, 16); ls += __shfl_xor(ls, 32);
    lss += __shfl_xor(lss, 16); lss += __shfl_xor(lss, 32);
    if (l < 8) { red[wv][l][0] = ls; red[wv][l][1] = lss; }
    __syncthreads();
    if (t < 8) {
        atomicAdd(&stats[(rb * NHD + t) * 2],
                  red[0][t][0] + red[1][t][0] + red[2][t][0] + red[3][t][0]);
        atomicAdd(&stats[(rb * NHD + t) * 2 + 1],
                  red[0][t][1] + red[1][t][1] + red[2][t][1] + red[3][t][1]);
    }
    // coalesced planar write-out: 960 runs of 8 pixels (chunk is contiguous)
    for (int u = t; u < 960; u += 256) {
        const int co = u / 120, run = u % 120;
        bf8_t d = *reinterpret_cast<const bf8_t*>(&Dt[co][run * 8]);
        *reinterpret_cast<bf8_t*>(
            &updOut[((size_t)(rb * NHD + co) * IMG_H + y0) * NREF + run * 8]) = d;
    }
}

// --- softmax over NREF (fused final LN+gelu+residual), 4 windows/block --------
__global__ __launch_bounds__(256) void k_qnewf(
    const float* __restrict__ scores, const unsigned short* __restrict__ upd,
    const float* __restrict__ st, const float* __restrict__ ref_v,
    unsigned short* __restrict__ qbuf) {
    const int bid = blockIdx.x;            // ((rb*8+h)*36 + wg)
    const int wg = bid % 36;
    const int rh = bid / 36;
    const int h = rh % NHD, rb = rh / NHD;
    __shared__ __align__(16) float rv[NREF][32];
    __shared__ float sl[4][64 * NREF];
    const int t = threadIdx.x;
    const int wv = t >> 6, n = t & 63;
    const float s0 = st[rh * 2], s1 = st[rh * 2 + 1];
    const float mean = s0 * (1.f / LN_CNT);
    const float var = s1 * (1.f / LN_CNT) - mean * mean;
    const float rsig = rsqrtf(var + LN_EPS);
    const float* rvs = &ref_v[(size_t)rh * NREF * HD];
    for (int u = t; u < NREF * 8; u += 256) {
        const int r = u >> 3, c4 = u & 7;
        *reinterpret_cast<float4*>(&rv[r][c4 * 4]) =
            *reinterpret_cast<const float4*>(&rvs[u * 4]);
    }
    const int w = wg * 4 + wv;
    const size_t base = (size_t)((rb * NHD + h) * IMG_H + w * 64) * NREF;
    for (int u = n; u < 64 * NREF; u += 64) {
        const float uv = bf2f(upd[base + u]);
        sl[wv][u] = scores[base + u] + gelu_f((uv - mean) * rsig);
    }
    __syncthreads();
    float p[NREF];
    float mx = -1e30f;
#pragma unroll
    for (int r = 0; r < NREF; ++r) { p[r] = sl[wv][n * NREF + r]; mx = fmaxf(mx, p[r]); }
    float sum = 0.f;
#pragma unroll
    for (int r = 0; r < NREF; ++r) { p[r] = expf(p[r] - mx); sum += p[r]; }
    const float inv = SCALE / sum;
    float acc[32] = {0.f};
#pragma unroll
    for (int r = 0; r < NREF; ++r) {
        const float pr = p[r] * inv;
#pragma unroll
        for (int d = 0; d < 32; ++d) acc[d] += pr * rv[r][d];
    }
    unsigned short* dst = &qbuf[(size_t)((rb * NWIN + w) * NHD + h) * NTOK * HD + n * 32];
#pragma unroll
    for (int c8 = 0; c8 < 4; ++c8) {
        bf8_t pk;
#pragma unroll
        for (int j = 0; j < 8; ++j) pk[j] = f2bf(acc[c8 * 8 + j]);
        *reinterpret_cast<bf8_t*>(&dst[c8 * 8]) = pk;
    }
}

// ---------------- window attention via MFMA, swapped operands ----------------
__global__ __launch_bounds__(256, 4) void k_wattn_mfma(
    const unsigned short* __restrict__ qbuf, const unsigned short* __restrict__ kbuf,
    const unsigned short* __restrict__ vbuf, const float* __restrict__ bmt,
    unsigned short* __restrict__ pre) {
    const int wh = blockIdx.x;             // w*8 + h
    const int w = wh >> 3, h = wh & 7;
    const int t = threadIdx.x;
    const int rb = t >> 6;                 // wave id = rb
    const int l = t & 63;
    const int lr = l & 15, lg = l >> 4;
    const int b = rb * NWIN + w;
    const int bid = b * NHD + h;
    __shared__ __align__(16) char P[4][64 * 128];

    // ---- C init from bmt[w][h][m][n]
    f4_t acc[4][4];
    const float* bm = &bmt[(size_t)wh * 4096];
#pragma unroll
    for (int mt = 0; mt < 4; ++mt)
#pragma unroll
        for (int nt = 0; nt < 4; ++nt)
#pragma unroll
            for (int j = 0; j < 4; ++j)
                acc[mt][nt][j] = bm[(mt * 16 + lg * 4 + j) * 64 + nt * 16 + lr];

    // ---- K frags (A) and Q frags (B): both bf16, 8 contiguous
    const unsigned short* kp = &kbuf[(size_t)bid * 2048];
    const unsigned short* qp = &qbuf[(size_t)bid * 2048];
    bf8_t kf[4], qf[4];
#pragma unroll
    for (int mt = 0; mt < 4; ++mt) {
        kf[mt] = *reinterpret_cast<const bf8_t*>(&kp[(mt * 16 + lr) * 32 + lg * 8]);
        qf[mt] = *reinterpret_cast<const bf8_t*>(&qp[(mt * 16 + lr) * 32 + lg * 8]);
    }
    // ---- S^T[m][n] = sum_k k[m][kk] q[n][kk] + bm
#pragma unroll
    for (int mt = 0; mt < 4; ++mt)
#pragma unroll
        for (int nt = 0; nt < 4; ++nt)
            acc[mt][nt] = __builtin_amdgcn_mfma_f32_16x16x32_bf16(kf[mt], qf[nt], acc[mt][nt], 0, 0, 0);

    // ---- softmax over m (in-lane mt,j + shfl over lg)
#pragma unroll
    for (int nt = 0; nt < 4; ++nt) {
        float mx = -1e30f;
#pragma unroll
        for (int mt = 0; mt < 4; ++mt)
#pragma unroll
            for (int j = 0; j < 4; ++j) mx = fmaxf(mx, acc[mt][nt][j]);
        mx = fmaxf(mx, __shfl_xor(mx, 16));
        mx = fmaxf(mx, __shfl_xor(mx, 32));
        float s = 0.f;
#pragma unroll
        for (int mt = 0; mt < 4; ++mt)
#pragma unroll
            for (int j = 0; j < 4; ++j) {
                const float e = expf(acc[mt][nt][j] - mx);
                acc[mt][nt][j] = e;
                s += e;
            }
        s += __shfl_xor(s, 16);
        s += __shfl_xor(s, 32);
        const float inv = 1.f / s;
#pragma unroll
        for (int mt = 0; mt < 4; ++mt)
#pragma unroll
            for (int j = 0; j < 4; ++j) acc[mt][nt][j] *= inv;
    }

    // ---- pack P[n][m] bf16 into LDS (row 128B, XOR ((n&7)<<4))
    const int n7 = (lr & 7) << 4;
    char* Pw = P[rb];
#pragma unroll
    for (int nt = 0; nt < 4; ++nt) {
        const int rowb = (nt * 16 + lr) * 128;
#pragma unroll
        for (int mt = 0; mt < 4; ++mt)
#pragma unroll
            for (int jp = 0; jp < 2; ++jp) {
                const unsigned lo = (unsigned short)f2bf(acc[mt][nt][jp * 2]);
                const unsigned hi = (unsigned short)f2bf(acc[mt][nt][jp * 2 + 1]);
                const int mb = (mt * 16 + lg * 4 + jp * 2) * 2;
                *reinterpret_cast<unsigned*>(&Pw[rowb + (mb ^ n7)]) = lo | (hi << 16);
            }
    }
    __syncthreads();

    // ---- V^T frags (A): row hd, k = m (gather u16)
    const unsigned short* vp = &vbuf[(size_t)bid * 2048];
    bf8_t vf[2][2];
#pragma unroll
    for (int ht = 0; ht < 2; ++ht)
#pragma unroll
        for (int ks = 0; ks < 2; ++ks) {
            bf8_t tv;
#pragma unroll
            for (int j = 0; j < 8; ++j)
                tv[j] = (short)vp[(ks * 32 + lg * 8 + j) * 32 + ht * 16 + lr];
            vf[ht][ks] = tv;
        }

    // ---- O^T = V^T @ P^T
    f4_t o[2][4] = {};
#pragma unroll
    for (int ks = 0; ks < 2; ++ks)
#pragma unroll
        for (int nt = 0; nt < 4; ++nt) {
            const int rowb = (nt * 16 + lr) * 128;
            bf8_t pf = *reinterpret_cast<const bf8_t*>(&Pw[rowb + ((ks * 64 + lg * 16) ^ n7)]);
#pragma unroll
            for (int ht = 0; ht < 2; ++ht)
                o[ht][nt] = __builtin_amdgcn_mfma_f32_16x16x32_bf16(vf[ht][ks], pf, o[ht][nt], 0, 0, 0);
        }

    // ---- store O^T as bf16: pre[(b*64+n)*256 + h*32 + hd]
#pragma unroll
    for (int ht = 0; ht < 2; ++ht)
#pragma unroll
        for (int nt = 0; nt < 4; ++nt) {
            ushort4 pk;
            pk.x = (unsigned short)f2bf(o[ht][nt][0]);
            pk.y = (unsigned short)f2bf(o[ht][nt][1]);
            pk.z = (unsigned short)f2bf(o[ht][nt][2]);
            pk.w = (unsigned short)f2bf(o[ht][nt][3]);
            const int n = nt * 16 + lr;
            const int hd = ht * 16 + lg * 4;
            *reinterpret_cast<ushort4*>(&pre[(size_t)(b * 64 + n) * 256 + h * 32 + hd]) = pk;
        }
}

extern "C" void kernel_launch(void* const* d_in, const int* in_sizes, int n_in,
                              void* d_out, int out_size, void* d_ws, size_t ws_size,
                              hipStream_t stream) {
    const float* x          = (const float*)d_in[0];
    const float* mask       = (const float*)d_in[1];
    const float* x_ref      = (const float*)d_in[2];
    const float* qkv_w      = (const float*)d_in[3];
    const float* qkv_b      = (const float*)d_in[4];
    const float* proj_w     = (const float*)d_in[5];
    const float* proj_b     = (const float*)d_in[6];
    const float* bias_table = (const float*)d_in[7];
    const float* diff_mu    = (const float*)d_in[8];
    const float* diff_ls    = (const float*)d_in[9];
    const float* ref_qk_w   = (const float*)d_in[10];
    const float* ref_qk_b   = (const float*)d_in[11];
    const float* conv_w     = (const float*)d_in[12];
    const float* conv_b     = (const float*)d_in[13];
    const int*   rel_index  = (const int*)d_in[14];
    float* out = (float*)d_out;

    unsigned short* xb   = (unsigned short*)d_ws;                // 9437184 u16
    unsigned short* qb16 = xb + 9437184;                         // 9437184 u16
    unsigned short* kb16 = qb16 + 9437184;                       // 9437184 u16
    unsigned short* vb16 = kb16 + 9437184;                       // 9437184 u16
    float* scA           = (float*)(vb16 + 9437184);             // 8847360 f
    unsigned short* updA = (unsigned short*)(scA + 8847360);     // 8847360 u16
    unsigned short* updB = updA + 8847360;                       // 8847360 u16
    float* rq            = (float*)(updB + 8847360);             // 30720 f
    float* rv            = rq + 30720;                           // 30720 f
    float* st            = rv + 30720;                           // 192 f (3 x 64)
    float* bmt           = st + 192;                             // 4718592 f
    unsigned short* wqb  = (unsigned short*)(bmt + 4718592);     // 196608 u16
    unsigned short* wpb  = wqb + 196608;                         // 65536 u16
    float* scB           = (float*)d_ws;                         // reuses xb+qb16 (dead during conv)
    unsigned short* pre  = (unsigned short*)scA;                 // alias: scA dead after k_qnewf

    k_cvt<<<2048, 256, 0, stream>>>(x, xb, 9437184 / 8);
    k_cvt<<<96, 256, 0, stream>>>(qkv_w, wqb, 196608 / 8);
    k_cvt<<<32, 256, 0, stream>>>(proj_w, wpb, 65536 / 8);
    k_refprep<<<RB, 256, 0, stream>>>(x_ref, ref_qk_w, ref_qk_b, diff_mu, diff_ls, rq, rv);
    k_bm<<<NWIN * NHD, 256, 0, stream>>>(mask, bias_table, rel_index, bmt);
    k_qkv_mfma<<<1728, 256, 0, stream>>>(xb, wqb, qkv_b, qb16, kb16, vb16);
    k_scores<<<RB * NHD * 36, 256, 0, stream>>>(qb16, rq, scA);
    hipMemsetAsync(st, 0, 192 * sizeof(float), stream);
    k_conv_mfma<0><<<RB * 288, 256, 0, stream>>>(scA, updA, st, conv_w, conv_b, scB, updA, st);
    k_conv_mfma<1><<<RB * 288, 256, 0, stream>>>(scA, updA, st, conv_w, conv_b, scB, updB, st + 64);
    k_conv_mfma<1><<<RB * 288, 256, 0, stream>>>(scB, updB, st + 64, conv_w, conv_b, scA, updA, st + 128);
    k_qnewf<<<RB * NHD * 36, 256, 0, stream>>>(scA, updA, st + 128, rv, qb16);
    k_wattn_mfma<<<NWIN * NHD, 256, 0, stream>>>(qb16, kb16, vb16, bmt, pre);
    k_proj_mfma<<<576, 256, 0, stream>>>(pre, wpb, proj_b, out);
}

// Round 18
// 295.518 us; speedup vs baseline: 1.0247x; 1.0247x over previous
//
#include <hip/hip_runtime.h>
#include <math.h>

#define NHD 8
#define HD 32
#define NREF 30
#define RB 4
#define NWIN 144
#define NTOK 64
#define IMG_H (NWIN*NTOK)        /* 9216  */
#define LN_CNT (IMG_H*NREF)      /* 276480 */
#define SCALE 0.1767766952966369f
#define LN_EPS 1e-5f

typedef __attribute__((ext_vector_type(8))) short bf8_t;   // 8 x bf16
typedef __attribute__((ext_vector_type(4))) float f4_t;    // MFMA acc

__device__ __forceinline__ float gelu_f(float v) {
    return 0.5f * v * (1.0f + erff(v * 0.7071067811865476f));
}

__device__ __forceinline__ short f2bf(float f) {           // fp32 -> bf16 RNE
    union { float f; unsigned u; } v; v.f = f;
    unsigned r = v.u + 0x7fffu + ((v.u >> 16) & 1u);
    return (short)(r >> 16);
}

__device__ __forceinline__ float bf2f(unsigned short u) {
    union { unsigned u; float f; } v; v.u = ((unsigned)u) << 16;
    return v.f;
}

// ---------------- fp32 -> bf16 bulk convert (8 elems/iter) ----------------
__global__ __launch_bounds__(256) void k_cvt(
    const float* __restrict__ src, unsigned short* __restrict__ dst, int n8) {
    const int stride = gridDim.x * blockDim.x;
    for (int i = blockIdx.x * blockDim.x + threadIdx.x; i < n8; i += stride) {
        const float* s = src + (size_t)i * 8;
        float4 a = *reinterpret_cast<const float4*>(s);
        float4 b = *reinterpret_cast<const float4*>(s + 4);
        bf8_t p;
        p[0] = f2bf(a.x); p[1] = f2bf(a.y); p[2] = f2bf(a.z); p[3] = f2bf(a.w);
        p[4] = f2bf(b.x); p[5] = f2bf(b.y); p[6] = f2bf(b.z); p[7] = f2bf(b.w);
        *reinterpret_cast<bf8_t*>(dst + (size_t)i * 8) = p;
    }
}

// ---------------- ref_q / ref_v prep (tiny) ----------------
__global__ __launch_bounds__(256) void k_refprep(
    const float* __restrict__ x_ref, const float* __restrict__ rw,
    const float* __restrict__ rbias, const float* __restrict__ dmu,
    const float* __restrict__ dls, float* __restrict__ ref_q,
    float* __restrict__ ref_v) {
    __shared__ float Wl[60][NREF];
    __shared__ float Bl[60];
    const int rb = blockIdx.x;
    const int t = threadIdx.x;
    for (int i = t; i < 60 * NREF; i += 256) Wl[i / NREF][i % NREF] = rw[i];
    if (t < 60) Bl[t] = rbias[t];
    __syncthreads();
    const int d = t;                       // 0..255
    float xr[NREF];
#pragma unroll
    for (int r = 0; r < NREF; ++r) xr[r] = x_ref[(rb * 256 + d) * NREF + r];
    const int h = d >> 5, hd = d & 31;
    const float mu = dmu[d], sg = expf(dls[d]);
    for (int j = 0; j < 60; ++j) {
        float acc = Bl[j];
#pragma unroll
        for (int r = 0; r < NREF; ++r) acc += xr[r] * Wl[j][r];
        if (j < NREF)
            ref_q[((rb * NHD + h) * NREF + j) * HD + hd] = mu + sg * acc;
        else
            ref_v[((rb * NHD + h) * NREF + (j - NREF)) * HD + hd] = acc;
    }
}

// ---------------- bias+mask table, transposed: bmt[w][h][m][n] ----------------
__global__ __launch_bounds__(256) void k_bm(
    const float* __restrict__ mask, const float* __restrict__ bias_table,
    const int* __restrict__ rel_index, float* __restrict__ bmt) {
    const int wh = blockIdx.x;             // w*8 + h
    const int w = wh >> 3, h = wh & 7;
    for (int u = threadIdx.x; u < 4096; u += 256) {
        const int m = u >> 6, n = u & 63;
        bmt[(size_t)wh * 4096 + u] = mask[(size_t)w * 4096 + n * 64 + m]
                                   + bias_table[rel_index[n * 64 + m] * NHD + h];
    }
}

// ------- qkv GEMM via bf16 MFMA: 128x128 tile, BK=64, 4 waves x (4x4 frags) ---
// A staged directly from fp32 x (inline f2bf in the load phase -> k_cvt(x)
// dispatch and its 36MB HBM round-trip eliminated). B from pre-cvt wqb.
__global__ __launch_bounds__(256) void k_qkv_mfma(
    const float* __restrict__ x, const unsigned short* __restrict__ wb,
    const float* __restrict__ bias, unsigned short* __restrict__ qb,
    unsigned short* __restrict__ kb, unsigned short* __restrict__ vb) {
    __shared__ __align__(16) char As[128 * 128];
    __shared__ __align__(16) char Bs[128 * 128];
    const int t = threadIdx.x;
    const int bid = blockIdx.x;
    const int swz = (bid & 7) * (1728 / 8) + (bid >> 3);
    const int r0 = (swz / 6) * 128;
    const int c0 = (swz % 6) * 128;
    const int wid = t >> 6, l = t & 63;
    const int wr = wid >> 1, wc = wid & 1;
    const int lr = l & 15, lg = l >> 4;
    f4_t acc[4][4] = {};
#pragma unroll 1
    for (int ks = 0; ks < 4; ++ks) {
        const int k0 = ks * 64;
        if (ks) __syncthreads();           // LDS reuse guard
#pragma unroll
        for (int i = 0; i < 4; ++i) {
            const int u = t + 256 * i;
            const int row = u >> 3, c8 = u & 7;
            const float* sa = &x[(size_t)(r0 + row) * 256 + k0 + c8 * 8];
            float4 a0 = *reinterpret_cast<const float4*>(sa);
            float4 a1 = *reinterpret_cast<const float4*>(sa + 4);
            bf8_t pa;
            pa[0] = f2bf(a0.x); pa[1] = f2bf(a0.y); pa[2] = f2bf(a0.z); pa[3] = f2bf(a0.w);
            pa[4] = f2bf(a1.x); pa[5] = f2bf(a1.y); pa[6] = f2bf(a1.z); pa[7] = f2bf(a1.w);
            *reinterpret_cast<bf8_t*>(As + row * 128 + ((c8 * 16) ^ ((row & 7) << 4))) = pa;
            bf8_t pb = *reinterpret_cast<const bf8_t*>(&wb[(size_t)(c0 + row) * 256 + k0 + c8 * 8]);
            *reinterpret_cast<bf8_t*>(Bs + row * 128 + ((c8 * 16) ^ ((row & 7) << 4))) = pb;
        }
        __syncthreads();
#pragma unroll
        for (int kk = 0; kk < 2; ++kk) {
            bf8_t a[4], b[4];
#pragma unroll
            for (int mt = 0; mt < 4; ++mt) {
                const int row = wr * 64 + mt * 16 + lr;
                a[mt] = *reinterpret_cast<const bf8_t*>(
                    As + row * 128 + ((kk * 64 + lg * 16) ^ ((row & 7) << 4)));
            }
#pragma unroll
            for (int nt = 0; nt < 4; ++nt) {
                const int row = wc * 64 + nt * 16 + lr;
                b[nt] = *reinterpret_cast<const bf8_t*>(
                    Bs + row * 128 + ((kk * 64 + lg * 16) ^ ((row & 7) << 4)));
            }
#pragma unroll
            for (int mt = 0; mt < 4; ++mt)
#pragma unroll
                for (int nt = 0; nt < 4; ++nt)
                    acc[mt][nt] = __builtin_amdgcn_mfma_f32_16x16x32_bf16(a[mt], b[nt], acc[mt][nt], 0, 0, 0);
        }
    }
#pragma unroll
    for (int nt = 0; nt < 4; ++nt) {
        const int gc = c0 + wc * 64 + nt * 16 + lr;
        const int i3 = gc >> 8, rem = gc & 255;
        const int h = rem >> 5, hd = rem & 31;
        const float bv = bias[gc];
        unsigned short* dst = (i3 == 0) ? qb : (i3 == 1) ? kb : vb;
#pragma unroll
        for (int mt = 0; mt < 4; ++mt)
#pragma unroll
            for (int j = 0; j < 4; ++j) {
                const int gr = r0 + wr * 64 + mt * 16 + lg * 4 + j;
                const int bb = gr >> 6, n = gr & 63;
                dst[(size_t)((bb * NHD + h) * NTOK + n) * HD + hd] =
                    (unsigned short)f2bf(acc[mt][nt][j] + bv);
            }
    }
}

// ------- proj GEMM via bf16 MFMA: 128x128 tile, BK=64 (same structure) --------
__global__ __launch_bounds__(256) void k_proj_mfma(
    const unsigned short* __restrict__ A, const unsigned short* __restrict__ w,
    const float* __restrict__ bias, float* __restrict__ out) {
    __shared__ __align__(16) char As[128 * 128];
    __shared__ __align__(16) char Bs[128 * 128];
    const int t = threadIdx.x;
    const int bid = blockIdx.x;
    const int swz = (bid & 7) * (576 / 8) + (bid >> 3);
    const int r0 = (swz / 2) * 128;
    const int c0 = (swz % 2) * 128;
    const int wid = t >> 6, l = t & 63;
    const int wr = wid >> 1, wc = wid & 1;
    const int lr = l & 15, lg = l >> 4;
    f4_t acc[4][4] = {};
#pragma unroll 1
    for (int ks = 0; ks < 4; ++ks) {
        const int k0 = ks * 64;
        if (ks) __syncthreads();
#pragma unroll
        for (int i = 0; i < 4; ++i) {
            const int u = t + 256 * i;
            const int row = u >> 3, c8 = u & 7;
            bf8_t pa = *reinterpret_cast<const bf8_t*>(&A[(size_t)(r0 + row) * 256 + k0 + c8 * 8]);
            *reinterpret_cast<bf8_t*>(As + row * 128 + ((c8 * 16) ^ ((row & 7) << 4))) = pa;
            bf8_t pb = *reinterpret_cast<const bf8_t*>(&w[(size_t)(c0 + row) * 256 + k0 + c8 * 8]);
            *reinterpret_cast<bf8_t*>(Bs + row * 128 + ((c8 * 16) ^ ((row & 7) << 4))) = pb;
        }
        __syncthreads();
#pragma unroll
        for (int kk = 0; kk < 2; ++kk) {
            bf8_t a[4], b[4];
#pragma unroll
            for (int mt = 0; mt < 4; ++mt) {
                const int row = wr * 64 + mt * 16 + lr;
                a[mt] = *reinterpret_cast<const bf8_t*>(
                    As + row * 128 + ((kk * 64 + lg * 16) ^ ((row & 7) << 4)));
            }
#pragma unroll
            for (int nt = 0; nt < 4; ++nt) {
                const int row = wc * 64 + nt * 16 + lr;
                b[nt] = *reinterpret_cast<const bf8_t*>(
                    Bs + row * 128 + ((kk * 64 + lg * 16) ^ ((row & 7) << 4)));
            }
#pragma unroll
            for (int mt = 0; mt < 4; ++mt)
#pragma unroll
                for (int nt = 0; nt < 4; ++nt)
                    acc[mt][nt] = __builtin_amdgcn_mfma_f32_16x16x32_bf16(a[mt], b[nt], acc[mt][nt], 0, 0, 0);
        }
    }
#pragma unroll
    for (int nt = 0; nt < 4; ++nt) {
        const int gc = c0 + wc * 64 + nt * 16 + lr;
        const float bv = bias[gc];
#pragma unroll
        for (int mt = 0; mt < 4; ++mt)
#pragma unroll
            for (int j = 0; j < 4; ++j) {
                const int gr = r0 + wr * 64 + mt * 16 + lg * 4 + j;
                out[(size_t)gr * 256 + gc] = acc[mt][nt][j] + bv;
            }
    }
}

// -------- ref scores, 4 windows/block: q(bf16) . ref_q -> scores --------------
__global__ __launch_bounds__(256) void k_scores(
    const unsigned short* __restrict__ qbuf, const float* __restrict__ ref_q,
    float* __restrict__ scores) {
    const int bid = blockIdx.x;            // ((rb*8+h)*36 + wg)
    const int wg = bid % 36;
    const int rh = bid / 36;
    const int h = rh % NHD, rb = rh / NHD;
    __shared__ __align__(16) float rs[NREF][32];
    __shared__ float outb[4][64 * NREF];
    const int t = threadIdx.x;
    const int wv = t >> 6, n = t & 63;
    const float* rsrc = &ref_q[(size_t)rh * NREF * HD];
    for (int u = t; u < NREF * 8; u += 256) {
        const int row = u >> 3, c4 = u & 7;
        *reinterpret_cast<float4*>(&rs[row][c4 * 4]) =
            *reinterpret_cast<const float4*>(&rsrc[u * 4]);
    }
    __syncthreads();
    const int w = wg * 4 + wv;
    const unsigned short* qsrc = &qbuf[(size_t)((rb * NWIN + w) * NHD + h) * NTOK * HD + n * 32];
    float q[32];
#pragma unroll
    for (int c8 = 0; c8 < 4; ++c8) {
        bf8_t v = *reinterpret_cast<const bf8_t*>(&qsrc[c8 * 8]);
#pragma unroll
        for (int j = 0; j < 8; ++j)
            q[c8 * 8 + j] = bf2f((unsigned short)v[j]);
    }
    for (int r = 0; r < NREF; ++r) {
        float acc = 0.f;
#pragma unroll
        for (int d = 0; d < 32; ++d) acc += q[d] * rs[r][d];
        outb[wv][n * NREF + r] = acc;
    }
    float* dst = &scores[(size_t)((rb * NHD + h) * IMG_H + w * 64) * NREF];
    for (int u = n; u < 64 * NREF; u += 64) dst[u] = outb[wv][u];
}

// ---------------- conv 3x3 via MFMA (implicit GEMM), 32-row chunks ------------
// Round-15 known-good config (47.7us): 1152 blocks, At[34][32][8] bf16 17.9KB.
// M = 16 pixels, N = 16 (8 co used), K = 96. A-frag = one ds_read_b128;
// B = 3 preloaded frags. D: col=co, row=pixel (direct scattered u16 stores --
// the round-17 LDS-transpose epilogue REGRESSED via occupancy loss; reverted).
// FUSED: staging applies sc + gelu(LN(upd)), writes scOut for own rows.
template<int FUSED>
__global__ __launch_bounds__(256) void k_conv_mfma(
    const float* __restrict__ scPrev, const unsigned short* __restrict__ updPrev,
    const float* __restrict__ stPrev, const float* __restrict__ conv_w,
    const float* __restrict__ conv_b, float* __restrict__ scOut,
    unsigned short* __restrict__ updOut, float* __restrict__ stats) {
    const int bid = blockIdx.x;            // rb*288 + ychunk
    const int rb = bid / 288;
    const int y0 = (bid % 288) * 32;
    __shared__ __align__(16) unsigned short At[34][32][8];
    __shared__ float red[4][8][2];
    __shared__ float lmean[8], lrsig[8];
    const int t = threadIdx.x;
    if (FUSED) {
        if (t < 8) {
            const float s0 = stPrev[(rb * NHD + t) * 2];
            const float s1 = stPrev[(rb * NHD + t) * 2 + 1];
            const float m = s0 * (1.f / LN_CNT);
            const float v = s1 * (1.f / LN_CNT) - m * m;
            lmean[t] = m;
            lrsig[t] = rsqrtf(v + LN_EPS);
        }
        __syncthreads();
    }
    // zero pad columns sx = 0 and 31
    for (int f = t; f < 34 * 2; f += 256) {
        const int yy = f >> 1, side = (f & 1) ? 31 : 0;
        bf8_t z;
#pragma unroll
        for (int j = 0; j < 8; ++j) z[j] = 0;
        *reinterpret_cast<bf8_t*>(&At[yy][side][0]) = z;
    }
    // stage: pixel (yy, xc) -> 8 channel loads -> one b128 write
    for (int ps = t; ps < 34 * 30; ps += 256) {
        const int yy = ps / 30, xc = ps % 30;
        const int y = y0 - 1 + yy;
        bf8_t pk;
#pragma unroll
        for (int j = 0; j < 8; ++j) pk[j] = 0;
        if (y >= 0 && y < IMG_H) {
#pragma unroll
            for (int ci = 0; ci < 8; ++ci) {
                const size_t idx = (size_t)((rb * NHD + ci) * IMG_H + y) * NREF + xc;
                float val;
                if (FUSED) {
                    const float u = bf2f(updPrev[idx]);
                    val = scPrev[idx] + gelu_f((u - lmean[ci]) * lrsig[ci]);
                    if (yy >= 1 && yy <= 32) scOut[idx] = val;
                } else {
                    val = scPrev[idx];
                }
                pk[ci] = f2bf(val);
            }
        }
        *reinterpret_cast<bf8_t*>(&At[yy][xc + 1][0]) = pk;
    }
    // weight B-fragments: lane (lr=co, lg) holds k-slice [tap=kg*4+lg][ci 0..7]
    const int l = t & 63, wv = t >> 6;
    const int lr = l & 15, lg = l >> 4;
    bf8_t wf[3];
#pragma unroll
    for (int kg = 0; kg < 3; ++kg) {
        const int tap = kg * 4 + lg;
        bf8_t wq;
#pragma unroll
        for (int j = 0; j < 8; ++j) wq[j] = 0;
        if (lr < 8 && tap < 9) {
            const int dy = tap / 3, dx = tap % 3;
#pragma unroll
            for (int ci = 0; ci < 8; ++ci)
                wq[ci] = f2bf(conv_w[lr * 72 + ci * 9 + dy * 3 + dx]);
        }
        wf[kg] = wq;
    }
    const float cb = (lr < 8) ? conv_b[lr] : 0.f;
    __syncthreads();
    float ls = 0.f, lss = 0.f;
    // 60 M-tiles of 16 pixels; wave wv owns tiles [wv*15, wv*15+15)
#pragma unroll 1
    for (int ti = 0; ti < 15; ++ti) {
        const int tile = wv * 15 + ti;
        const int pA = tile * 16 + lr;     // A-side pixel for this lane
        const int ylA = pA / 30, xA = pA % 30;
        f4_t o;
        o[0] = cb; o[1] = cb; o[2] = cb; o[3] = cb;
#pragma unroll
        for (int kg = 0; kg < 3; ++kg) {
            const int tap = kg * 4 + lg;
            const int dy = (tap < 9) ? tap / 3 : 0;
            const int dx = (tap < 9) ? tap % 3 : 0;
            bf8_t a = *reinterpret_cast<const bf8_t*>(&At[ylA + dy][xA + dx][0]);
            o = __builtin_amdgcn_mfma_f32_16x16x32_bf16(a, wf[kg], o, 0, 0, 0);
        }
        if (lr < 8) {
#pragma unroll
            for (int j = 0; j < 4; ++j) {
                const int pD = tile * 16 + lg * 4 + j;
                const int yl = pD / 30, x = pD % 30;
                updOut[(size_t)((rb * NHD + lr) * IMG_H + y0 + yl) * NREF + x] =
                    (unsigned short)f2bf(o[j]);
                ls += o[j];
                lss += o[j] * o[j];
            }
        }
    }
    ls += __shfl_xor(ls, 16); ls += __shfl_xor(ls, 32);
    lss += __shfl_xor(lss, 16); lss += __shfl_xor(lss, 32);
    if (l < 8) { red[wv][l][0] = ls; red[wv][l][1] = lss; }
    __syncthreads();
    if (t < 8) {
        atomicAdd(&stats[(rb * NHD + t) * 2],
                  red[0][t][0] + red[1][t][0] + red[2][t][0] + red[3][t][0]);
        atomicAdd(&stats[(rb * NHD + t) * 2 + 1],
                  red[0][t][1] + red[1][t][1] + red[2][t][1] + red[3][t][1]);
    }
}

// --- softmax over NREF (fused final LN+gelu+residual), 4 windows/block --------
__global__ __launch_bounds__(256) void k_qnewf(
    const float* __restrict__ scores, const unsigned short* __restrict__ upd,
    const float* __restrict__ st, const float* __restrict__ ref_v,
    unsigned short* __restrict__ qbuf) {
    const int bid = blockIdx.x;            // ((rb*8+h)*36 + wg)
    const int wg = bid % 36;
    const int rh = bid / 36;
    const int h = rh % NHD, rb = rh / NHD;
    __shared__ __align__(16) float rv[NREF][32];
    __shared__ float sl[4][64 * NREF];
    const int t = threadIdx.x;
    const int wv = t >> 6, n = t & 63;
    const float s0 = st[rh * 2], s1 = st[rh * 2 + 1];
    const float mean = s0 * (1.f / LN_CNT);
    const float var = s1 * (1.f / LN_CNT) - mean * mean;
    const float rsig = rsqrtf(var + LN_EPS);
    const float* rvs = &ref_v[(size_t)rh * NREF * HD];
    for (int u = t; u < NREF * 8; u += 256) {
        const int r = u >> 3, c4 = u & 7;
        *reinterpret_cast<float4*>(&rv[r][c4 * 4]) =
            *reinterpret_cast<const float4*>(&rvs[u * 4]);
    }
    const int w = wg * 4 + wv;
    const size_t base = (size_t)((rb * NHD + h) * IMG_H + w * 64) * NREF;
    for (int u = n; u < 64 * NREF; u += 64) {
        const float uv = bf2f(upd[base + u]);
        sl[wv][u] = scores[base + u] + gelu_f((uv - mean) * rsig);
    }
    __syncthreads();
    float p[NREF];
    float mx = -1e30f;
#pragma unroll
    for (int r = 0; r < NREF; ++r) { p[r] = sl[wv][n * NREF + r]; mx = fmaxf(mx, p[r]); }
    float sum = 0.f;
#pragma unroll
    for (int r = 0; r < NREF; ++r) { p[r] = expf(p[r] - mx); sum += p[r]; }
    const float inv = SCALE / sum;
    float acc[32] = {0.f};
#pragma unroll
    for (int r = 0; r < NREF; ++r) {
        const float pr = p[r] * inv;
#pragma unroll
        for (int d = 0; d < 32; ++d) acc[d] += pr * rv[r][d];
    }
    unsigned short* dst = &qbuf[(size_t)((rb * NWIN + w) * NHD + h) * NTOK * HD + n * 32];
#pragma unroll
    for (int c8 = 0; c8 < 4; ++c8) {
        bf8_t pk;
#pragma unroll
        for (int j = 0; j < 8; ++j) pk[j] = f2bf(acc[c8 * 8 + j]);
        *reinterpret_cast<bf8_t*>(&dst[c8 * 8]) = pk;
    }
}

// ---------------- window attention via MFMA, swapped operands ----------------
__global__ __launch_bounds__(256, 4) void k_wattn_mfma(
    const unsigned short* __restrict__ qbuf, const unsigned short* __restrict__ kbuf,
    const unsigned short* __restrict__ vbuf, const float* __restrict__ bmt,
    unsigned short* __restrict__ pre) {
    const int wh = blockIdx.x;             // w*8 + h
    const int w = wh >> 3, h = wh & 7;
    const int t = threadIdx.x;
    const int rb = t >> 6;                 // wave id = rb
    const int l = t & 63;
    const int lr = l & 15, lg = l >> 4;
    const int b = rb * NWIN + w;
    const int bid = b * NHD + h;
    __shared__ __align__(16) char P[4][64 * 128];

    // ---- C init from bmt[w][h][m][n]
    f4_t acc[4][4];
    const float* bm = &bmt[(size_t)wh * 4096];
#pragma unroll
    for (int mt = 0; mt < 4; ++mt)
#pragma unroll
        for (int nt = 0; nt < 4; ++nt)
#pragma unroll
            for (int j = 0; j < 4; ++j)
                acc[mt][nt][j] = bm[(mt * 16 + lg * 4 + j) * 64 + nt * 16 + lr];

    // ---- K frags (A) and Q frags (B): both bf16, 8 contiguous
    const unsigned short* kp = &kbuf[(size_t)bid * 2048];
    const unsigned short* qp = &qbuf[(size_t)bid * 2048];
    bf8_t kf[4], qf[4];
#pragma unroll
    for (int mt = 0; mt < 4; ++mt) {
        kf[mt] = *reinterpret_cast<const bf8_t*>(&kp[(mt * 16 + lr) * 32 + lg * 8]);
        qf[mt] = *reinterpret_cast<const bf8_t*>(&qp[(mt * 16 + lr) * 32 + lg * 8]);
    }
    // ---- S^T[m][n] = sum_k k[m][kk] q[n][kk] + bm
#pragma unroll
    for (int mt = 0; mt < 4; ++mt)
#pragma unroll
        for (int nt = 0; nt < 4; ++nt)
            acc[mt][nt] = __builtin_amdgcn_mfma_f32_16x16x32_bf16(kf[mt], qf[nt], acc[mt][nt], 0, 0, 0);

    // ---- softmax over m (in-lane mt,j + shfl over lg)
#pragma unroll
    for (int nt = 0; nt < 4; ++nt) {
        float mx = -1e30f;
#pragma unroll
        for (int mt = 0; mt < 4; ++mt)
#pragma unroll
            for (int j = 0; j < 4; ++j) mx = fmaxf(mx, acc[mt][nt][j]);
        mx = fmaxf(mx, __shfl_xor(mx, 16));
        mx = fmaxf(mx, __shfl_xor(mx, 32));
        float s = 0.f;
#pragma unroll
        for (int mt = 0; mt < 4; ++mt)
#pragma unroll
            for (int j = 0; j < 4; ++j) {
                const float e = expf(acc[mt][nt][j] - mx);
                acc[mt][nt][j] = e;
                s += e;
            }
        s += __shfl_xor(s, 16);
        s += __shfl_xor(s, 32);
        const float inv = 1.f / s;
#pragma unroll
        for (int mt = 0; mt < 4; ++mt)
#pragma unroll
            for (int j = 0; j < 4; ++j) acc[mt][nt][j] *= inv;
    }

    // ---- pack P[n][m] bf16 into LDS (row 128B, XOR ((n&7)<<4))
    const int n7 = (lr & 7) << 4;
    char* Pw = P[rb];
#pragma unroll
    for (int nt = 0; nt < 4; ++nt) {
        const int rowb = (nt * 16 + lr) * 128;
#pragma unroll
        for (int mt = 0; mt < 4; ++mt)
#pragma unroll
            for (int jp = 0; jp < 2; ++jp) {
                const unsigned lo = (unsigned short)f2bf(acc[mt][nt][jp * 2]);
                const unsigned hi = (unsigned short)f2bf(acc[mt][nt][jp * 2 + 1]);
                const int mb = (mt * 16 + lg * 4 + jp * 2) * 2;
                *reinterpret_cast<unsigned*>(&Pw[rowb + (mb ^ n7)]) = lo | (hi << 16);
            }
    }
    __syncthreads();

    // ---- V^T frags (A): row hd, k = m (gather u16)
    const unsigned short* vp = &vbuf[(size_t)bid * 2048];
    bf8_t vf[2][2];
#pragma unroll
    for (int ht = 0; ht < 2; ++ht)
#pragma unroll
        for (int ks = 0; ks < 2; ++ks) {
            bf8_t tv;
#pragma unroll
            for (int j = 0; j < 8; ++j)
                tv[j] = (short)vp[(ks * 32 + lg * 8 + j) * 32 + ht * 16 + lr];
            vf[ht][ks] = tv;
        }

    // ---- O^T = V^T @ P^T
    f4_t o[2][4] = {};
#pragma unroll
    for (int ks = 0; ks < 2; ++ks)
#pragma unroll
        for (int nt = 0; nt < 4; ++nt) {
            const int rowb = (nt * 16 + lr) * 128;
            bf8_t pf = *reinterpret_cast<const bf8_t*>(&Pw[rowb + ((ks * 64 + lg * 16) ^ n7)]);
#pragma unroll
            for (int ht = 0; ht < 2; ++ht)
                o[ht][nt] = __builtin_amdgcn_mfma_f32_16x16x32_bf16(vf[ht][ks], pf, o[ht][nt], 0, 0, 0);
        }

    // ---- store O^T as bf16: pre[(b*64+n)*256 + h*32 + hd]
#pragma unroll
    for (int ht = 0; ht < 2; ++ht)
#pragma unroll
        for (int nt = 0; nt < 4; ++nt) {
            ushort4 pk;
            pk.x = (unsigned short)f2bf(o[ht][nt][0]);
            pk.y = (unsigned short)f2bf(o[ht][nt][1]);
            pk.z = (unsigned short)f2bf(o[ht][nt][2]);
            pk.w = (unsigned short)f2bf(o[ht][nt][3]);
            const int n = nt * 16 + lr;
            const int hd = ht * 16 + lg * 4;
            *reinterpret_cast<ushort4*>(&pre[(size_t)(b * 64 + n) * 256 + h * 32 + hd]) = pk;
        }
}

extern "C" void kernel_launch(void* const* d_in, const int* in_sizes, int n_in,
                              void* d_out, int out_size, void* d_ws, size_t ws_size,
                              hipStream_t stream) {
    const float* x          = (const float*)d_in[0];
    const float* mask       = (const float*)d_in[1];
    const float* x_ref      = (const float*)d_in[2];
    const float* qkv_w      = (const float*)d_in[3];
    const float* qkv_b      = (const float*)d_in[4];
    const float* proj_w     = (const float*)d_in[5];
    const float* proj_b     = (const float*)d_in[6];
    const float* bias_table = (const float*)d_in[7];
    const float* diff_mu    = (const float*)d_in[8];
    const float* diff_ls    = (const float*)d_in[9];
    const float* ref_qk_w   = (const float*)d_in[10];
    const float* ref_qk_b   = (const float*)d_in[11];
    const float* conv_w     = (const float*)d_in[12];
    const float* conv_b     = (const float*)d_in[13];
    const int*   rel_index  = (const int*)d_in[14];
    float* out = (float*)d_out;

    unsigned short* qb16 = (unsigned short*)d_ws;                // 9437184 u16
    unsigned short* kb16 = qb16 + 9437184;                       // 9437184 u16
    unsigned short* vb16 = kb16 + 9437184;                       // 9437184 u16
    float* scA           = (float*)(vb16 + 9437184);             // 8847360 f
    unsigned short* updA = (unsigned short*)(scA + 8847360);     // 8847360 u16
    unsigned short* updB = updA + 8847360;                       // 8847360 u16
    float* rq            = (float*)(updB + 8847360);             // 30720 f
    float* rv            = rq + 30720;                           // 30720 f
    float* st            = rv + 30720;                           // 192 f (3 x 64)
    float* bmt           = st + 192;                             // 4718592 f
    unsigned short* wqb  = (unsigned short*)(bmt + 4718592);     // 196608 u16
    unsigned short* wpb  = wqb + 196608;                         // 65536 u16
    float* scB           = (float*)(wpb + 65536);                // 8847360 f
    unsigned short* pre  = (unsigned short*)scA;                 // alias: scA dead after k_qnewf

    k_cvt<<<96, 256, 0, stream>>>(qkv_w, wqb, 196608 / 8);
    k_cvt<<<32, 256, 0, stream>>>(proj_w, wpb, 65536 / 8);
    k_refprep<<<RB, 256, 0, stream>>>(x_ref, ref_qk_w, ref_qk_b, diff_mu, diff_ls, rq, rv);
    k_bm<<<NWIN * NHD, 256, 0, stream>>>(mask, bias_table, rel_index, bmt);
    k_qkv_mfma<<<1728, 256, 0, stream>>>(x, wqb, qkv_b, qb16, kb16, vb16);
    k_scores<<<RB * NHD * 36, 256, 0, stream>>>(qb16, rq, scA);
    hipMemsetAsync(st, 0, 192 * sizeof(float), stream);
    k_conv_mfma<0><<<RB * 288, 256, 0, stream>>>(scA, updA, st, conv_w, conv_b, scB, updA, st);
    k_conv_mfma<1><<<RB * 288, 256, 0, stream>>>(scA, updA, st, conv_w, conv_b, scB, updB, st + 64);
    k_conv_mfma<1><<<RB * 288, 256, 0, stream>>>(scB, updB, st + 64, conv_w, conv_b, scA, updA, st + 128);
    k_qnewf<<<RB * NHD * 36, 256, 0, stream>>>(scA, updA, st + 128, rv, qb16);
    k_wattn_mfma<<<NWIN * NHD, 256, 0, stream>>>(qb16, kb16, vb16, bmt, pre);
    k_proj_mfma<<<576, 256, 0, stream>>>(pre, wpb, proj_b, out);
}

// Round 19
// 289.750 us; speedup vs baseline: 1.0451x; 1.0199x over previous
//
#include <hip/hip_runtime.h>
#include <math.h>

#define NHD 8
#define HD 32
#define NREF 30
#define RB 4
#define NWIN 144
#define NTOK 64
#define IMG_H (NWIN*NTOK)        /* 9216  */
#define LN_CNT (IMG_H*NREF)      /* 276480 */
#define SCALE 0.1767766952966369f
#define LN_EPS 1e-5f

typedef __attribute__((ext_vector_type(8))) short bf8_t;   // 8 x bf16
typedef __attribute__((ext_vector_type(4))) float f4_t;    // MFMA acc

__device__ __forceinline__ float gelu_f(float v) {
    return 0.5f * v * (1.0f + erff(v * 0.7071067811865476f));
}

__device__ __forceinline__ short f2bf(float f) {           // fp32 -> bf16 RNE
    union { float f; unsigned u; } v; v.f = f;
    unsigned r = v.u + 0x7fffu + ((v.u >> 16) & 1u);
    return (short)(r >> 16);
}

__device__ __forceinline__ float bf2f(unsigned short u) {
    union { unsigned u; float f; } v; v.u = ((unsigned)u) << 16;
    return v.f;
}

// ---------------- fp32 -> bf16 bulk convert (8 elems/iter) ----------------
__global__ __launch_bounds__(256) void k_cvt(
    const float* __restrict__ src, unsigned short* __restrict__ dst, int n8) {
    const int stride = gridDim.x * blockDim.x;
    for (int i = blockIdx.x * blockDim.x + threadIdx.x; i < n8; i += stride) {
        const float* s = src + (size_t)i * 8;
        float4 a = *reinterpret_cast<const float4*>(s);
        float4 b = *reinterpret_cast<const float4*>(s + 4);
        bf8_t p;
        p[0] = f2bf(a.x); p[1] = f2bf(a.y); p[2] = f2bf(a.z); p[3] = f2bf(a.w);
        p[4] = f2bf(b.x); p[5] = f2bf(b.y); p[6] = f2bf(b.z); p[7] = f2bf(b.w);
        *reinterpret_cast<bf8_t*>(dst + (size_t)i * 8) = p;
    }
}

// ---------------- ref_q / ref_v prep (tiny) ----------------
__global__ __launch_bounds__(256) void k_refprep(
    const float* __restrict__ x_ref, const float* __restrict__ rw,
    const float* __restrict__ rbias, const float* __restrict__ dmu,
    const float* __restrict__ dls, float* __restrict__ ref_q,
    float* __restrict__ ref_v) {
    __shared__ float Wl[60][NREF];
    __shared__ float Bl[60];
    const int rb = blockIdx.x;
    const int t = threadIdx.x;
    for (int i = t; i < 60 * NREF; i += 256) Wl[i / NREF][i % NREF] = rw[i];
    if (t < 60) Bl[t] = rbias[t];
    __syncthreads();
    const int d = t;                       // 0..255
    float xr[NREF];
#pragma unroll
    for (int r = 0; r < NREF; ++r) xr[r] = x_ref[(rb * 256 + d) * NREF + r];
    const int h = d >> 5, hd = d & 31;
    const float mu = dmu[d], sg = expf(dls[d]);
    for (int j = 0; j < 60; ++j) {
        float acc = Bl[j];
#pragma unroll
        for (int r = 0; r < NREF; ++r) acc += xr[r] * Wl[j][r];
        if (j < NREF)
            ref_q[((rb * NHD + h) * NREF + j) * HD + hd] = mu + sg * acc;
        else
            ref_v[((rb * NHD + h) * NREF + (j - NREF)) * HD + hd] = acc;
    }
}

// ---------------- bias+mask table, transposed: bmt[w][h][m][n] ----------------
__global__ __launch_bounds__(256) void k_bm(
    const float* __restrict__ mask, const float* __restrict__ bias_table,
    const int* __restrict__ rel_index, float* __restrict__ bmt) {
    const int wh = blockIdx.x;             // w*8 + h
    const int w = wh >> 3, h = wh & 7;
    for (int u = threadIdx.x; u < 4096; u += 256) {
        const int m = u >> 6, n = u & 63;
        bmt[(size_t)wh * 4096 + u] = mask[(size_t)w * 4096 + n * 64 + m]
                                   + bias_table[rel_index[n * 64 + m] * NHD + h];
    }
}

// ------- qkv GEMM via bf16 MFMA: 128x128 tile, BK=64, 4 waves x (4x4 frags) ---
// T14 register prefetch: slab ks+1's A/B panels load right after the staging
// barrier so the 8 global loads overlap the MFMA phase (+32 VGPR).
__global__ __launch_bounds__(256) void k_qkv_mfma(
    const unsigned short* __restrict__ xb, const unsigned short* __restrict__ wb,
    const float* __restrict__ bias, unsigned short* __restrict__ qb,
    unsigned short* __restrict__ kb, unsigned short* __restrict__ vb) {
    __shared__ __align__(16) char As[128 * 128];
    __shared__ __align__(16) char Bs[128 * 128];
    const int t = threadIdx.x;
    const int bid = blockIdx.x;
    const int swz = (bid & 7) * (1728 / 8) + (bid >> 3);
    const int r0 = (swz / 6) * 128;
    const int c0 = (swz % 6) * 128;
    const int wid = t >> 6, l = t & 63;
    const int wr = wid >> 1, wc = wid & 1;
    const int lr = l & 15, lg = l >> 4;
    f4_t acc[4][4] = {};
    bf8_t ra[4], rb_[4];
#pragma unroll
    for (int i = 0; i < 4; ++i) {
        const int u = t + 256 * i;
        const int row = u >> 3, c8 = u & 7;
        ra[i]  = *reinterpret_cast<const bf8_t*>(&xb[(size_t)(r0 + row) * 256 + c8 * 8]);
        rb_[i] = *reinterpret_cast<const bf8_t*>(&wb[(size_t)(c0 + row) * 256 + c8 * 8]);
    }
#pragma unroll 1
    for (int ks = 0; ks < 4; ++ks) {
#pragma unroll
        for (int i = 0; i < 4; ++i) {
            const int u = t + 256 * i;
            const int row = u >> 3, c8 = u & 7;
            *reinterpret_cast<bf8_t*>(As + row * 128 + ((c8 * 16) ^ ((row & 7) << 4))) = ra[i];
            *reinterpret_cast<bf8_t*>(Bs + row * 128 + ((c8 * 16) ^ ((row & 7) << 4))) = rb_[i];
        }
        __syncthreads();
        if (ks < 3) {
            const int k0n = (ks + 1) * 64;
#pragma unroll
            for (int i = 0; i < 4; ++i) {
                const int u = t + 256 * i;
                const int row = u >> 3, c8 = u & 7;
                ra[i]  = *reinterpret_cast<const bf8_t*>(&xb[(size_t)(r0 + row) * 256 + k0n + c8 * 8]);
                rb_[i] = *reinterpret_cast<const bf8_t*>(&wb[(size_t)(c0 + row) * 256 + k0n + c8 * 8]);
            }
        }
#pragma unroll
        for (int kk = 0; kk < 2; ++kk) {
            bf8_t a[4], b[4];
#pragma unroll
            for (int mt = 0; mt < 4; ++mt) {
                const int row = wr * 64 + mt * 16 + lr;
                a[mt] = *reinterpret_cast<const bf8_t*>(
                    As + row * 128 + ((kk * 64 + lg * 16) ^ ((row & 7) << 4)));
            }
#pragma unroll
            for (int nt = 0; nt < 4; ++nt) {
                const int row = wc * 64 + nt * 16 + lr;
                b[nt] = *reinterpret_cast<const bf8_t*>(
                    Bs + row * 128 + ((kk * 64 + lg * 16) ^ ((row & 7) << 4)));
            }
#pragma unroll
            for (int mt = 0; mt < 4; ++mt)
#pragma unroll
                for (int nt = 0; nt < 4; ++nt)
                    acc[mt][nt] = __builtin_amdgcn_mfma_f32_16x16x32_bf16(a[mt], b[nt], acc[mt][nt], 0, 0, 0);
        }
        __syncthreads();                   // reads done before next slab's writes
    }
#pragma unroll
    for (int nt = 0; nt < 4; ++nt) {
        const int gc = c0 + wc * 64 + nt * 16 + lr;
        const int i3 = gc >> 8, rem = gc & 255;
        const int h = rem >> 5, hd = rem & 31;
        const float bv = bias[gc];
        unsigned short* dst = (i3 == 0) ? qb : (i3 == 1) ? kb : vb;
#pragma unroll
        for (int mt = 0; mt < 4; ++mt)
#pragma unroll
            for (int j = 0; j < 4; ++j) {
                const int gr = r0 + wr * 64 + mt * 16 + lg * 4 + j;
                const int bb = gr >> 6, n = gr & 63;
                dst[(size_t)((bb * NHD + h) * NTOK + n) * HD + hd] =
                    (unsigned short)f2bf(acc[mt][nt][j] + bv);
            }
    }
}

// ------- proj GEMM via bf16 MFMA: 128x128 tile, BK=64, T14 prefetch -----------
__global__ __launch_bounds__(256) void k_proj_mfma(
    const unsigned short* __restrict__ A, const unsigned short* __restrict__ w,
    const float* __restrict__ bias, float* __restrict__ out) {
    __shared__ __align__(16) char As[128 * 128];
    __shared__ __align__(16) char Bs[128 * 128];
    const int t = threadIdx.x;
    const int bid = blockIdx.x;
    const int swz = (bid & 7) * (576 / 8) + (bid >> 3);
    const int r0 = (swz / 2) * 128;
    const int c0 = (swz % 2) * 128;
    const int wid = t >> 6, l = t & 63;
    const int wr = wid >> 1, wc = wid & 1;
    const int lr = l & 15, lg = l >> 4;
    f4_t acc[4][4] = {};
    bf8_t ra[4], rb_[4];
#pragma unroll
    for (int i = 0; i < 4; ++i) {
        const int u = t + 256 * i;
        const int row = u >> 3, c8 = u & 7;
        ra[i]  = *reinterpret_cast<const bf8_t*>(&A[(size_t)(r0 + row) * 256 + c8 * 8]);
        rb_[i] = *reinterpret_cast<const bf8_t*>(&w[(size_t)(c0 + row) * 256 + c8 * 8]);
    }
#pragma unroll 1
    for (int ks = 0; ks < 4; ++ks) {
#pragma unroll
        for (int i = 0; i < 4; ++i) {
            const int u = t + 256 * i;
            const int row = u >> 3, c8 = u & 7;
            *reinterpret_cast<bf8_t*>(As + row * 128 + ((c8 * 16) ^ ((row & 7) << 4))) = ra[i];
            *reinterpret_cast<bf8_t*>(Bs + row * 128 + ((c8 * 16) ^ ((row & 7) << 4))) = rb_[i];
        }
        __syncthreads();
        if (ks < 3) {
            const int k0n = (ks + 1) * 64;
#pragma unroll
            for (int i = 0; i < 4; ++i) {
                const int u = t + 256 * i;
                const int row = u >> 3, c8 = u & 7;
                ra[i]  = *reinterpret_cast<const bf8_t*>(&A[(size_t)(r0 + row) * 256 + k0n + c8 * 8]);
                rb_[i] = *reinterpret_cast<const bf8_t*>(&w[(size_t)(c0 + row) * 256 + k0n + c8 * 8]);
            }
        }
#pragma unroll
        for (int kk = 0; kk < 2; ++kk) {
            bf8_t a[4], b[4];
#pragma unroll
            for (int mt = 0; mt < 4; ++mt) {
                const int row = wr * 64 + mt * 16 + lr;
                a[mt] = *reinterpret_cast<const bf8_t*>(
                    As + row * 128 + ((kk * 64 + lg * 16) ^ ((row & 7) << 4)));
            }
#pragma unroll
            for (int nt = 0; nt < 4; ++nt) {
                const int row = wc * 64 + nt * 16 + lr;
                b[nt] = *reinterpret_cast<const bf8_t*>(
                    Bs + row * 128 + ((kk * 64 + lg * 16) ^ ((row & 7) << 4)));
            }
#pragma unroll
            for (int mt = 0; mt < 4; ++mt)
#pragma unroll
                for (int nt = 0; nt < 4; ++nt)
                    acc[mt][nt] = __builtin_amdgcn_mfma_f32_16x16x32_bf16(a[mt], b[nt], acc[mt][nt], 0, 0, 0);
        }
        __syncthreads();
    }
#pragma unroll
    for (int nt = 0; nt < 4; ++nt) {
        const int gc = c0 + wc * 64 + nt * 16 + lr;
        const float bv = bias[gc];
#pragma unroll
        for (int mt = 0; mt < 4; ++mt)
#pragma unroll
            for (int j = 0; j < 4; ++j) {
                const int gr = r0 + wr * 64 + mt * 16 + lg * 4 + j;
                out[(size_t)gr * 256 + gc] = acc[mt][nt][j] + bv;
            }
    }
}

// -------- ref scores, 4 windows/block: q(bf16) . ref_q -> scores --------------
__global__ __launch_bounds__(256) void k_scores(
    const unsigned short* __restrict__ qbuf, const float* __restrict__ ref_q,
    float* __restrict__ scores) {
    const int bid = blockIdx.x;            // ((rb*8+h)*36 + wg)
    const int wg = bid % 36;
    const int rh = bid / 36;
    const int h = rh % NHD, rb = rh / NHD;
    __shared__ __align__(16) float rs[NREF][32];
    __shared__ float outb[4][64 * NREF];
    const int t = threadIdx.x;
    const int wv = t >> 6, n = t & 63;
    const float* rsrc = &ref_q[(size_t)rh * NREF * HD];
    for (int u = t; u < NREF * 8; u += 256) {
        const int row = u >> 3, c4 = u & 7;
        *reinterpret_cast<float4*>(&rs[row][c4 * 4]) =
            *reinterpret_cast<const float4*>(&rsrc[u * 4]);
    }
    __syncthreads();
    const int w = wg * 4 + wv;
    const unsigned short* qsrc = &qbuf[(size_t)((rb * NWIN + w) * NHD + h) * NTOK * HD + n * 32];
    float q[32];
#pragma unroll
    for (int c8 = 0; c8 < 4; ++c8) {
        bf8_t v = *reinterpret_cast<const bf8_t*>(&qsrc[c8 * 8]);
#pragma unroll
        for (int j = 0; j < 8; ++j)
            q[c8 * 8 + j] = bf2f((unsigned short)v[j]);
    }
    for (int r = 0; r < NREF; ++r) {
        float acc = 0.f;
#pragma unroll
        for (int d = 0; d < 32; ++d) acc += q[d] * rs[r][d];
        outb[wv][n * NREF + r] = acc;
    }
    float* dst = &scores[(size_t)((rb * NHD + h) * IMG_H + w * 64) * NREF];
    for (int u = n; u < 64 * NREF; u += 64) dst[u] = outb[wv][u];
}

// ---------------- conv 3x3 via MFMA (implicit GEMM), 32-row chunks ------------
// Round-15 known-good config (47.7us): 1152 blocks, At[34][32][8] bf16 17.9KB.
// M = 16 pixels, N = 16 (8 co used), K = 96. A-frag = one ds_read_b128;
// B = 3 preloaded frags. D: col=co, row=pixel (direct scattered u16 stores).
// FUSED: staging applies sc + gelu(LN(upd)), writes scOut for own rows.
template<int FUSED>
__global__ __launch_bounds__(256) void k_conv_mfma(
    const float* __restrict__ scPrev, const unsigned short* __restrict__ updPrev,
    const float* __restrict__ stPrev, const float* __restrict__ conv_w,
    const float* __restrict__ conv_b, float* __restrict__ scOut,
    unsigned short* __restrict__ updOut, float* __restrict__ stats) {
    const int bid = blockIdx.x;            // rb*288 + ychunk
    const int rb = bid / 288;
    const int y0 = (bid % 288) * 32;
    __shared__ __align__(16) unsigned short At[34][32][8];
    __shared__ float red[4][8][2];
    __shared__ float lmean[8], lrsig[8];
    const int t = threadIdx.x;
    if (FUSED) {
        if (t < 8) {
            const float s0 = stPrev[(rb * NHD + t) * 2];
            const float s1 = stPrev[(rb * NHD + t) * 2 + 1];
            const float m = s0 * (1.f / LN_CNT);
            const float v = s1 * (1.f / LN_CNT) - m * m;
            lmean[t] = m;
            lrsig[t] = rsqrtf(v + LN_EPS);
        }
        __syncthreads();
    }
    // zero pad columns sx = 0 and 31
    for (int f = t; f < 34 * 2; f += 256) {
        const int yy = f >> 1, side = (f & 1) ? 31 : 0;
        bf8_t z;
#pragma unroll
        for (int j = 0; j < 8; ++j) z[j] = 0;
        *reinterpret_cast<bf8_t*>(&At[yy][side][0]) = z;
    }
    // stage: pixel (yy, xc) -> 8 channel loads -> one b128 write
    for (int ps = t; ps < 34 * 30; ps += 256) {
        const int yy = ps / 30, xc = ps % 30;
        const int y = y0 - 1 + yy;
        bf8_t pk;
#pragma unroll
        for (int j = 0; j < 8; ++j) pk[j] = 0;
        if (y >= 0 && y < IMG_H) {
#pragma unroll
            for (int ci = 0; ci < 8; ++ci) {
                const size_t idx = (size_t)((rb * NHD + ci) * IMG_H + y) * NREF + xc;
                float val;
                if (FUSED) {
                    const float u = bf2f(updPrev[idx]);
                    val = scPrev[idx] + gelu_f((u - lmean[ci]) * lrsig[ci]);
                    if (yy >= 1 && yy <= 32) scOut[idx] = val;
                } else {
                    val = scPrev[idx];
                }
                pk[ci] = f2bf(val);
            }
        }
        *reinterpret_cast<bf8_t*>(&At[yy][xc + 1][0]) = pk;
    }
    // weight B-fragments: lane (lr=co, lg) holds k-slice [tap=kg*4+lg][ci 0..7]
    const int l = t & 63, wv = t >> 6;
    const int lr = l & 15, lg = l >> 4;
    bf8_t wf[3];
#pragma unroll
    for (int kg = 0; kg < 3; ++kg) {
        const int tap = kg * 4 + lg;
        bf8_t wq;
#pragma unroll
        for (int j = 0; j < 8; ++j) wq[j] = 0;
        if (lr < 8 && tap < 9) {
            const int dy = tap / 3, dx = tap % 3;
#pragma unroll
            for (int ci = 0; ci < 8; ++ci)
                wq[ci] = f2bf(conv_w[lr * 72 + ci * 9 + dy * 3 + dx]);
        }
        wf[kg] = wq;
    }
    const float cb = (lr < 8) ? conv_b[lr] : 0.f;
    __syncthreads();
    float ls = 0.f, lss = 0.f;
    // 60 M-tiles of 16 pixels; wave wv owns tiles [wv*15, wv*15+15)
#pragma unroll 1
    for (int ti = 0; ti < 15; ++ti) {
        const int tile = wv * 15 + ti;
        const int pA = tile * 16 + lr;     // A-side pixel for this lane
        const int ylA = pA / 30, xA = pA % 30;
        f4_t o;
        o[0] = cb; o[1] = cb; o[2] = cb; o[3] = cb;
#pragma unroll
        for (int kg = 0; kg < 3; ++kg) {
            const int tap = kg * 4 + lg;
            const int dy = (tap < 9) ? tap / 3 : 0;
            const int dx = (tap < 9) ? tap % 3 : 0;
            bf8_t a = *reinterpret_cast<const bf8_t*>(&At[ylA + dy][xA + dx][0]);
            o = __builtin_amdgcn_mfma_f32_16x16x32_bf16(a, wf[kg], o, 0, 0, 0);
        }
        if (lr < 8) {
#pragma unroll
            for (int j = 0; j < 4; ++j) {
                const int pD = tile * 16 + lg * 4 + j;
                const int yl = pD / 30, x = pD % 30;
                updOut[(size_t)((rb * NHD + lr) * IMG_H + y0 + yl) * NREF + x] =
                    (unsigned short)f2bf(o[j]);
                ls += o[j];
                lss += o[j] * o[j];
            }
        }
    }
    ls += __shfl_xor(ls, 16); ls += __shfl_xor(ls, 32);
    lss += __shfl_xor(lss, 16); lss += __shfl_xor(lss, 32);
    if (l < 8) { red[wv][l][0] = ls; red[wv][l][1] = lss; }
    __syncthreads();
    if (t < 8) {
        atomicAdd(&stats[(rb * NHD + t) * 2],
                  red[0][t][0] + red[1][t][0] + red[2][t][0] + red[3][t][0]);
        atomicAdd(&stats[(rb * NHD + t) * 2 + 1],
                  red[0][t][1] + red[1][t][1] + red[2][t][1] + red[3][t][1]);
    }
}

// --- softmax over NREF (fused final LN+gelu+residual), 4 windows/block --------
__global__ __launch_bounds__(256) void k_qnewf(
    const float* __restrict__ scores, const unsigned short* __restrict__ upd,
    const float* __restrict__ st, const float* __restrict__ ref_v,
    unsigned short* __restrict__ qbuf) {
    const int bid = blockIdx.x;            // ((rb*8+h)*36 + wg)
    const int wg = bid % 36;
    const int rh = bid / 36;
    const int h = rh % NHD, rb = rh / NHD;
    __shared__ __align__(16) float rv[NREF][32];
    __shared__ float sl[4][64 * NREF];
    const int t = threadIdx.x;
    const int wv = t >> 6, n = t & 63;
    const float s0 = st[rh * 2], s1 = st[rh * 2 + 1];
    const float mean = s0 * (1.f / LN_CNT);
    const float var = s1 * (1.f / LN_CNT) - mean * mean;
    const float rsig = rsqrtf(var + LN_EPS);
    const float* rvs = &ref_v[(size_t)rh * NREF * HD];
    for (int u = t; u < NREF * 8; u += 256) {
        const int r = u >> 3, c4 = u & 7;
        *reinterpret_cast<float4*>(&rv[r][c4 * 4]) =
            *reinterpret_cast<const float4*>(&rvs[u * 4]);
    }
    const int w = wg * 4 + wv;
    const size_t base = (size_t)((rb * NHD + h) * IMG_H + w * 64) * NREF;
    for (int u = n; u < 64 * NREF; u += 64) {
        const float uv = bf2f(upd[base + u]);
        sl[wv][u] = scores[base + u] + gelu_f((uv - mean) * rsig);
    }
    __syncthreads();
    float p[NREF];
    float mx = -1e30f;
#pragma unroll
    for (int r = 0; r < NREF; ++r) { p[r] = sl[wv][n * NREF + r]; mx = fmaxf(mx, p[r]); }
    float sum = 0.f;
#pragma unroll
    for (int r = 0; r < NREF; ++r) { p[r] = expf(p[r] - mx); sum += p[r]; }
    const float inv = SCALE / sum;
    float acc[32] = {0.f};
#pragma unroll
    for (int r = 0; r < NREF; ++r) {
        const float pr = p[r] * inv;
#pragma unroll
        for (int d = 0; d < 32; ++d) acc[d] += pr * rv[r][d];
    }
    unsigned short* dst = &qbuf[(size_t)((rb * NWIN + w) * NHD + h) * NTOK * HD + n * 32];
#pragma unroll
    for (int c8 = 0; c8 < 4; ++c8) {
        bf8_t pk;
#pragma unroll
        for (int j = 0; j < 8; ++j) pk[j] = f2bf(acc[c8 * 8 + j]);
        *reinterpret_cast<bf8_t*>(&dst[c8 * 8]) = pk;
    }
}

// ---------------- window attention via MFMA, swapped operands ----------------
__global__ __launch_bounds__(256, 4) void k_wattn_mfma(
    const unsigned short* __restrict__ qbuf, const unsigned short* __restrict__ kbuf,
    const unsigned short* __restrict__ vbuf, const float* __restrict__ bmt,
    unsigned short* __restrict__ pre) {
    const int wh = blockIdx.x;             // w*8 + h
    const int w = wh >> 3, h = wh & 7;
    const int t = threadIdx.x;
    const int rb = t >> 6;                 // wave id = rb
    const int l = t & 63;
    const int lr = l & 15, lg = l >> 4;
    const int b = rb * NWIN + w;
    const int bid = b * NHD + h;
    __shared__ __align__(16) char P[4][64 * 128];

    // ---- C init from bmt[w][h][m][n]
    f4_t acc[4][4];
    const float* bm = &bmt[(size_t)wh * 4096];
#pragma unroll
    for (int mt = 0; mt < 4; ++mt)
#pragma unroll
        for (int nt = 0; nt < 4; ++nt)
#pragma unroll
            for (int j = 0; j < 4; ++j)
                acc[mt][nt][j] = bm[(mt * 16 + lg * 4 + j) * 64 + nt * 16 + lr];

    // ---- K frags (A) and Q frags (B): both bf16, 8 contiguous
    const unsigned short* kp = &kbuf[(size_t)bid * 2048];
    const unsigned short* qp = &qbuf[(size_t)bid * 2048];
    bf8_t kf[4], qf[4];
#pragma unroll
    for (int mt = 0; mt < 4; ++mt) {
        kf[mt] = *reinterpret_cast<const bf8_t*>(&kp[(mt * 16 + lr) * 32 + lg * 8]);
        qf[mt] = *reinterpret_cast<const bf8_t*>(&qp[(mt * 16 + lr) * 32 + lg * 8]);
    }
    // ---- S^T[m][n] = sum_k k[m][kk] q[n][kk] + bm
#pragma unroll
    for (int mt = 0; mt < 4; ++mt)
#pragma unroll
        for (int nt = 0; nt < 4; ++nt)
            acc[mt][nt] = __builtin_amdgcn_mfma_f32_16x16x32_bf16(kf[mt], qf[nt], acc[mt][nt], 0, 0, 0);

    // ---- softmax over m (in-lane mt,j + shfl over lg)
#pragma unroll
    for (int nt = 0; nt < 4; ++nt) {
        float mx = -1e30f;
#pragma unroll
        for (int mt = 0; mt < 4; ++mt)
#pragma unroll
            for (int j = 0; j < 4; ++j) mx = fmaxf(mx, acc[mt][nt][j]);
        mx = fmaxf(mx, __shfl_xor(mx, 16));
        mx = fmaxf(mx, __shfl_xor(mx, 32));
        float s = 0.f;
#pragma unroll
        for (int mt = 0; mt < 4; ++mt)
#pragma unroll
            for (int j = 0; j < 4; ++j) {
                const float e = expf(acc[mt][nt][j] - mx);
                acc[mt][nt][j] = e;
                s += e;
            }
        s += __shfl_xor(s, 16);
        s += __shfl_xor(s, 32);
        const float inv = 1.f / s;
#pragma unroll
        for (int mt = 0; mt < 4; ++mt)
#pragma unroll
            for (int j = 0; j < 4; ++j) acc[mt][nt][j] *= inv;
    }

    // ---- pack P[n][m] bf16 into LDS (row 128B, XOR ((n&7)<<4))
    const int n7 = (lr & 7) << 4;
    char* Pw = P[rb];
#pragma unroll
    for (int nt = 0; nt < 4; ++nt) {
        const int rowb = (nt * 16 + lr) * 128;
#pragma unroll
        for (int mt = 0; mt < 4; ++mt)
#pragma unroll
            for (int jp = 0; jp < 2; ++jp) {
                const unsigned lo = (unsigned short)f2bf(acc[mt][nt][jp * 2]);
                const unsigned hi = (unsigned short)f2bf(acc[mt][nt][jp * 2 + 1]);
                const int mb = (mt * 16 + lg * 4 + jp * 2) * 2;
                *reinterpret_cast<unsigned*>(&Pw[rowb + (mb ^ n7)]) = lo | (hi << 16);
            }
    }
    __syncthreads();

    // ---- V^T frags (A): row hd, k = m (gather u16)
    const unsigned short* vp = &vbuf[(size_t)bid * 2048];
    bf8_t vf[2][2];
#pragma unroll
    for (int ht = 0; ht < 2; ++ht)
#pragma unroll
        for (int ks = 0; ks < 2; ++ks) {
            bf8_t tv;
#pragma unroll
            for (int j = 0; j < 8; ++j)
                tv[j] = (short)vp[(ks * 32 + lg * 8 + j) * 32 + ht * 16 + lr];
            vf[ht][ks] = tv;
        }

    // ---- O^T = V^T @ P^T
    f4_t o[2][4] = {};
#pragma unroll
    for (int ks = 0; ks < 2; ++ks)
#pragma unroll
        for (int nt = 0; nt < 4; ++nt) {
            const int rowb = (nt * 16 + lr) * 128;
            bf8_t pf = *reinterpret_cast<const bf8_t*>(&Pw[rowb + ((ks * 64 + lg * 16) ^ n7)]);
#pragma unroll
            for (int ht = 0; ht < 2; ++ht)
                o[ht][nt] = __builtin_amdgcn_mfma_f32_16x16x32_bf16(vf[ht][ks], pf, o[ht][nt], 0, 0, 0);
        }

    // ---- store O^T as bf16: pre[(b*64+n)*256 + h*32 + hd]
#pragma unroll
    for (int ht = 0; ht < 2; ++ht)
#pragma unroll
        for (int nt = 0; nt < 4; ++nt) {
            ushort4 pk;
            pk.x = (unsigned short)f2bf(o[ht][nt][0]);
            pk.y = (unsigned short)f2bf(o[ht][nt][1]);
            pk.z = (unsigned short)f2bf(o[ht][nt][2]);
            pk.w = (unsigned short)f2bf(o[ht][nt][3]);
            const int n = nt * 16 + lr;
            const int hd = ht * 16 + lg * 4;
            *reinterpret_cast<ushort4*>(&pre[(size_t)(b * 64 + n) * 256 + h * 32 + hd]) = pk;
        }
}

extern "C" void kernel_launch(void* const* d_in, const int* in_sizes, int n_in,
                              void* d_out, int out_size, void* d_ws, size_t ws_size,
                              hipStream_t stream) {
    const float* x          = (const float*)d_in[0];
    const float* mask       = (const float*)d_in[1];
    const float* x_ref      = (const float*)d_in[2];
    const float* qkv_w      = (const float*)d_in[3];
    const float* qkv_b      = (const float*)d_in[4];
    const float* proj_w     = (const float*)d_in[5];
    const float* proj_b     = (const float*)d_in[6];
    const float* bias_table = (const float*)d_in[7];
    const float* diff_mu    = (const float*)d_in[8];
    const float* diff_ls    = (const float*)d_in[9];
    const float* ref_qk_w   = (const float*)d_in[10];
    const float* ref_qk_b   = (const float*)d_in[11];
    const float* conv_w     = (const float*)d_in[12];
    const float* conv_b     = (const float*)d_in[13];
    const int*   rel_index  = (const int*)d_in[14];
    float* out = (float*)d_out;

    unsigned short* xb   = (unsigned short*)d_ws;                // 9437184 u16
    unsigned short* qb16 = xb + 9437184;                         // 9437184 u16
    unsigned short* kb16 = qb16 + 9437184;                       // 9437184 u16
    unsigned short* vb16 = kb16 + 9437184;                       // 9437184 u16
    float* scA           = (float*)(vb16 + 9437184);             // 8847360 f
    unsigned short* updA = (unsigned short*)(scA + 8847360);     // 8847360 u16
    unsigned short* updB = updA + 8847360;                       // 8847360 u16
    float* rq            = (float*)(updB + 8847360);             // 30720 f
    float* rv            = rq + 30720;                           // 30720 f
    float* st            = rv + 30720;                           // 192 f (3 x 64)
    float* bmt           = st + 192;                             // 4718592 f
    unsigned short* wqb  = (unsigned short*)(bmt + 4718592);     // 196608 u16
    unsigned short* wpb  = wqb + 196608;                         // 65536 u16
    float* scB           = (float*)d_ws;                         // reuses xb+qb16 (dead during conv)
    unsigned short* pre  = (unsigned short*)scA;                 // alias: scA dead after k_qnewf

    k_cvt<<<2048, 256, 0, stream>>>(x, xb, 9437184 / 8);
    k_cvt<<<96, 256, 0, stream>>>(qkv_w, wqb, 196608 / 8);
    k_cvt<<<32, 256, 0, stream>>>(proj_w, wpb, 65536 / 8);
    k_refprep<<<RB, 256, 0, stream>>>(x_ref, ref_qk_w, ref_qk_b, diff_mu, diff_ls, rq, rv);
    k_bm<<<NWIN * NHD, 256, 0, stream>>>(mask, bias_table, rel_index, bmt);
    k_qkv_mfma<<<1728, 256, 0, stream>>>(xb, wqb, qkv_b, qb16, kb16, vb16);
    k_scores<<<RB * NHD * 36, 256, 0, stream>>>(qb16, rq, scA);
    hipMemsetAsync(st, 0, 192 * sizeof(float), stream);
    k_conv_mfma<0><<<RB * 288, 256, 0, stream>>>(scA, updA, st, conv_w, conv_b, scB, updA, st);
    k_conv_mfma<1><<<RB * 288, 256, 0, stream>>>(scA, updA, st, conv_w, conv_b, scB, updB, st + 64);
    k_conv_mfma<1><<<RB * 288, 256, 0, stream>>>(scB, updB, st + 64, conv_w, conv_b, scA, updA, st + 128);
    k_qnewf<<<RB * NHD * 36, 256, 0, stream>>>(scA, updA, st + 128, rv, qb16);
    k_wattn_mfma<<<NWIN * NHD, 256, 0, stream>>>(qb16, kb16, vb16, bmt, pre);
    k_proj_mfma<<<576, 256, 0, stream>>>(pre, wpb, proj_b, out);
}

// Round 20
// 289.061 us; speedup vs baseline: 1.0476x; 1.0024x over previous
//
#include <hip/hip_runtime.h>
#include <math.h>

#define NHD 8
#define HD 32
#define NREF 30
#define RB 4
#define NWIN 144
#define NTOK 64
#define IMG_H (NWIN*NTOK)        /* 9216  */
#define LN_CNT (IMG_H*NREF)      /* 276480 */
#define SCALE 0.1767766952966369f
#define LN_EPS 1e-5f

typedef __attribute__((ext_vector_type(8))) short bf8_t;   // 8 x bf16
typedef __attribute__((ext_vector_type(4))) float f4_t;    // MFMA acc

__device__ __forceinline__ float gelu_f(float v) {
    return 0.5f * v * (1.0f + erff(v * 0.7071067811865476f));
}

__device__ __forceinline__ short f2bf(float f) {           // fp32 -> bf16 RNE
    union { float f; unsigned u; } v; v.f = f;
    unsigned r = v.u + 0x7fffu + ((v.u >> 16) & 1u);
    return (short)(r >> 16);
}

__device__ __forceinline__ float bf2f(unsigned short u) {
    union { unsigned u; float f; } v; v.u = ((unsigned)u) << 16;
    return v.f;
}

// ---------------- fp32 -> bf16 bulk convert (8 elems/iter) ----------------
__global__ __launch_bounds__(256) void k_cvt(
    const float* __restrict__ src, unsigned short* __restrict__ dst, int n8) {
    const int stride = gridDim.x * blockDim.x;
    for (int i = blockIdx.x * blockDim.x + threadIdx.x; i < n8; i += stride) {
        const float* s = src + (size_t)i * 8;
        float4 a = *reinterpret_cast<const float4*>(s);
        float4 b = *reinterpret_cast<const float4*>(s + 4);
        bf8_t p;
        p[0] = f2bf(a.x); p[1] = f2bf(a.y); p[2] = f2bf(a.z); p[3] = f2bf(a.w);
        p[4] = f2bf(b.x); p[5] = f2bf(b.y); p[6] = f2bf(b.z); p[7] = f2bf(b.w);
        *reinterpret_cast<bf8_t*>(dst + (size_t)i * 8) = p;
    }
}

// ---------------- ref_q / ref_v prep (tiny) ----------------
__global__ __launch_bounds__(256) void k_refprep(
    const float* __restrict__ x_ref, const float* __restrict__ rw,
    const float* __restrict__ rbias, const float* __restrict__ dmu,
    const float* __restrict__ dls, float* __restrict__ ref_q,
    float* __restrict__ ref_v) {
    __shared__ float Wl[60][NREF];
    __shared__ float Bl[60];
    const int rb = blockIdx.x;
    const int t = threadIdx.x;
    for (int i = t; i < 60 * NREF; i += 256) Wl[i / NREF][i % NREF] = rw[i];
    if (t < 60) Bl[t] = rbias[t];
    __syncthreads();
    const int d = t;                       // 0..255
    float xr[NREF];
#pragma unroll
    for (int r = 0; r < NREF; ++r) xr[r] = x_ref[(rb * 256 + d) * NREF + r];
    const int h = d >> 5, hd = d & 31;
    const float mu = dmu[d], sg = expf(dls[d]);
    for (int j = 0; j < 60; ++j) {
        float acc = Bl[j];
#pragma unroll
        for (int r = 0; r < NREF; ++r) acc += xr[r] * Wl[j][r];
        if (j < NREF)
            ref_q[((rb * NHD + h) * NREF + j) * HD + hd] = mu + sg * acc;
        else
            ref_v[((rb * NHD + h) * NREF + (j - NREF)) * HD + hd] = acc;
    }
}

// ---------------- bias+mask table, transposed: bmt[w][h][m][n] ----------------
__global__ __launch_bounds__(256) void k_bm(
    const float* __restrict__ mask, const float* __restrict__ bias_table,
    const int* __restrict__ rel_index, float* __restrict__ bmt) {
    const int wh = blockIdx.x;             // w*8 + h
    const int w = wh >> 3, h = wh & 7;
    for (int u = threadIdx.x; u < 4096; u += 256) {
        const int m = u >> 6, n = u & 63;
        bmt[(size_t)wh * 4096 + u] = mask[(size_t)w * 4096 + n * 64 + m]
                                   + bias_table[rel_index[n * 64 + m] * NHD + h];
    }
}

// ------- qkv GEMM via bf16 MFMA: 128x128 tile, BK=64, 4 waves x (4x4 frags) ---
// T14 register prefetch: slab ks+1's A/B panels load right after the staging
// barrier so the 8 global loads overlap the MFMA phase (+32 VGPR).
__global__ __launch_bounds__(256) void k_qkv_mfma(
    const unsigned short* __restrict__ xb, const unsigned short* __restrict__ wb,
    const float* __restrict__ bias, unsigned short* __restrict__ qb,
    unsigned short* __restrict__ kb, unsigned short* __restrict__ vb) {
    __shared__ __align__(16) char As[128 * 128];
    __shared__ __align__(16) char Bs[128 * 128];
    const int t = threadIdx.x;
    const int bid = blockIdx.x;
    const int swz = (bid & 7) * (1728 / 8) + (bid >> 3);
    const int r0 = (swz / 6) * 128;
    const int c0 = (swz % 6) * 128;
    const int wid = t >> 6, l = t & 63;
    const int wr = wid >> 1, wc = wid & 1;
    const int lr = l & 15, lg = l >> 4;
    f4_t acc[4][4] = {};
    bf8_t ra[4], rb_[4];
#pragma unroll
    for (int i = 0; i < 4; ++i) {
        const int u = t + 256 * i;
        const int row = u >> 3, c8 = u & 7;
        ra[i]  = *reinterpret_cast<const bf8_t*>(&xb[(size_t)(r0 + row) * 256 + c8 * 8]);
        rb_[i] = *reinterpret_cast<const bf8_t*>(&wb[(size_t)(c0 + row) * 256 + c8 * 8]);
    }
#pragma unroll 1
    for (int ks = 0; ks < 4; ++ks) {
#pragma unroll
        for (int i = 0; i < 4; ++i) {
            const int u = t + 256 * i;
            const int row = u >> 3, c8 = u & 7;
            *reinterpret_cast<bf8_t*>(As + row * 128 + ((c8 * 16) ^ ((row & 7) << 4))) = ra[i];
            *reinterpret_cast<bf8_t*>(Bs + row * 128 + ((c8 * 16) ^ ((row & 7) << 4))) = rb_[i];
        }
        __syncthreads();
        if (ks < 3) {
            const int k0n = (ks + 1) * 64;
#pragma unroll
            for (int i = 0; i < 4; ++i) {
                const int u = t + 256 * i;
                const int row = u >> 3, c8 = u & 7;
                ra[i]  = *reinterpret_cast<const bf8_t*>(&xb[(size_t)(r0 + row) * 256 + k0n + c8 * 8]);
                rb_[i] = *reinterpret_cast<const bf8_t*>(&wb[(size_t)(c0 + row) * 256 + k0n + c8 * 8]);
            }
        }
#pragma unroll
        for (int kk = 0; kk < 2; ++kk) {
            bf8_t a[4], b[4];
#pragma unroll
            for (int mt = 0; mt < 4; ++mt) {
                const int row = wr * 64 + mt * 16 + lr;
                a[mt] = *reinterpret_cast<const bf8_t*>(
                    As + row * 128 + ((kk * 64 + lg * 16) ^ ((row & 7) << 4)));
            }
#pragma unroll
            for (int nt = 0; nt < 4; ++nt) {
                const int row = wc * 64 + nt * 16 + lr;
                b[nt] = *reinterpret_cast<const bf8_t*>(
                    Bs + row * 128 + ((kk * 64 + lg * 16) ^ ((row & 7) << 4)));
            }
#pragma unroll
            for (int mt = 0; mt < 4; ++mt)
#pragma unroll
                for (int nt = 0; nt < 4; ++nt)
                    acc[mt][nt] = __builtin_amdgcn_mfma_f32_16x16x32_bf16(a[mt], b[nt], acc[mt][nt], 0, 0, 0);
        }
        __syncthreads();                   // reads done before next slab's writes
    }
#pragma unroll
    for (int nt = 0; nt < 4; ++nt) {
        const int gc = c0 + wc * 64 + nt * 16 + lr;
        const int i3 = gc >> 8, rem = gc & 255;
        const int h = rem >> 5, hd = rem & 31;
        const float bv = bias[gc];
        unsigned short* dst = (i3 == 0) ? qb : (i3 == 1) ? kb : vb;
#pragma unroll
        for (int mt = 0; mt < 4; ++mt)
#pragma unroll
            for (int j = 0; j < 4; ++j) {
                const int gr = r0 + wr * 64 + mt * 16 + lg * 4 + j;
                const int bb = gr >> 6, n = gr & 63;
                dst[(size_t)((bb * NHD + h) * NTOK + n) * HD + hd] =
                    (unsigned short)f2bf(acc[mt][nt][j] + bv);
            }
    }
}

// ------- proj GEMM via bf16 MFMA: 128x128 tile, BK=64, T14 prefetch -----------
__global__ __launch_bounds__(256) void k_proj_mfma(
    const unsigned short* __restrict__ A, const unsigned short* __restrict__ w,
    const float* __restrict__ bias, float* __restrict__ out) {
    __shared__ __align__(16) char As[128 * 128];
    __shared__ __align__(16) char Bs[128 * 128];
    const int t = threadIdx.x;
    const int bid = blockIdx.x;
    const int swz = (bid & 7) * (576 / 8) + (bid >> 3);
    const int r0 = (swz / 2) * 128;
    const int c0 = (swz % 2) * 128;
    const int wid = t >> 6, l = t & 63;
    const int wr = wid >> 1, wc = wid & 1;
    const int lr = l & 15, lg = l >> 4;
    f4_t acc[4][4] = {};
    bf8_t ra[4], rb_[4];
#pragma unroll
    for (int i = 0; i < 4; ++i) {
        const int u = t + 256 * i;
        const int row = u >> 3, c8 = u & 7;
        ra[i]  = *reinterpret_cast<const bf8_t*>(&A[(size_t)(r0 + row) * 256 + c8 * 8]);
        rb_[i] = *reinterpret_cast<const bf8_t*>(&w[(size_t)(c0 + row) * 256 + c8 * 8]);
    }
#pragma unroll 1
    for (int ks = 0; ks < 4; ++ks) {
#pragma unroll
        for (int i = 0; i < 4; ++i) {
            const int u = t + 256 * i;
            const int row = u >> 3, c8 = u & 7;
            *reinterpret_cast<bf8_t*>(As + row * 128 + ((c8 * 16) ^ ((row & 7) << 4))) = ra[i];
            *reinterpret_cast<bf8_t*>(Bs + row * 128 + ((c8 * 16) ^ ((row & 7) << 4))) = rb_[i];
        }
        __syncthreads();
        if (ks < 3) {
            const int k0n = (ks + 1) * 64;
#pragma unroll
            for (int i = 0; i < 4; ++i) {
                const int u = t + 256 * i;
                const int row = u >> 3, c8 = u & 7;
                ra[i]  = *reinterpret_cast<const bf8_t*>(&A[(size_t)(r0 + row) * 256 + k0n + c8 * 8]);
                rb_[i] = *reinterpret_cast<const bf8_t*>(&w[(size_t)(c0 + row) * 256 + k0n + c8 * 8]);
            }
        }
#pragma unroll
        for (int kk = 0; kk < 2; ++kk) {
            bf8_t a[4], b[4];
#pragma unroll
            for (int mt = 0; mt < 4; ++mt) {
                const int row = wr * 64 + mt * 16 + lr;
                a[mt] = *reinterpret_cast<const bf8_t*>(
                    As + row * 128 + ((kk * 64 + lg * 16) ^ ((row & 7) << 4)));
            }
#pragma unroll
            for (int nt = 0; nt < 4; ++nt) {
                const int row = wc * 64 + nt * 16 + lr;
                b[nt] = *reinterpret_cast<const bf8_t*>(
                    Bs + row * 128 + ((kk * 64 + lg * 16) ^ ((row & 7) << 4)));
            }
#pragma unroll
            for (int mt = 0; mt < 4; ++mt)
#pragma unroll
                for (int nt = 0; nt < 4; ++nt)
                    acc[mt][nt] = __builtin_amdgcn_mfma_f32_16x16x32_bf16(a[mt], b[nt], acc[mt][nt], 0, 0, 0);
        }
        __syncthreads();
    }
#pragma unroll
    for (int nt = 0; nt < 4; ++nt) {
        const int gc = c0 + wc * 64 + nt * 16 + lr;
        const float bv = bias[gc];
#pragma unroll
        for (int mt = 0; mt < 4; ++mt)
#pragma unroll
            for (int j = 0; j < 4; ++j) {
                const int gr = r0 + wr * 64 + mt * 16 + lg * 4 + j;
                out[(size_t)gr * 256 + gc] = acc[mt][nt][j] + bv;
            }
    }
}

// -------- ref scores, 4 windows/block: q(bf16) . ref_q -> scores --------------
__global__ __launch_bounds__(256) void k_scores(
    const unsigned short* __restrict__ qbuf, const float* __restrict__ ref_q,
    float* __restrict__ scores) {
    const int bid = blockIdx.x;            // ((rb*8+h)*36 + wg)
    const int wg = bid % 36;
    const int rh = bid / 36;
    const int h = rh % NHD, rb = rh / NHD;
    __shared__ __align__(16) float rs[NREF][32];
    __shared__ float outb[4][64 * NREF];
    const int t = threadIdx.x;
    const int wv = t >> 6, n = t & 63;
    const float* rsrc = &ref_q[(size_t)rh * NREF * HD];
    for (int u = t; u < NREF * 8; u += 256) {
        const int row = u >> 3, c4 = u & 7;
        *reinterpret_cast<float4*>(&rs[row][c4 * 4]) =
            *reinterpret_cast<const float4*>(&rsrc[u * 4]);
    }
    __syncthreads();
    const int w = wg * 4 + wv;
    const unsigned short* qsrc = &qbuf[(size_t)((rb * NWIN + w) * NHD + h) * NTOK * HD + n * 32];
    float q[32];
#pragma unroll
    for (int c8 = 0; c8 < 4; ++c8) {
        bf8_t v = *reinterpret_cast<const bf8_t*>(&qsrc[c8 * 8]);
#pragma unroll
        for (int j = 0; j < 8; ++j)
            q[c8 * 8 + j] = bf2f((unsigned short)v[j]);
    }
    for (int r = 0; r < NREF; ++r) {
        float acc = 0.f;
#pragma unroll
        for (int d = 0; d < 32; ++d) acc += q[d] * rs[r][d];
        outb[wv][n * NREF + r] = acc;
    }
    float* dst = &scores[(size_t)((rb * NHD + h) * IMG_H + w * 64) * NREF];
    for (int u = n; u < 64 * NREF; u += 64) dst[u] = outb[wv][u];
}

// ---------------- conv 3x3 via MFMA (implicit GEMM), 32-row chunks ------------
// Round-15 macro-structure (47.7us) with G13-vectorized staging: loop items are
// (yy, ci, x-pair) -> float2 scPrev load + dword updPrev load + float2 scOut
// store (memory instruction counts halved vs scalar; NREF=30=15 pairs, all
// accesses 8B/4B aligned since indices are even). Two u16 LDS writes per pair.
// FUSED: staging applies sc + gelu(LN(upd)), writes scOut for own rows.
template<int FUSED>
__global__ __launch_bounds__(256) void k_conv_mfma(
    const float* __restrict__ scPrev, const unsigned short* __restrict__ updPrev,
    const float* __restrict__ stPrev, const float* __restrict__ conv_w,
    const float* __restrict__ conv_b, float* __restrict__ scOut,
    unsigned short* __restrict__ updOut, float* __restrict__ stats) {
    const int bid = blockIdx.x;            // rb*288 + ychunk
    const int rb = bid / 288;
    const int y0 = (bid % 288) * 32;
    __shared__ __align__(16) unsigned short At[34][32][8];
    __shared__ float red[4][8][2];
    __shared__ float lmean[8], lrsig[8];
    const int t = threadIdx.x;
    if (FUSED) {
        if (t < 8) {
            const float s0 = stPrev[(rb * NHD + t) * 2];
            const float s1 = stPrev[(rb * NHD + t) * 2 + 1];
            const float m = s0 * (1.f / LN_CNT);
            const float v = s1 * (1.f / LN_CNT) - m * m;
            lmean[t] = m;
            lrsig[t] = rsqrtf(v + LN_EPS);
        }
        __syncthreads();
    }
    // zero pad columns sx = 0 and 31
    for (int f = t; f < 34 * 2; f += 256) {
        const int yy = f >> 1, side = (f & 1) ? 31 : 0;
        bf8_t z;
#pragma unroll
        for (int j = 0; j < 8; ++j) z[j] = 0;
        *reinterpret_cast<bf8_t*>(&At[yy][side][0]) = z;
    }
    // stage: item (yy, ci, x-pair) -> float2 load -> 2 u16 LDS writes
    for (int ps = t; ps < 34 * 8 * 15; ps += 256) {
        const int yy = ps / 120;
        const int rem = ps % 120;
        const int ci = rem / 15, xh = rem % 15;
        const int xc = xh * 2;
        const int y = y0 - 1 + yy;
        unsigned short v0 = 0, v1 = 0;
        if (y >= 0 && y < IMG_H) {
            const size_t idx = (size_t)((rb * NHD + ci) * IMG_H + y) * NREF + xc;
            float2 sv = *reinterpret_cast<const float2*>(&scPrev[idx]);
            float a0, a1;
            if (FUSED) {
                const unsigned u2 = *reinterpret_cast<const unsigned*>(&updPrev[idx]);
                a0 = sv.x + gelu_f((bf2f((unsigned short)(u2 & 0xffffu)) - lmean[ci]) * lrsig[ci]);
                a1 = sv.y + gelu_f((bf2f((unsigned short)(u2 >> 16)) - lmean[ci]) * lrsig[ci]);
                if (yy >= 1 && yy <= 32) {
                    float2 so; so.x = a0; so.y = a1;
                    *reinterpret_cast<float2*>(&scOut[idx]) = so;
                }
            } else {
                a0 = sv.x; a1 = sv.y;
            }
            v0 = (unsigned short)f2bf(a0);
            v1 = (unsigned short)f2bf(a1);
        }
        At[yy][xc + 1][ci] = v0;
        At[yy][xc + 2][ci] = v1;
    }
    // weight B-fragments: lane (lr=co, lg) holds k-slice [tap=kg*4+lg][ci 0..7]
    const int l = t & 63, wv = t >> 6;
    const int lr = l & 15, lg = l >> 4;
    bf8_t wf[3];
#pragma unroll
    for (int kg = 0; kg < 3; ++kg) {
        const int tap = kg * 4 + lg;
        bf8_t wq;
#pragma unroll
        for (int j = 0; j < 8; ++j) wq[j] = 0;
        if (lr < 8 && tap < 9) {
            const int dy = tap / 3, dx = tap % 3;
#pragma unroll
            for (int ci = 0; ci < 8; ++ci)
                wq[ci] = f2bf(conv_w[lr * 72 + ci * 9 + dy * 3 + dx]);
        }
        wf[kg] = wq;
    }
    const float cb = (lr < 8) ? conv_b[lr] : 0.f;
    __syncthreads();
    float ls = 0.f, lss = 0.f;
    // 60 M-tiles of 16 pixels; wave wv owns tiles [wv*15, wv*15+15)
#pragma unroll 1
    for (int ti = 0; ti < 15; ++ti) {
        const int tile = wv * 15 + ti;
        const int pA = tile * 16 + lr;     // A-side pixel for this lane
        const int ylA = pA / 30, xA = pA % 30;
        f4_t o;
        o[0] = cb; o[1] = cb; o[2] = cb; o[3] = cb;
#pragma unroll
        for (int kg = 0; kg < 3; ++kg) {
            const int tap = kg * 4 + lg;
            const int dy = (tap < 9) ? tap / 3 : 0;
            const int dx = (tap < 9) ? tap % 3 : 0;
            bf8_t a = *reinterpret_cast<const bf8_t*>(&At[ylA + dy][xA + dx][0]);
            o = __builtin_amdgcn_mfma_f32_16x16x32_bf16(a, wf[kg], o, 0, 0, 0);
        }
        if (lr < 8) {
#pragma unroll
            for (int j = 0; j < 4; ++j) {
                const int pD = tile * 16 + lg * 4 + j;
                const int yl = pD / 30, x = pD % 30;
                updOut[(size_t)((rb * NHD + lr) * IMG_H + y0 + yl) * NREF + x] =
                    (unsigned short)f2bf(o[j]);
                ls += o[j];
                lss += o[j] * o[j];
            }
        }
    }
    ls += __shfl_xor(ls, 16); ls += __shfl_xor(ls, 32);
    lss += __shfl_xor(lss, 16); lss += __shfl_xor(lss, 32);
    if (l < 8) { red[wv][l][0] = ls; red[wv][l][1] = lss; }
    __syncthreads();
    if (t < 8) {
        atomicAdd(&stats[(rb * NHD + t) * 2],
                  red[0][t][0] + red[1][t][0] + red[2][t][0] + red[3][t][0]);
        atomicAdd(&stats[(rb * NHD + t) * 2 + 1],
                  red[0][t][1] + red[1][t][1] + red[2][t][1] + red[3][t][1]);
    }
}

// --- softmax over NREF (fused final LN+gelu+residual), 4 windows/block --------
__global__ __launch_bounds__(256) void k_qnewf(
    const float* __restrict__ scores, const unsigned short* __restrict__ upd,
    const float* __restrict__ st, const float* __restrict__ ref_v,
    unsigned short* __restrict__ qbuf) {
    const int bid = blockIdx.x;            // ((rb*8+h)*36 + wg)
    const int wg = bid % 36;
    const int rh = bid / 36;
    const int h = rh % NHD, rb = rh / NHD;
    __shared__ __align__(16) float rv[NREF][32];
    __shared__ float sl[4][64 * NREF];
    const int t = threadIdx.x;
    const int wv = t >> 6, n = t & 63;
    const float s0 = st[rh * 2], s1 = st[rh * 2 + 1];
    const float mean = s0 * (1.f / LN_CNT);
    const float var = s1 * (1.f / LN_CNT) - mean * mean;
    const float rsig = rsqrtf(var + LN_EPS);
    const float* rvs = &ref_v[(size_t)rh * NREF * HD];
    for (int u = t; u < NREF * 8; u += 256) {
        const int r = u >> 3, c4 = u & 7;
        *reinterpret_cast<float4*>(&rv[r][c4 * 4]) =
            *reinterpret_cast<const float4*>(&rvs[u * 4]);
    }
    const int w = wg * 4 + wv;
    const size_t base = (size_t)((rb * NHD + h) * IMG_H + w * 64) * NREF;
    for (int u = n; u < 64 * NREF; u += 64) {
        const float uv = bf2f(upd[base + u]);
        sl[wv][u] = scores[base + u] + gelu_f((uv - mean) * rsig);
    }
    __syncthreads();
    float p[NREF];
    float mx = -1e30f;
#pragma unroll
    for (int r = 0; r < NREF; ++r) { p[r] = sl[wv][n * NREF + r]; mx = fmaxf(mx, p[r]); }
    float sum = 0.f;
#pragma unroll
    for (int r = 0; r < NREF; ++r) { p[r] = expf(p[r] - mx); sum += p[r]; }
    const float inv = SCALE / sum;
    float acc[32] = {0.f};
#pragma unroll
    for (int r = 0; r < NREF; ++r) {
        const float pr = p[r] * inv;
#pragma unroll
        for (int d = 0; d < 32; ++d) acc[d] += pr * rv[r][d];
    }
    unsigned short* dst = &qbuf[(size_t)((rb * NWIN + w) * NHD + h) * NTOK * HD + n * 32];
#pragma unroll
    for (int c8 = 0; c8 < 4; ++c8) {
        bf8_t pk;
#pragma unroll
        for (int j = 0; j < 8; ++j) pk[j] = f2bf(acc[c8 * 8 + j]);
        *reinterpret_cast<bf8_t*>(&dst[c8 * 8]) = pk;
    }
}

// ---------------- window attention via MFMA, swapped operands ----------------
__global__ __launch_bounds__(256, 4) void k_wattn_mfma(
    const unsigned short* __restrict__ qbuf, const unsigned short* __restrict__ kbuf,
    const unsigned short* __restrict__ vbuf, const float* __restrict__ bmt,
    unsigned short* __restrict__ pre) {
    const int wh = blockIdx.x;             // w*8 + h
    const int w = wh >> 3, h = wh & 7;
    const int t = threadIdx.x;
    const int rb = t >> 6;                 // wave id = rb
    const int l = t & 63;
    const int lr = l & 15, lg = l >> 4;
    const int b = rb * NWIN + w;
    const int bid = b * NHD + h;
    __shared__ __align__(16) char P[4][64 * 128];

    // ---- C init from bmt[w][h][m][n]
    f4_t acc[4][4];
    const float* bm = &bmt[(size_t)wh * 4096];
#pragma unroll
    for (int mt = 0; mt < 4; ++mt)
#pragma unroll
        for (int nt = 0; nt < 4; ++nt)
#pragma unroll
            for (int j = 0; j < 4; ++j)
                acc[mt][nt][j] = bm[(mt * 16 + lg * 4 + j) * 64 + nt * 16 + lr];

    // ---- K frags (A) and Q frags (B): both bf16, 8 contiguous
    const unsigned short* kp = &kbuf[(size_t)bid * 2048];
    const unsigned short* qp = &qbuf[(size_t)bid * 2048];
    bf8_t kf[4], qf[4];
#pragma unroll
    for (int mt = 0; mt < 4; ++mt) {
        kf[mt] = *reinterpret_cast<const bf8_t*>(&kp[(mt * 16 + lr) * 32 + lg * 8]);
        qf[mt] = *reinterpret_cast<const bf8_t*>(&qp[(mt * 16 + lr) * 32 + lg * 8]);
    }
    // ---- S^T[m][n] = sum_k k[m][kk] q[n][kk] + bm
#pragma unroll
    for (int mt = 0; mt < 4; ++mt)
#pragma unroll
        for (int nt = 0; nt < 4; ++nt)
            acc[mt][nt] = __builtin_amdgcn_mfma_f32_16x16x32_bf16(kf[mt], qf[nt], acc[mt][nt], 0, 0, 0);

    // ---- softmax over m (in-lane mt,j + shfl over lg)
#pragma unroll
    for (int nt = 0; nt < 4; ++nt) {
        float mx = -1e30f;
#pragma unroll
        for (int mt = 0; mt < 4; ++mt)
#pragma unroll
            for (int j = 0; j < 4; ++j) mx = fmaxf(mx, acc[mt][nt][j]);
        mx = fmaxf(mx, __shfl_xor(mx, 16));
        mx = fmaxf(mx, __shfl_xor(mx, 32));
        float s = 0.f;
#pragma unroll
        for (int mt = 0; mt < 4; ++mt)
#pragma unroll
            for (int j = 0; j < 4; ++j) {
                const float e = expf(acc[mt][nt][j] - mx);
                acc[mt][nt][j] = e;
                s += e;
            }
        s += __shfl_xor(s, 16);
        s += __shfl_xor(s, 32);
        const float inv = 1.f / s;
#pragma unroll
        for (int mt = 0; mt < 4; ++mt)
#pragma unroll
            for (int j = 0; j < 4; ++j) acc[mt][nt][j] *= inv;
    }

    // ---- pack P[n][m] bf16 into LDS (row 128B, XOR ((n&7)<<4))
    const int n7 = (lr & 7) << 4;
    char* Pw = P[rb];
#pragma unroll
    for (int nt = 0; nt < 4; ++nt) {
        const int rowb = (nt * 16 + lr) * 128;
#pragma unroll
        for (int mt = 0; mt < 4; ++mt)
#pragma unroll
            for (int jp = 0; jp < 2; ++jp) {
                const unsigned lo = (unsigned short)f2bf(acc[mt][nt][jp * 2]);
                const unsigned hi = (unsigned short)f2bf(acc[mt][nt][jp * 2 + 1]);
                const int mb = (mt * 16 + lg * 4 + jp * 2) * 2;
                *reinterpret_cast<unsigned*>(&Pw[rowb + (mb ^ n7)]) = lo | (hi << 16);
            }
    }
    __syncthreads();

    // ---- V^T frags (A): row hd, k = m (gather u16)
    const unsigned short* vp = &vbuf[(size_t)bid * 2048];
    bf8_t vf[2][2];
#pragma unroll
    for (int ht = 0; ht < 2; ++ht)
#pragma unroll
        for (int ks = 0; ks < 2; ++ks) {
            bf8_t tv;
#pragma unroll
            for (int j = 0; j < 8; ++j)
                tv[j] = (short)vp[(ks * 32 + lg * 8 + j) * 32 + ht * 16 + lr];
            vf[ht][ks] = tv;
        }

    // ---- O^T = V^T @ P^T
    f4_t o[2][4] = {};
#pragma unroll
    for (int ks = 0; ks < 2; ++ks)
#pragma unroll
        for (int nt = 0; nt < 4; ++nt) {
            const int rowb = (nt * 16 + lr) * 128;
            bf8_t pf = *reinterpret_cast<const bf8_t*>(&Pw[rowb + ((ks * 64 + lg * 16) ^ n7)]);
#pragma unroll
            for (int ht = 0; ht < 2; ++ht)
                o[ht][nt] = __builtin_amdgcn_mfma_f32_16x16x32_bf16(vf[ht][ks], pf, o[ht][nt], 0, 0, 0);
        }

    // ---- store O^T as bf16: pre[(b*64+n)*256 + h*32 + hd]
#pragma unroll
    for (int ht = 0; ht < 2; ++ht)
#pragma unroll
        for (int nt = 0; nt < 4; ++nt) {
            ushort4 pk;
            pk.x = (unsigned short)f2bf(o[ht][nt][0]);
            pk.y = (unsigned short)f2bf(o[ht][nt][1]);
            pk.z = (unsigned short)f2bf(o[ht][nt][2]);
            pk.w = (unsigned short)f2bf(o[ht][nt][3]);
            const int n = nt * 16 + lr;
            const int hd = ht * 16 + lg * 4;
            *reinterpret_cast<ushort4*>(&pre[(size_t)(b * 64 + n) * 256 + h * 32 + hd]) = pk;
        }
}

extern "C" void kernel_launch(void* const* d_in, const int* in_sizes, int n_in,
                              void* d_out, int out_size, void* d_ws, size_t ws_size,
                              hipStream_t stream) {
    const float* x          = (const float*)d_in[0];
    const float* mask       = (const float*)d_in[1];
    const float* x_ref      = (const float*)d_in[2];
    const float* qkv_w      = (const float*)d_in[3];
    const float* qkv_b      = (const float*)d_in[4];
    const float* proj_w     = (const float*)d_in[5];
    const float* proj_b     = (const float*)d_in[6];
    const float* bias_table = (const float*)d_in[7];
    const float* diff_mu    = (const float*)d_in[8];
    const float* diff_ls    = (const float*)d_in[9];
    const float* ref_qk_w   = (const float*)d_in[10];
    const float* ref_qk_b   = (const float*)d_in[11];
    const float* conv_w     = (const float*)d_in[12];
    const float* conv_b     = (const float*)d_in[13];
    const int*   rel_index  = (const int*)d_in[14];
    float* out = (float*)d_out;

    unsigned short* xb   = (unsigned short*)d_ws;                // 9437184 u16
    unsigned short* qb16 = xb + 9437184;                         // 9437184 u16
    unsigned short* kb16 = qb16 + 9437184;                       // 9437184 u16
    unsigned short* vb16 = kb16 + 9437184;                       // 9437184 u16
    float* scA           = (float*)(vb16 + 9437184);             // 8847360 f
    unsigned short* updA = (unsigned short*)(scA + 8847360);     // 8847360 u16
    unsigned short* updB = updA + 8847360;                       // 8847360 u16
    float* rq            = (float*)(updB + 8847360);             // 30720 f
    float* rv            = rq + 30720;                           // 30720 f
    float* st            = rv + 30720;                           // 192 f (3 x 64)
    float* bmt           = st + 192;                             // 4718592 f
    unsigned short* wqb  = (unsigned short*)(bmt + 4718592);     // 196608 u16
    unsigned short* wpb  = wqb + 196608;                         // 65536 u16
    float* scB           = (float*)d_ws;                         // reuses xb+qb16 (dead during conv)
    unsigned short* pre  = (unsigned short*)scA;                 // alias: scA dead after k_qnewf

    k_cvt<<<2048, 256, 0, stream>>>(x, xb, 9437184 / 8);
    k_cvt<<<96, 256, 0, stream>>>(qkv_w, wqb, 196608 / 8);
    k_cvt<<<32, 256, 0, stream>>>(proj_w, wpb, 65536 / 8);
    k_refprep<<<RB, 256, 0, stream>>>(x_ref, ref_qk_w, ref_qk_b, diff_mu, diff_ls, rq, rv);
    k_bm<<<NWIN * NHD, 256, 0, stream>>>(mask, bias_table, rel_index, bmt);
    k_qkv_mfma<<<1728, 256, 0, stream>>>(xb, wqb, qkv_b, qb16, kb16, vb16);
    k_scores<<<RB * NHD * 36, 256, 0, stream>>>(qb16, rq, scA);
    hipMemsetAsync(st, 0, 192 * sizeof(float), stream);
    k_conv_mfma<0><<<RB * 288, 256, 0, stream>>>(scA, updA, st, conv_w, conv_b, scB, updA, st);
    k_conv_mfma<1><<<RB * 288, 256, 0, stream>>>(scA, updA, st, conv_w, conv_b, scB, updB, st + 64);
    k_conv_mfma<1><<<RB * 288, 256, 0, stream>>>(scB, updB, st + 64, conv_w, conv_b, scA, updA, st + 128);
    k_qnewf<<<RB * NHD * 36, 256, 0, stream>>>(scA, updA, st + 128, rv, qb16);
    k_wattn_mfma<<<NWIN * NHD, 256, 0, stream>>>(qb16, kb16, vb16, bmt, pre);
    k_proj_mfma<<<576, 256, 0, stream>>>(pre, wpb, proj_b, out);
}

// Round 21
// 275.319 us; speedup vs baseline: 1.0999x; 1.0499x over previous
//
#include <hip/hip_runtime.h>
#include <math.h>

#define NHD 8
#define HD 32
#define NREF 30
#define RB 4
#define NWIN 144
#define NTOK 64
#define IMG_H (NWIN*NTOK)        /* 9216  */
#define LN_CNT (IMG_H*NREF)      /* 276480 */
#define SCALE 0.1767766952966369f
#define LN_EPS 1e-5f

typedef __attribute__((ext_vector_type(8))) short bf8_t;   // 8 x bf16
typedef __attribute__((ext_vector_type(4))) float f4_t;    // MFMA acc

__device__ __forceinline__ float gelu_f(float v) {
    return 0.5f * v * (1.0f + erff(v * 0.7071067811865476f));
}

__device__ __forceinline__ short f2bf(float f) {           // fp32 -> bf16 RNE
    union { float f; unsigned u; } v; v.f = f;
    unsigned r = v.u + 0x7fffu + ((v.u >> 16) & 1u);
    return (short)(r >> 16);
}

__device__ __forceinline__ float bf2f(unsigned short u) {
    union { unsigned u; float f; } v; v.u = ((unsigned)u) << 16;
    return v.f;
}

// ---- fused prep: cvt(x) | bm | cvt(qkv_w) | cvt(proj_w) | refprep ----
// Five independent front-end kernels merged into one launch (block-range
// dispatch) to remove 4 inter-launch serializations + the 4-block refprep
// stranding the machine. Each branch is the byte-identical loop body of the
// kernel it replaces.
__global__ __launch_bounds__(256) void k_prep(
    const float* __restrict__ x, unsigned short* __restrict__ xb,
    const float* __restrict__ qkv_w, unsigned short* __restrict__ wqb,
    const float* __restrict__ proj_w, unsigned short* __restrict__ wpb,
    const float* __restrict__ mask, const float* __restrict__ bias_table,
    const int* __restrict__ rel_index, float* __restrict__ bmt,
    const float* __restrict__ x_ref, const float* __restrict__ rw,
    const float* __restrict__ rbias, const float* __restrict__ dmu,
    const float* __restrict__ dls, float* __restrict__ ref_q,
    float* __restrict__ ref_v) {
    __shared__ float shbuf[60 * NREF + 64];
    const int bid = blockIdx.x;
    const int t = threadIdx.x;
    if (bid < 2048) {                      // ---- cvt x (36MB -> 18MB)
        const int n8 = 9437184 / 8;
        for (int i = bid * 256 + t; i < n8; i += 2048 * 256) {
            const float* s = x + (size_t)i * 8;
            float4 a = *reinterpret_cast<const float4*>(s);
            float4 b = *reinterpret_cast<const float4*>(s + 4);
            bf8_t p;
            p[0] = f2bf(a.x); p[1] = f2bf(a.y); p[2] = f2bf(a.z); p[3] = f2bf(a.w);
            p[4] = f2bf(b.x); p[5] = f2bf(b.y); p[6] = f2bf(b.z); p[7] = f2bf(b.w);
            *reinterpret_cast<bf8_t*>(xb + (size_t)i * 8) = p;
        }
    } else if (bid < 3200) {               // ---- bm table (1152 blocks)
        const int wh = bid - 2048;         // w*8 + h
        const int w = wh >> 3, h = wh & 7;
        for (int u = t; u < 4096; u += 256) {
            const int m = u >> 6, n = u & 63;
            bmt[(size_t)wh * 4096 + u] = mask[(size_t)w * 4096 + n * 64 + m]
                                       + bias_table[rel_index[n * 64 + m] * NHD + h];
        }
    } else if (bid < 3296) {               // ---- cvt qkv_w (96 blocks)
        const int b2 = bid - 3200;
        const int n8 = 196608 / 8;
        for (int i = b2 * 256 + t; i < n8; i += 96 * 256) {
            const float* s = qkv_w + (size_t)i * 8;
            float4 a = *reinterpret_cast<const float4*>(s);
            float4 b = *reinterpret_cast<const float4*>(s + 4);
            bf8_t p;
            p[0] = f2bf(a.x); p[1] = f2bf(a.y); p[2] = f2bf(a.z); p[3] = f2bf(a.w);
            p[4] = f2bf(b.x); p[5] = f2bf(b.y); p[6] = f2bf(b.z); p[7] = f2bf(b.w);
            *reinterpret_cast<bf8_t*>(wqb + (size_t)i * 8) = p;
        }
    } else if (bid < 3328) {               // ---- cvt proj_w (32 blocks)
        const int b2 = bid - 3296;
        const int n8 = 65536 / 8;
        for (int i = b2 * 256 + t; i < n8; i += 32 * 256) {
            const float* s = proj_w + (size_t)i * 8;
            float4 a = *reinterpret_cast<const float4*>(s);
            float4 b = *reinterpret_cast<const float4*>(s + 4);
            bf8_t p;
            p[0] = f2bf(a.x); p[1] = f2bf(a.y); p[2] = f2bf(a.z); p[3] = f2bf(a.w);
            p[4] = f2bf(b.x); p[5] = f2bf(b.y); p[6] = f2bf(b.z); p[7] = f2bf(b.w);
            *reinterpret_cast<bf8_t*>(wpb + (size_t)i * 8) = p;
        }
    } else {                               // ---- refprep (4 blocks)
        float* Wl = shbuf;                 // [60][NREF]
        float* Bl = shbuf + 60 * NREF;     // [60]
        const int rb = bid - 3328;
        for (int i = t; i < 60 * NREF; i += 256) Wl[i] = rw[i];
        if (t < 60) Bl[t] = rbias[t];
        __syncthreads();
        const int d = t;                   // 0..255
        float xr[NREF];
#pragma unroll
        for (int r = 0; r < NREF; ++r) xr[r] = x_ref[(rb * 256 + d) * NREF + r];
        const int h = d >> 5, hd = d & 31;
        const float mu = dmu[d], sg = expf(dls[d]);
        for (int j = 0; j < 60; ++j) {
            float acc = Bl[j];
#pragma unroll
            for (int r = 0; r < NREF; ++r) acc += xr[r] * Wl[j * NREF + r];
            if (j < NREF)
                ref_q[((rb * NHD + h) * NREF + j) * HD + hd] = mu + sg * acc;
            else
                ref_v[((rb * NHD + h) * NREF + (j - NREF)) * HD + hd] = acc;
        }
    }
}

// ------- qkv GEMM via bf16 MFMA: 128x128 tile, BK=64, 4 waves x (4x4 frags) ---
// T14 register prefetch: slab ks+1's A/B panels load right after the staging
// barrier so the 8 global loads overlap the MFMA phase (+32 VGPR).
__global__ __launch_bounds__(256) void k_qkv_mfma(
    const unsigned short* __restrict__ xb, const unsigned short* __restrict__ wb,
    const float* __restrict__ bias, unsigned short* __restrict__ qb,
    unsigned short* __restrict__ kb, unsigned short* __restrict__ vb) {
    __shared__ __align__(16) char As[128 * 128];
    __shared__ __align__(16) char Bs[128 * 128];
    const int t = threadIdx.x;
    const int bid = blockIdx.x;
    const int swz = (bid & 7) * (1728 / 8) + (bid >> 3);
    const int r0 = (swz / 6) * 128;
    const int c0 = (swz % 6) * 128;
    const int wid = t >> 6, l = t & 63;
    const int wr = wid >> 1, wc = wid & 1;
    const int lr = l & 15, lg = l >> 4;
    f4_t acc[4][4] = {};
    bf8_t ra[4], rb_[4];
#pragma unroll
    for (int i = 0; i < 4; ++i) {
        const int u = t + 256 * i;
        const int row = u >> 3, c8 = u & 7;
        ra[i]  = *reinterpret_cast<const bf8_t*>(&xb[(size_t)(r0 + row) * 256 + c8 * 8]);
        rb_[i] = *reinterpret_cast<const bf8_t*>(&wb[(size_t)(c0 + row) * 256 + c8 * 8]);
    }
#pragma unroll 1
    for (int ks = 0; ks < 4; ++ks) {
#pragma unroll
        for (int i = 0; i < 4; ++i) {
            const int u = t + 256 * i;
            const int row = u >> 3, c8 = u & 7;
            *reinterpret_cast<bf8_t*>(As + row * 128 + ((c8 * 16) ^ ((row & 7) << 4))) = ra[i];
            *reinterpret_cast<bf8_t*>(Bs + row * 128 + ((c8 * 16) ^ ((row & 7) << 4))) = rb_[i];
        }
        __syncthreads();
        if (ks < 3) {
            const int k0n = (ks + 1) * 64;
#pragma unroll
            for (int i = 0; i < 4; ++i) {
                const int u = t + 256 * i;
                const int row = u >> 3, c8 = u & 7;
                ra[i]  = *reinterpret_cast<const bf8_t*>(&xb[(size_t)(r0 + row) * 256 + k0n + c8 * 8]);
                rb_[i] = *reinterpret_cast<const bf8_t*>(&wb[(size_t)(c0 + row) * 256 + k0n + c8 * 8]);
            }
        }
#pragma unroll
        for (int kk = 0; kk < 2; ++kk) {
            bf8_t a[4], b[4];
#pragma unroll
            for (int mt = 0; mt < 4; ++mt) {
                const int row = wr * 64 + mt * 16 + lr;
                a[mt] = *reinterpret_cast<const bf8_t*>(
                    As + row * 128 + ((kk * 64 + lg * 16) ^ ((row & 7) << 4)));
            }
#pragma unroll
            for (int nt = 0; nt < 4; ++nt) {
                const int row = wc * 64 + nt * 16 + lr;
                b[nt] = *reinterpret_cast<const bf8_t*>(
                    Bs + row * 128 + ((kk * 64 + lg * 16) ^ ((row & 7) << 4)));
            }
#pragma unroll
            for (int mt = 0; mt < 4; ++mt)
#pragma unroll
                for (int nt = 0; nt < 4; ++nt)
                    acc[mt][nt] = __builtin_amdgcn_mfma_f32_16x16x32_bf16(a[mt], b[nt], acc[mt][nt], 0, 0, 0);
        }
        __syncthreads();                   // reads done before next slab's writes
    }
#pragma unroll
    for (int nt = 0; nt < 4; ++nt) {
        const int gc = c0 + wc * 64 + nt * 16 + lr;
        const int i3 = gc >> 8, rem = gc & 255;
        const int h = rem >> 5, hd = rem & 31;
        const float bv = bias[gc];
        unsigned short* dst = (i3 == 0) ? qb : (i3 == 1) ? kb : vb;
#pragma unroll
        for (int mt = 0; mt < 4; ++mt)
#pragma unroll
            for (int j = 0; j < 4; ++j) {
                const int gr = r0 + wr * 64 + mt * 16 + lg * 4 + j;
                const int bb = gr >> 6, n = gr & 63;
                dst[(size_t)((bb * NHD + h) * NTOK + n) * HD + hd] =
                    (unsigned short)f2bf(acc[mt][nt][j] + bv);
            }
    }
}

// ------- proj GEMM via bf16 MFMA: 128x128 tile, BK=64, T14 prefetch -----------
__global__ __launch_bounds__(256) void k_proj_mfma(
    const unsigned short* __restrict__ A, const unsigned short* __restrict__ w,
    const float* __restrict__ bias, float* __restrict__ out) {
    __shared__ __align__(16) char As[128 * 128];
    __shared__ __align__(16) char Bs[128 * 128];
    const int t = threadIdx.x;
    const int bid = blockIdx.x;
    const int swz = (bid & 7) * (576 / 8) + (bid >> 3);
    const int r0 = (swz / 2) * 128;
    const int c0 = (swz % 2) * 128;
    const int wid = t >> 6, l = t & 63;
    const int wr = wid >> 1, wc = wid & 1;
    const int lr = l & 15, lg = l >> 4;
    f4_t acc[4][4] = {};
    bf8_t ra[4], rb_[4];
#pragma unroll
    for (int i = 0; i < 4; ++i) {
        const int u = t + 256 * i;
        const int row = u >> 3, c8 = u & 7;
        ra[i]  = *reinterpret_cast<const bf8_t*>(&A[(size_t)(r0 + row) * 256 + c8 * 8]);
        rb_[i] = *reinterpret_cast<const bf8_t*>(&w[(size_t)(c0 + row) * 256 + c8 * 8]);
    }
#pragma unroll 1
    for (int ks = 0; ks < 4; ++ks) {
#pragma unroll
        for (int i = 0; i < 4; ++i) {
            const int u = t + 256 * i;
            const int row = u >> 3, c8 = u & 7;
            *reinterpret_cast<bf8_t*>(As + row * 128 + ((c8 * 16) ^ ((row & 7) << 4))) = ra[i];
            *reinterpret_cast<bf8_t*>(Bs + row * 128 + ((c8 * 16) ^ ((row & 7) << 4))) = rb_[i];
        }
        __syncthreads();
        if (ks < 3) {
            const int k0n = (ks + 1) * 64;
#pragma unroll
            for (int i = 0; i < 4; ++i) {
                const int u = t + 256 * i;
                const int row = u >> 3, c8 = u & 7;
                ra[i]  = *reinterpret_cast<const bf8_t*>(&A[(size_t)(r0 + row) * 256 + k0n + c8 * 8]);
                rb_[i] = *reinterpret_cast<const bf8_t*>(&w[(size_t)(c0 + row) * 256 + k0n + c8 * 8]);
            }
        }
#pragma unroll
        for (int kk = 0; kk < 2; ++kk) {
            bf8_t a[4], b[4];
#pragma unroll
            for (int mt = 0; mt < 4; ++mt) {
                const int row = wr * 64 + mt * 16 + lr;
                a[mt] = *reinterpret_cast<const bf8_t*>(
                    As + row * 128 + ((kk * 64 + lg * 16) ^ ((row & 7) << 4)));
            }
#pragma unroll
            for (int nt = 0; nt < 4; ++nt) {
                const int row = wc * 64 + nt * 16 + lr;
                b[nt] = *reinterpret_cast<const bf8_t*>(
                    Bs + row * 128 + ((kk * 64 + lg * 16) ^ ((row & 7) << 4)));
            }
#pragma unroll
            for (int mt = 0; mt < 4; ++mt)
#pragma unroll
                for (int nt = 0; nt < 4; ++nt)
                    acc[mt][nt] = __builtin_amdgcn_mfma_f32_16x16x32_bf16(a[mt], b[nt], acc[mt][nt], 0, 0, 0);
        }
        __syncthreads();
    }
#pragma unroll
    for (int nt = 0; nt < 4; ++nt) {
        const int gc = c0 + wc * 64 + nt * 16 + lr;
        const float bv = bias[gc];
#pragma unroll
        for (int mt = 0; mt < 4; ++mt)
#pragma unroll
            for (int j = 0; j < 4; ++j) {
                const int gr = r0 + wr * 64 + mt * 16 + lg * 4 + j;
                out[(size_t)gr * 256 + gc] = acc[mt][nt][j] + bv;
            }
    }
}

// -------- ref scores, 4 windows/block: q(bf16) . ref_q -> scores --------------
__global__ __launch_bounds__(256) void k_scores(
    const unsigned short* __restrict__ qbuf, const float* __restrict__ ref_q,
    float* __restrict__ scores) {
    const int bid = blockIdx.x;            // ((rb*8+h)*36 + wg)
    const int wg = bid % 36;
    const int rh = bid / 36;
    const int h = rh % NHD, rb = rh / NHD;
    __shared__ __align__(16) float rs[NREF][32];
    __shared__ float outb[4][64 * NREF];
    const int t = threadIdx.x;
    const int wv = t >> 6, n = t & 63;
    const float* rsrc = &ref_q[(size_t)rh * NREF * HD];
    for (int u = t; u < NREF * 8; u += 256) {
        const int row = u >> 3, c4 = u & 7;
        *reinterpret_cast<float4*>(&rs[row][c4 * 4]) =
            *reinterpret_cast<const float4*>(&rsrc[u * 4]);
    }
    __syncthreads();
    const int w = wg * 4 + wv;
    const unsigned short* qsrc = &qbuf[(size_t)((rb * NWIN + w) * NHD + h) * NTOK * HD + n * 32];
    float q[32];
#pragma unroll
    for (int c8 = 0; c8 < 4; ++c8) {
        bf8_t v = *reinterpret_cast<const bf8_t*>(&qsrc[c8 * 8]);
#pragma unroll
        for (int j = 0; j < 8; ++j)
            q[c8 * 8 + j] = bf2f((unsigned short)v[j]);
    }
    for (int r = 0; r < NREF; ++r) {
        float acc = 0.f;
#pragma unroll
        for (int d = 0; d < 32; ++d) acc += q[d] * rs[r][d];
        outb[wv][n * NREF + r] = acc;
    }
    float* dst = &scores[(size_t)((rb * NHD + h) * IMG_H + w * 64) * NREF];
    for (int u = n; u < 64 * NREF; u += 64) dst[u] = outb[wv][u];
}

// ---------------- conv 3x3 via MFMA (implicit GEMM), 32-row chunks ------------
// Round-20 config (46.8us): 1152 blocks, At[34][32][8] bf16 17.9KB, vectorized
// staging (float2 loads, dword updPrev, float2 scOut stores). M = 16 pixels,
// N = 16 (8 co used), K = 96. A-frag = one ds_read_b128; B = 3 preloaded frags.
// FUSED: staging applies sc + gelu(LN(upd)), writes scOut for own rows.
template<int FUSED>
__global__ __launch_bounds__(256) void k_conv_mfma(
    const float* __restrict__ scPrev, const unsigned short* __restrict__ updPrev,
    const float* __restrict__ stPrev, const float* __restrict__ conv_w,
    const float* __restrict__ conv_b, float* __restrict__ scOut,
    unsigned short* __restrict__ updOut, float* __restrict__ stats) {
    const int bid = blockIdx.x;            // rb*288 + ychunk
    const int rb = bid / 288;
    const int y0 = (bid % 288) * 32;
    __shared__ __align__(16) unsigned short At[34][32][8];
    __shared__ float red[4][8][2];
    __shared__ float lmean[8], lrsig[8];
    const int t = threadIdx.x;
    if (FUSED) {
        if (t < 8) {
            const float s0 = stPrev[(rb * NHD + t) * 2];
            const float s1 = stPrev[(rb * NHD + t) * 2 + 1];
            const float m = s0 * (1.f / LN_CNT);
            const float v = s1 * (1.f / LN_CNT) - m * m;
            lmean[t] = m;
            lrsig[t] = rsqrtf(v + LN_EPS);
        }
        __syncthreads();
    }
    // zero pad columns sx = 0 and 31
    for (int f = t; f < 34 * 2; f += 256) {
        const int yy = f >> 1, side = (f & 1) ? 31 : 0;
        bf8_t z;
#pragma unroll
        for (int j = 0; j < 8; ++j) z[j] = 0;
        *reinterpret_cast<bf8_t*>(&At[yy][side][0]) = z;
    }
    // stage: item (yy, ci, x-pair) -> float2 load -> 2 u16 LDS writes
    for (int ps = t; ps < 34 * 8 * 15; ps += 256) {
        const int yy = ps / 120;
        const int rem = ps % 120;
        const int ci = rem / 15, xh = rem % 15;
        const int xc = xh * 2;
        const int y = y0 - 1 + yy;
        unsigned short v0 = 0, v1 = 0;
        if (y >= 0 && y < IMG_H) {
            const size_t idx = (size_t)((rb * NHD + ci) * IMG_H + y) * NREF + xc;
            float2 sv = *reinterpret_cast<const float2*>(&scPrev[idx]);
            float a0, a1;
            if (FUSED) {
                const unsigned u2 = *reinterpret_cast<const unsigned*>(&updPrev[idx]);
                a0 = sv.x + gelu_f((bf2f((unsigned short)(u2 & 0xffffu)) - lmean[ci]) * lrsig[ci]);
                a1 = sv.y + gelu_f((bf2f((unsigned short)(u2 >> 16)) - lmean[ci]) * lrsig[ci]);
                if (yy >= 1 && yy <= 32) {
                    float2 so; so.x = a0; so.y = a1;
                    *reinterpret_cast<float2*>(&scOut[idx]) = so;
                }
            } else {
                a0 = sv.x; a1 = sv.y;
            }
            v0 = (unsigned short)f2bf(a0);
            v1 = (unsigned short)f2bf(a1);
        }
        At[yy][xc + 1][ci] = v0;
        At[yy][xc + 2][ci] = v1;
    }
    // weight B-fragments: lane (lr=co, lg) holds k-slice [tap=kg*4+lg][ci 0..7]
    const int l = t & 63, wv = t >> 6;
    const int lr = l & 15, lg = l >> 4;
    bf8_t wf[3];
#pragma unroll
    for (int kg = 0; kg < 3; ++kg) {
        const int tap = kg * 4 + lg;
        bf8_t wq;
#pragma unroll
        for (int j = 0; j < 8; ++j) wq[j] = 0;
        if (lr < 8 && tap < 9) {
            const int dy = tap / 3, dx = tap % 3;
#pragma unroll
            for (int ci = 0; ci < 8; ++ci)
                wq[ci] = f2bf(conv_w[lr * 72 + ci * 9 + dy * 3 + dx]);
        }
        wf[kg] = wq;
    }
    const float cb = (lr < 8) ? conv_b[lr] : 0.f;
    __syncthreads();
    float ls = 0.f, lss = 0.f;
    // 60 M-tiles of 16 pixels; wave wv owns tiles [wv*15, wv*15+15)
#pragma unroll 1
    for (int ti = 0; ti < 15; ++ti) {
        const int tile = wv * 15 + ti;
        const int pA = tile * 16 + lr;     // A-side pixel for this lane
        const int ylA = pA / 30, xA = pA % 30;
        f4_t o;
        o[0] = cb; o[1] = cb; o[2] = cb; o[3] = cb;
#pragma unroll
        for (int kg = 0; kg < 3; ++kg) {
            const int tap = kg * 4 + lg;
            const int dy = (tap < 9) ? tap / 3 : 0;
            const int dx = (tap < 9) ? tap % 3 : 0;
            bf8_t a = *reinterpret_cast<const bf8_t*>(&At[ylA + dy][xA + dx][0]);
            o = __builtin_amdgcn_mfma_f32_16x16x32_bf16(a, wf[kg], o, 0, 0, 0);
        }
        if (lr < 8) {
#pragma unroll
            for (int j = 0; j < 4; ++j) {
                const int pD = tile * 16 + lg * 4 + j;
                const int yl = pD / 30, x = pD % 30;
                updOut[(size_t)((rb * NHD + lr) * IMG_H + y0 + yl) * NREF + x] =
                    (unsigned short)f2bf(o[j]);
                ls += o[j];
                lss += o[j] * o[j];
            }
        }
    }
    ls += __shfl_xor(ls, 16); ls += __shfl_xor(ls, 32);
    lss += __shfl_xor(lss, 16); lss += __shfl_xor(lss, 32);
    if (l < 8) { red[wv][l][0] = ls; red[wv][l][1] = lss; }
    __syncthreads();
    if (t < 8) {
        atomicAdd(&stats[(rb * NHD + t) * 2],
                  red[0][t][0] + red[1][t][0] + red[2][t][0] + red[3][t][0]);
        atomicAdd(&stats[(rb * NHD + t) * 2 + 1],
                  red[0][t][1] + red[1][t][1] + red[2][t][1] + red[3][t][1]);
    }
}

// --- softmax over NREF (fused final LN+gelu+residual), 4 windows/block --------
__global__ __launch_bounds__(256) void k_qnewf(
    const float* __restrict__ scores, const unsigned short* __restrict__ upd,
    const float* __restrict__ st, const float* __restrict__ ref_v,
    unsigned short* __restrict__ qbuf) {
    const int bid = blockIdx.x;            // ((rb*8+h)*36 + wg)
    const int wg = bid % 36;
    const int rh = bid / 36;
    const int h = rh % NHD, rb = rh / NHD;
    __shared__ __align__(16) float rv[NREF][32];
    __shared__ float sl[4][64 * NREF];
    const int t = threadIdx.x;
    const int wv = t >> 6, n = t & 63;
    const float s0 = st[rh * 2], s1 = st[rh * 2 + 1];
    const float mean = s0 * (1.f / LN_CNT);
    const float var = s1 * (1.f / LN_CNT) - mean * mean;
    const float rsig = rsqrtf(var + LN_EPS);
    const float* rvs = &ref_v[(size_t)rh * NREF * HD];
    for (int u = t; u < NREF * 8; u += 256) {
        const int r = u >> 3, c4 = u & 7;
        *reinterpret_cast<float4*>(&rv[r][c4 * 4]) =
            *reinterpret_cast<const float4*>(&rvs[u * 4]);
    }
    const int w = wg * 4 + wv;
    const size_t base = (size_t)((rb * NHD + h) * IMG_H + w * 64) * NREF;
    for (int u = n; u < 64 * NREF; u += 64) {
        const float uv = bf2f(upd[base + u]);
        sl[wv][u] = scores[base + u] + gelu_f((uv - mean) * rsig);
    }
    __syncthreads();
    float p[NREF];
    float mx = -1e30f;
#pragma unroll
    for (int r = 0; r < NREF; ++r) { p[r] = sl[wv][n * NREF + r]; mx = fmaxf(mx, p[r]); }
    float sum = 0.f;
#pragma unroll
    for (int r = 0; r < NREF; ++r) { p[r] = expf(p[r] - mx); sum += p[r]; }
    const float inv = SCALE / sum;
    float acc[32] = {0.f};
#pragma unroll
    for (int r = 0; r < NREF; ++r) {
        const float pr = p[r] * inv;
#pragma unroll
        for (int d = 0; d < 32; ++d) acc[d] += pr * rv[r][d];
    }
    unsigned short* dst = &qbuf[(size_t)((rb * NWIN + w) * NHD + h) * NTOK * HD + n * 32];
#pragma unroll
    for (int c8 = 0; c8 < 4; ++c8) {
        bf8_t pk;
#pragma unroll
        for (int j = 0; j < 8; ++j) pk[j] = f2bf(acc[c8 * 8 + j]);
        *reinterpret_cast<bf8_t*>(&dst[c8 * 8]) = pk;
    }
}

// ---------------- window attention via MFMA, swapped operands ----------------
__global__ __launch_bounds__(256, 4) void k_wattn_mfma(
    const unsigned short* __restrict__ qbuf, const unsigned short* __restrict__ kbuf,
    const unsigned short* __restrict__ vbuf, const float* __restrict__ bmt,
    unsigned short* __restrict__ pre) {
    const int wh = blockIdx.x;             // w*8 + h
    const int w = wh >> 3, h = wh & 7;
    const int t = threadIdx.x;
    const int rb = t >> 6;                 // wave id = rb
    const int l = t & 63;
    const int lr = l & 15, lg = l >> 4;
    const int b = rb * NWIN + w;
    const int bid = b * NHD + h;
    __shared__ __align__(16) char P[4][64 * 128];

    // ---- C init from bmt[w][h][m][n]
    f4_t acc[4][4];
    const float* bm = &bmt[(size_t)wh * 4096];
#pragma unroll
    for (int mt = 0; mt < 4; ++mt)
#pragma unroll
        for (int nt = 0; nt < 4; ++nt)
#pragma unroll
            for (int j = 0; j < 4; ++j)
                acc[mt][nt][j] = bm[(mt * 16 + lg * 4 + j) * 64 + nt * 16 + lr];

    // ---- K frags (A) and Q frags (B): both bf16, 8 contiguous
    const unsigned short* kp = &kbuf[(size_t)bid * 2048];
    const unsigned short* qp = &qbuf[(size_t)bid * 2048];
    bf8_t kf[4], qf[4];
#pragma unroll
    for (int mt = 0; mt < 4; ++mt) {
        kf[mt] = *reinterpret_cast<const bf8_t*>(&kp[(mt * 16 + lr) * 32 + lg * 8]);
        qf[mt] = *reinterpret_cast<const bf8_t*>(&qp[(mt * 16 + lr) * 32 + lg * 8]);
    }
    // ---- S^T[m][n] = sum_k k[m][kk] q[n][kk] + bm
#pragma unroll
    for (int mt = 0; mt < 4; ++mt)
#pragma unroll
        for (int nt = 0; nt < 4; ++nt)
            acc[mt][nt] = __builtin_amdgcn_mfma_f32_16x16x32_bf16(kf[mt], qf[nt], acc[mt][nt], 0, 0, 0);

    // ---- softmax over m (in-lane mt,j + shfl over lg)
#pragma unroll
    for (int nt = 0; nt < 4; ++nt) {
        float mx = -1e30f;
#pragma unroll
        for (int mt = 0; mt < 4; ++mt)
#pragma unroll
            for (int j = 0; j < 4; ++j) mx = fmaxf(mx, acc[mt][nt][j]);
        mx = fmaxf(mx, __shfl_xor(mx, 16));
        mx = fmaxf(mx, __shfl_xor(mx, 32));
        float s = 0.f;
#pragma unroll
        for (int mt = 0; mt < 4; ++mt)
#pragma unroll
            for (int j = 0; j < 4; ++j) {
                const float e = expf(acc[mt][nt][j] - mx);
                acc[mt][nt][j] = e;
                s += e;
            }
        s += __shfl_xor(s, 16);
        s += __shfl_xor(s, 32);
        const float inv = 1.f / s;
#pragma unroll
        for (int mt = 0; mt < 4; ++mt)
#pragma unroll
            for (int j = 0; j < 4; ++j) acc[mt][nt][j] *= inv;
    }

    // ---- pack P[n][m] bf16 into LDS (row 128B, XOR ((n&7)<<4))
    const int n7 = (lr & 7) << 4;
    char* Pw = P[rb];
#pragma unroll
    for (int nt = 0; nt < 4; ++nt) {
        const int rowb = (nt * 16 + lr) * 128;
#pragma unroll
        for (int mt = 0; mt < 4; ++mt)
#pragma unroll
            for (int jp = 0; jp < 2; ++jp) {
                const unsigned lo = (unsigned short)f2bf(acc[mt][nt][jp * 2]);
                const unsigned hi = (unsigned short)f2bf(acc[mt][nt][jp * 2 + 1]);
                const int mb = (mt * 16 + lg * 4 + jp * 2) * 2;
                *reinterpret_cast<unsigned*>(&Pw[rowb + (mb ^ n7)]) = lo | (hi << 16);
            }
    }
    __syncthreads();

    // ---- V^T frags (A): row hd, k = m (gather u16)
    const unsigned short* vp = &vbuf[(size_t)bid * 2048];
    bf8_t vf[2][2];
#pragma unroll
    for (int ht = 0; ht < 2; ++ht)
#pragma unroll
        for (int ks = 0; ks < 2; ++ks) {
            bf8_t tv;
#pragma unroll
            for (int j = 0; j < 8; ++j)
                tv[j] = (short)vp[(ks * 32 + lg * 8 + j) * 32 + ht * 16 + lr];
            vf[ht][ks] = tv;
        }

    // ---- O^T = V^T @ P^T
    f4_t o[2][4] = {};
#pragma unroll
    for (int ks = 0; ks < 2; ++ks)
#pragma unroll
        for (int nt = 0; nt < 4; ++nt) {
            const int rowb = (nt * 16 + lr) * 128;
            bf8_t pf = *reinterpret_cast<const bf8_t*>(&Pw[rowb + ((ks * 64 + lg * 16) ^ n7)]);
#pragma unroll
            for (int ht = 0; ht < 2; ++ht)
                o[ht][nt] = __builtin_amdgcn_mfma_f32_16x16x32_bf16(vf[ht][ks], pf, o[ht][nt], 0, 0, 0);
        }

    // ---- store O^T as bf16: pre[(b*64+n)*256 + h*32 + hd]
#pragma unroll
    for (int ht = 0; ht < 2; ++ht)
#pragma unroll
        for (int nt = 0; nt < 4; ++nt) {
            ushort4 pk;
            pk.x = (unsigned short)f2bf(o[ht][nt][0]);
            pk.y = (unsigned short)f2bf(o[ht][nt][1]);
            pk.z = (unsigned short)f2bf(o[ht][nt][2]);
            pk.w = (unsigned short)f2bf(o[ht][nt][3]);
            const int n = nt * 16 + lr;
            const int hd = ht * 16 + lg * 4;
            *reinterpret_cast<ushort4*>(&pre[(size_t)(b * 64 + n) * 256 + h * 32 + hd]) = pk;
        }
}

extern "C" void kernel_launch(void* const* d_in, const int* in_sizes, int n_in,
                              void* d_out, int out_size, void* d_ws, size_t ws_size,
                              hipStream_t stream) {
    const float* x          = (const float*)d_in[0];
    const float* mask       = (const float*)d_in[1];
    const float* x_ref      = (const float*)d_in[2];
    const float* qkv_w      = (const float*)d_in[3];
    const float* qkv_b      = (const float*)d_in[4];
    const float* proj_w     = (const float*)d_in[5];
    const float* proj_b     = (const float*)d_in[6];
    const float* bias_table = (const float*)d_in[7];
    const float* diff_mu    = (const float*)d_in[8];
    const float* diff_ls    = (const float*)d_in[9];
    const float* ref_qk_w   = (const float*)d_in[10];
    const float* ref_qk_b   = (const float*)d_in[11];
    const float* conv_w     = (const float*)d_in[12];
    const float* conv_b     = (const float*)d_in[13];
    const int*   rel_index  = (const int*)d_in[14];
    float* out = (float*)d_out;

    unsigned short* xb   = (unsigned short*)d_ws;                // 9437184 u16
    unsigned short* qb16 = xb + 9437184;                         // 9437184 u16
    unsigned short* kb16 = qb16 + 9437184;                       // 9437184 u16
    unsigned short* vb16 = kb16 + 9437184;                       // 9437184 u16
    float* scA           = (float*)(vb16 + 9437184);             // 8847360 f
    unsigned short* updA = (unsigned short*)(scA + 8847360);     // 8847360 u16
    unsigned short* updB = updA + 8847360;                       // 8847360 u16
    float* rq            = (float*)(updB + 8847360);             // 30720 f
    float* rv            = rq + 30720;                           // 30720 f
    float* st            = rv + 30720;                           // 192 f (3 x 64)
    float* bmt           = st + 192;                             // 4718592 f
    unsigned short* wqb  = (unsigned short*)(bmt + 4718592);     // 196608 u16
    unsigned short* wpb  = wqb + 196608;                         // 65536 u16
    float* scB           = (float*)d_ws;                         // reuses xb+qb16 (dead during conv)
    unsigned short* pre  = (unsigned short*)scA;                 // alias: scA dead after k_qnewf

    k_prep<<<3332, 256, 0, stream>>>(x, xb, qkv_w, wqb, proj_w, wpb,
                                     mask, bias_table, rel_index, bmt,
                                     x_ref, ref_qk_w, ref_qk_b, diff_mu, diff_ls,
                                     rq, rv);
    k_qkv_mfma<<<1728, 256, 0, stream>>>(xb, wqb, qkv_b, qb16, kb16, vb16);
    k_scores<<<RB * NHD * 36, 256, 0, stream>>>(qb16, rq, scA);
    hipMemsetAsync(st, 0, 192 * sizeof(float), stream);
    k_conv_mfma<0><<<RB * 288, 256, 0, stream>>>(scA, updA, st, conv_w, conv_b, scB, updA, st);
    k_conv_mfma<1><<<RB * 288, 256, 0, stream>>>(scA, updA, st, conv_w, conv_b, scB, updB, st + 64);
    k_conv_mfma<1><<<RB * 288, 256, 0, stream>>>(scB, updB, st + 64, conv_w, conv_b, scA, updA, st + 128);
    k_qnewf<<<RB * NHD * 36, 256, 0, stream>>>(scA, updA, st + 128, rv, qb16);
    k_wattn_mfma<<<NWIN * NHD, 256, 0, stream>>>(qb16, kb16, vb16, bmt, pre);
    k_proj_mfma<<<576, 256, 0, stream>>>(pre, wpb, proj_b, out);
}

// Round 22
// 259.732 us; speedup vs baseline: 1.1659x; 1.0600x over previous
//
#include <hip/hip_runtime.h>
#include <math.h>

#define NHD 8
#define HD 32
#define NREF 30
#define RB 4
#define NWIN 144
#define NTOK 64
#define IMG_H (NWIN*NTOK)        /* 9216  */
#define LN_CNT (IMG_H*NREF)      /* 276480 */
#define SCALE 0.1767766952966369f
#define LN_EPS 1e-5f

typedef __attribute__((ext_vector_type(8))) short bf8_t;   // 8 x bf16
typedef __attribute__((ext_vector_type(4))) float f4_t;    // MFMA acc

__device__ __forceinline__ float gelu_f(float v) {
    return 0.5f * v * (1.0f + erff(v * 0.7071067811865476f));
}

__device__ __forceinline__ short f2bf(float f) {           // fp32 -> bf16 RNE
    union { float f; unsigned u; } v; v.f = f;
    unsigned r = v.u + 0x7fffu + ((v.u >> 16) & 1u);
    return (short)(r >> 16);
}

__device__ __forceinline__ float bf2f(unsigned short u) {
    union { unsigned u; float f; } v; v.u = ((unsigned)u) << 16;
    return v.f;
}

// ---- fused prep: cvt(x) | bm | cvt(qkv_w) | cvt(proj_w) | refprep ----
// bm branch: one block per window (144 blocks) serving all 8 heads. mask[w]
// staged coalesced into LDS [64][65] (padded -> transposed read is 2-way
// bank-aliased = free), bias_table staged in LDS -> the previous 9.4M
// scattered 4B global gathers become LDS ops; rel gather volume drops 8x.
__global__ __launch_bounds__(256) void k_prep(
    const float* __restrict__ x, unsigned short* __restrict__ xb,
    const float* __restrict__ qkv_w, unsigned short* __restrict__ wqb,
    const float* __restrict__ proj_w, unsigned short* __restrict__ wpb,
    const float* __restrict__ mask, const float* __restrict__ bias_table,
    const int* __restrict__ rel_index, float* __restrict__ bmt,
    const float* __restrict__ x_ref, const float* __restrict__ rw,
    const float* __restrict__ rbias, const float* __restrict__ dmu,
    const float* __restrict__ dls, float* __restrict__ ref_q,
    float* __restrict__ ref_v) {
    __shared__ float shbuf[4160 + 1800];   // bm: lm[64][65] + lb[1800]; refprep: 1864
    const int bid = blockIdx.x;
    const int t = threadIdx.x;
    if (bid < 2048) {                      // ---- cvt x (36MB -> 18MB)
        const int n8 = 9437184 / 8;
        for (int i = bid * 256 + t; i < n8; i += 2048 * 256) {
            const float* s = x + (size_t)i * 8;
            float4 a = *reinterpret_cast<const float4*>(s);
            float4 b = *reinterpret_cast<const float4*>(s + 4);
            bf8_t p;
            p[0] = f2bf(a.x); p[1] = f2bf(a.y); p[2] = f2bf(a.z); p[3] = f2bf(a.w);
            p[4] = f2bf(b.x); p[5] = f2bf(b.y); p[6] = f2bf(b.z); p[7] = f2bf(b.w);
            *reinterpret_cast<bf8_t*>(xb + (size_t)i * 8) = p;
        }
    } else if (bid < 2192) {               // ---- bm table (144 blocks, 1/window)
        const int w = bid - 2048;
        float* lm = shbuf;                 // [64][65] transposed-padded mask
        float* lb = shbuf + 4160;          // bias_table copy (225*8)
        for (int u = t; u < 4096; u += 256)
            lm[(u >> 6) * 65 + (u & 63)] = mask[(size_t)w * 4096 + u];
        for (int u = t; u < 1800; u += 256) lb[u] = bias_table[u];
        __syncthreads();
        for (int u = t; u < 4096; u += 256) {
            const int m = u >> 6, n = u & 63;
            const float mv = lm[n * 65 + m];
            const int ri = rel_index[n * 64 + m];
#pragma unroll
            for (int h = 0; h < 8; ++h)
                bmt[(size_t)(w * 8 + h) * 4096 + u] = mv + lb[ri * 8 + h];
        }
    } else if (bid < 2288) {               // ---- cvt qkv_w (96 blocks)
        const int b2 = bid - 2192;
        const int n8 = 196608 / 8;
        for (int i = b2 * 256 + t; i < n8; i += 96 * 256) {
            const float* s = qkv_w + (size_t)i * 8;
            float4 a = *reinterpret_cast<const float4*>(s);
            float4 b = *reinterpret_cast<const float4*>(s + 4);
            bf8_t p;
            p[0] = f2bf(a.x); p[1] = f2bf(a.y); p[2] = f2bf(a.z); p[3] = f2bf(a.w);
            p[4] = f2bf(b.x); p[5] = f2bf(b.y); p[6] = f2bf(b.z); p[7] = f2bf(b.w);
            *reinterpret_cast<bf8_t*>(wqb + (size_t)i * 8) = p;
        }
    } else if (bid < 2320) {               // ---- cvt proj_w (32 blocks)
        const int b2 = bid - 2288;
        const int n8 = 65536 / 8;
        for (int i = b2 * 256 + t; i < n8; i += 32 * 256) {
            const float* s = proj_w + (size_t)i * 8;
            float4 a = *reinterpret_cast<const float4*>(s);
            float4 b = *reinterpret_cast<const float4*>(s + 4);
            bf8_t p;
            p[0] = f2bf(a.x); p[1] = f2bf(a.y); p[2] = f2bf(a.z); p[3] = f2bf(a.w);
            p[4] = f2bf(b.x); p[5] = f2bf(b.y); p[6] = f2bf(b.z); p[7] = f2bf(b.w);
            *reinterpret_cast<bf8_t*>(wpb + (size_t)i * 8) = p;
        }
    } else {                               // ---- refprep (4 blocks)
        float* Wl = shbuf;                 // [60][NREF]
        float* Bl = shbuf + 60 * NREF;     // [60]
        const int rb = bid - 2320;
        for (int i = t; i < 60 * NREF; i += 256) Wl[i] = rw[i];
        if (t < 60) Bl[t] = rbias[t];
        __syncthreads();
        const int d = t;                   // 0..255
        float xr[NREF];
#pragma unroll
        for (int r = 0; r < NREF; ++r) xr[r] = x_ref[(rb * 256 + d) * NREF + r];
        const int h = d >> 5, hd = d & 31;
        const float mu = dmu[d], sg = expf(dls[d]);
        for (int j = 0; j < 60; ++j) {
            float acc = Bl[j];
#pragma unroll
            for (int r = 0; r < NREF; ++r) acc += xr[r] * Wl[j * NREF + r];
            if (j < NREF)
                ref_q[((rb * NHD + h) * NREF + j) * HD + hd] = mu + sg * acc;
            else
                ref_v[((rb * NHD + h) * NREF + (j - NREF)) * HD + hd] = acc;
        }
    }
}

// ------- qkv GEMM via bf16 MFMA: 128x128 tile, BK=64, 4 waves x (4x4 frags) ---
// T14 register prefetch: slab ks+1's A/B panels load right after the staging
// barrier so the 8 global loads overlap the MFMA phase (+32 VGPR).
__global__ __launch_bounds__(256) void k_qkv_mfma(
    const unsigned short* __restrict__ xb, const unsigned short* __restrict__ wb,
    const float* __restrict__ bias, unsigned short* __restrict__ qb,
    unsigned short* __restrict__ kb, unsigned short* __restrict__ vb) {
    __shared__ __align__(16) char As[128 * 128];
    __shared__ __align__(16) char Bs[128 * 128];
    const int t = threadIdx.x;
    const int bid = blockIdx.x;
    const int swz = (bid & 7) * (1728 / 8) + (bid >> 3);
    const int r0 = (swz / 6) * 128;
    const int c0 = (swz % 6) * 128;
    const int wid = t >> 6, l = t & 63;
    const int wr = wid >> 1, wc = wid & 1;
    const int lr = l & 15, lg = l >> 4;
    f4_t acc[4][4] = {};
    bf8_t ra[4], rb_[4];
#pragma unroll
    for (int i = 0; i < 4; ++i) {
        const int u = t + 256 * i;
        const int row = u >> 3, c8 = u & 7;
        ra[i]  = *reinterpret_cast<const bf8_t*>(&xb[(size_t)(r0 + row) * 256 + c8 * 8]);
        rb_[i] = *reinterpret_cast<const bf8_t*>(&wb[(size_t)(c0 + row) * 256 + c8 * 8]);
    }
#pragma unroll 1
    for (int ks = 0; ks < 4; ++ks) {
#pragma unroll
        for (int i = 0; i < 4; ++i) {
            const int u = t + 256 * i;
            const int row = u >> 3, c8 = u & 7;
            *reinterpret_cast<bf8_t*>(As + row * 128 + ((c8 * 16) ^ ((row & 7) << 4))) = ra[i];
            *reinterpret_cast<bf8_t*>(Bs + row * 128 + ((c8 * 16) ^ ((row & 7) << 4))) = rb_[i];
        }
        __syncthreads();
        if (ks < 3) {
            const int k0n = (ks + 1) * 64;
#pragma unroll
            for (int i = 0; i < 4; ++i) {
                const int u = t + 256 * i;
                const int row = u >> 3, c8 = u & 7;
                ra[i]  = *reinterpret_cast<const bf8_t*>(&xb[(size_t)(r0 + row) * 256 + k0n + c8 * 8]);
                rb_[i] = *reinterpret_cast<const bf8_t*>(&wb[(size_t)(c0 + row) * 256 + k0n + c8 * 8]);
            }
        }
#pragma unroll
        for (int kk = 0; kk < 2; ++kk) {
            bf8_t a[4], b[4];
#pragma unroll
            for (int mt = 0; mt < 4; ++mt) {
                const int row = wr * 64 + mt * 16 + lr;
                a[mt] = *reinterpret_cast<const bf8_t*>(
                    As + row * 128 + ((kk * 64 + lg * 16) ^ ((row & 7) << 4)));
            }
#pragma unroll
            for (int nt = 0; nt < 4; ++nt) {
                const int row = wc * 64 + nt * 16 + lr;
                b[nt] = *reinterpret_cast<const bf8_t*>(
                    Bs + row * 128 + ((kk * 64 + lg * 16) ^ ((row & 7) << 4)));
            }
#pragma unroll
            for (int mt = 0; mt < 4; ++mt)
#pragma unroll
                for (int nt = 0; nt < 4; ++nt)
                    acc[mt][nt] = __builtin_amdgcn_mfma_f32_16x16x32_bf16(a[mt], b[nt], acc[mt][nt], 0, 0, 0);
        }
        __syncthreads();                   // reads done before next slab's writes
    }
#pragma unroll
    for (int nt = 0; nt < 4; ++nt) {
        const int gc = c0 + wc * 64 + nt * 16 + lr;
        const int i3 = gc >> 8, rem = gc & 255;
        const int h = rem >> 5, hd = rem & 31;
        const float bv = bias[gc];
        unsigned short* dst = (i3 == 0) ? qb : (i3 == 1) ? kb : vb;
#pragma unroll
        for (int mt = 0; mt < 4; ++mt)
#pragma unroll
            for (int j = 0; j < 4; ++j) {
                const int gr = r0 + wr * 64 + mt * 16 + lg * 4 + j;
                const int bb = gr >> 6, n = gr & 63;
                dst[(size_t)((bb * NHD + h) * NTOK + n) * HD + hd] =
                    (unsigned short)f2bf(acc[mt][nt][j] + bv);
            }
    }
}

// ------- proj GEMM via bf16 MFMA: 128x128 tile, BK=64, T14 prefetch -----------
__global__ __launch_bounds__(256) void k_proj_mfma(
    const unsigned short* __restrict__ A, const unsigned short* __restrict__ w,
    const float* __restrict__ bias, float* __restrict__ out) {
    __shared__ __align__(16) char As[128 * 128];
    __shared__ __align__(16) char Bs[128 * 128];
    const int t = threadIdx.x;
    const int bid = blockIdx.x;
    const int swz = (bid & 7) * (576 / 8) + (bid >> 3);
    const int r0 = (swz / 2) * 128;
    const int c0 = (swz % 2) * 128;
    const int wid = t >> 6, l = t & 63;
    const int wr = wid >> 1, wc = wid & 1;
    const int lr = l & 15, lg = l >> 4;
    f4_t acc[4][4] = {};
    bf8_t ra[4], rb_[4];
#pragma unroll
    for (int i = 0; i < 4; ++i) {
        const int u = t + 256 * i;
        const int row = u >> 3, c8 = u & 7;
        ra[i]  = *reinterpret_cast<const bf8_t*>(&A[(size_t)(r0 + row) * 256 + c8 * 8]);
        rb_[i] = *reinterpret_cast<const bf8_t*>(&w[(size_t)(c0 + row) * 256 + c8 * 8]);
    }
#pragma unroll 1
    for (int ks = 0; ks < 4; ++ks) {
#pragma unroll
        for (int i = 0; i < 4; ++i) {
            const int u = t + 256 * i;
            const int row = u >> 3, c8 = u & 7;
            *reinterpret_cast<bf8_t*>(As + row * 128 + ((c8 * 16) ^ ((row & 7) << 4))) = ra[i];
            *reinterpret_cast<bf8_t*>(Bs + row * 128 + ((c8 * 16) ^ ((row & 7) << 4))) = rb_[i];
        }
        __syncthreads();
        if (ks < 3) {
            const int k0n = (ks + 1) * 64;
#pragma unroll
            for (int i = 0; i < 4; ++i) {
                const int u = t + 256 * i;
                const int row = u >> 3, c8 = u & 7;
                ra[i]  = *reinterpret_cast<const bf8_t*>(&A[(size_t)(r0 + row) * 256 + k0n + c8 * 8]);
                rb_[i] = *reinterpret_cast<const bf8_t*>(&w[(size_t)(c0 + row) * 256 + k0n + c8 * 8]);
            }
        }
#pragma unroll
        for (int kk = 0; kk < 2; ++kk) {
            bf8_t a[4], b[4];
#pragma unroll
            for (int mt = 0; mt < 4; ++mt) {
                const int row = wr * 64 + mt * 16 + lr;
                a[mt] = *reinterpret_cast<const bf8_t*>(
                    As + row * 128 + ((kk * 64 + lg * 16) ^ ((row & 7) << 4)));
            }
#pragma unroll
            for (int nt = 0; nt < 4; ++nt) {
                const int row = wc * 64 + nt * 16 + lr;
                b[nt] = *reinterpret_cast<const bf8_t*>(
                    Bs + row * 128 + ((kk * 64 + lg * 16) ^ ((row & 7) << 4)));
            }
#pragma unroll
            for (int mt = 0; mt < 4; ++mt)
#pragma unroll
                for (int nt = 0; nt < 4; ++nt)
                    acc[mt][nt] = __builtin_amdgcn_mfma_f32_16x16x32_bf16(a[mt], b[nt], acc[mt][nt], 0, 0, 0);
        }
        __syncthreads();
    }
#pragma unroll
    for (int nt = 0; nt < 4; ++nt) {
        const int gc = c0 + wc * 64 + nt * 16 + lr;
        const float bv = bias[gc];
#pragma unroll
        for (int mt = 0; mt < 4; ++mt)
#pragma unroll
            for (int j = 0; j < 4; ++j) {
                const int gr = r0 + wr * 64 + mt * 16 + lg * 4 + j;
                out[(size_t)gr * 256 + gc] = acc[mt][nt][j] + bv;
            }
    }
}

// -------- ref scores, 4 windows/block: q(bf16) . ref_q -> scores --------------
__global__ __launch_bounds__(256) void k_scores(
    const unsigned short* __restrict__ qbuf, const float* __restrict__ ref_q,
    float* __restrict__ scores) {
    const int bid = blockIdx.x;            // ((rb*8+h)*36 + wg)
    const int wg = bid % 36;
    const int rh = bid / 36;
    const int h = rh % NHD, rb = rh / NHD;
    __shared__ __align__(16) float rs[NREF][32];
    __shared__ float outb[4][64 * NREF];
    const int t = threadIdx.x;
    const int wv = t >> 6, n = t & 63;
    const float* rsrc = &ref_q[(size_t)rh * NREF * HD];
    for (int u = t; u < NREF * 8; u += 256) {
        const int row = u >> 3, c4 = u & 7;
        *reinterpret_cast<float4*>(&rs[row][c4 * 4]) =
            *reinterpret_cast<const float4*>(&rsrc[u * 4]);
    }
    __syncthreads();
    const int w = wg * 4 + wv;
    const unsigned short* qsrc = &qbuf[(size_t)((rb * NWIN + w) * NHD + h) * NTOK * HD + n * 32];
    float q[32];
#pragma unroll
    for (int c8 = 0; c8 < 4; ++c8) {
        bf8_t v = *reinterpret_cast<const bf8_t*>(&qsrc[c8 * 8]);
#pragma unroll
        for (int j = 0; j < 8; ++j)
            q[c8 * 8 + j] = bf2f((unsigned short)v[j]);
    }
    for (int r = 0; r < NREF; ++r) {
        float acc = 0.f;
#pragma unroll
        for (int d = 0; d < 32; ++d) acc += q[d] * rs[r][d];
        outb[wv][n * NREF + r] = acc;
    }
    float* dst = &scores[(size_t)((rb * NHD + h) * IMG_H + w * 64) * NREF];
    for (int u = n; u < 64 * NREF; u += 64) dst[u] = outb[wv][u];
}

// ---------------- conv 3x3 via MFMA (implicit GEMM), 32-row chunks ------------
// Round-20 config (46.8us): 1152 blocks, At[34][32][8] bf16 17.9KB, vectorized
// staging (float2 loads, dword updPrev, float2 scOut stores). M = 16 pixels,
// N = 16 (8 co used), K = 96. A-frag = one ds_read_b128; B = 3 preloaded frags.
// FUSED: staging applies sc + gelu(LN(upd)), writes scOut for own rows.
template<int FUSED>
__global__ __launch_bounds__(256) void k_conv_mfma(
    const float* __restrict__ scPrev, const unsigned short* __restrict__ updPrev,
    const float* __restrict__ stPrev, const float* __restrict__ conv_w,
    const float* __restrict__ conv_b, float* __restrict__ scOut,
    unsigned short* __restrict__ updOut, float* __restrict__ stats) {
    const int bid = blockIdx.x;            // rb*288 + ychunk
    const int rb = bid / 288;
    const int y0 = (bid % 288) * 32;
    __shared__ __align__(16) unsigned short At[34][32][8];
    __shared__ float red[4][8][2];
    __shared__ float lmean[8], lrsig[8];
    const int t = threadIdx.x;
    if (FUSED) {
        if (t < 8) {
            const float s0 = stPrev[(rb * NHD + t) * 2];
            const float s1 = stPrev[(rb * NHD + t) * 2 + 1];
            const float m = s0 * (1.f / LN_CNT);
            const float v = s1 * (1.f / LN_CNT) - m * m;
            lmean[t] = m;
            lrsig[t] = rsqrtf(v + LN_EPS);
        }
        __syncthreads();
    }
    // zero pad columns sx = 0 and 31
    for (int f = t; f < 34 * 2; f += 256) {
        const int yy = f >> 1, side = (f & 1) ? 31 : 0;
        bf8_t z;
#pragma unroll
        for (int j = 0; j < 8; ++j) z[j] = 0;
        *reinterpret_cast<bf8_t*>(&At[yy][side][0]) = z;
    }
    // stage: item (yy, ci, x-pair) -> float2 load -> 2 u16 LDS writes
    for (int ps = t; ps < 34 * 8 * 15; ps += 256) {
        const int yy = ps / 120;
        const int rem = ps % 120;
        const int ci = rem / 15, xh = rem % 15;
        const int xc = xh * 2;
        const int y = y0 - 1 + yy;
        unsigned short v0 = 0, v1 = 0;
        if (y >= 0 && y < IMG_H) {
            const size_t idx = (size_t)((rb * NHD + ci) * IMG_H + y) * NREF + xc;
            float2 sv = *reinterpret_cast<const float2*>(&scPrev[idx]);
            float a0, a1;
            if (FUSED) {
                const unsigned u2 = *reinterpret_cast<const unsigned*>(&updPrev[idx]);
                a0 = sv.x + gelu_f((bf2f((unsigned short)(u2 & 0xffffu)) - lmean[ci]) * lrsig[ci]);
                a1 = sv.y + gelu_f((bf2f((unsigned short)(u2 >> 16)) - lmean[ci]) * lrsig[ci]);
                if (yy >= 1 && yy <= 32) {
                    float2 so; so.x = a0; so.y = a1;
                    *reinterpret_cast<float2*>(&scOut[idx]) = so;
                }
            } else {
                a0 = sv.x; a1 = sv.y;
            }
            v0 = (unsigned short)f2bf(a0);
            v1 = (unsigned short)f2bf(a1);
        }
        At[yy][xc + 1][ci] = v0;
        At[yy][xc + 2][ci] = v1;
    }
    // weight B-fragments: lane (lr=co, lg) holds k-slice [tap=kg*4+lg][ci 0..7]
    const int l = t & 63, wv = t >> 6;
    const int lr = l & 15, lg = l >> 4;
    bf8_t wf[3];
#pragma unroll
    for (int kg = 0; kg < 3; ++kg) {
        const int tap = kg * 4 + lg;
        bf8_t wq;
#pragma unroll
        for (int j = 0; j < 8; ++j) wq[j] = 0;
        if (lr < 8 && tap < 9) {
            const int dy = tap / 3, dx = tap % 3;
#pragma unroll
            for (int ci = 0; ci < 8; ++ci)
                wq[ci] = f2bf(conv_w[lr * 72 + ci * 9 + dy * 3 + dx]);
        }
        wf[kg] = wq;
    }
    const float cb = (lr < 8) ? conv_b[lr] : 0.f;
    __syncthreads();
    float ls = 0.f, lss = 0.f;
    // 60 M-tiles of 16 pixels; wave wv owns tiles [wv*15, wv*15+15)
#pragma unroll 1
    for (int ti = 0; ti < 15; ++ti) {
        const int tile = wv * 15 + ti;
        const int pA = tile * 16 + lr;     // A-side pixel for this lane
        const int ylA = pA / 30, xA = pA % 30;
        f4_t o;
        o[0] = cb; o[1] = cb; o[2] = cb; o[3] = cb;
#pragma unroll
        for (int kg = 0; kg < 3; ++kg) {
            const int tap = kg * 4 + lg;
            const int dy = (tap < 9) ? tap / 3 : 0;
            const int dx = (tap < 9) ? tap % 3 : 0;
            bf8_t a = *reinterpret_cast<const bf8_t*>(&At[ylA + dy][xA + dx][0]);
            o = __builtin_amdgcn_mfma_f32_16x16x32_bf16(a, wf[kg], o, 0, 0, 0);
        }
        if (lr < 8) {
#pragma unroll
            for (int j = 0; j < 4; ++j) {
                const int pD = tile * 16 + lg * 4 + j;
                const int yl = pD / 30, x = pD % 30;
                updOut[(size_t)((rb * NHD + lr) * IMG_H + y0 + yl) * NREF + x] =
                    (unsigned short)f2bf(o[j]);
                ls += o[j];
                lss += o[j] * o[j];
            }
        }
    }
    ls += __shfl_xor(ls, 16); ls += __shfl_xor(ls, 32);
    lss += __shfl_xor(lss, 16); lss += __shfl_xor(lss, 32);
    if (l < 8) { red[wv][l][0] = ls; red[wv][l][1] = lss; }
    __syncthreads();
    if (t < 8) {
        atomicAdd(&stats[(rb * NHD + t) * 2],
                  red[0][t][0] + red[1][t][0] + red[2][t][0] + red[3][t][0]);
        atomicAdd(&stats[(rb * NHD + t) * 2 + 1],
                  red[0][t][1] + red[1][t][1] + red[2][t][1] + red[3][t][1]);
    }
}

// --- softmax over NREF (fused final LN+gelu+residual), 4 windows/block --------
__global__ __launch_bounds__(256) void k_qnewf(
    const float* __restrict__ scores, const unsigned short* __restrict__ upd,
    const float* __restrict__ st, const float* __restrict__ ref_v,
    unsigned short* __restrict__ qbuf) {
    const int bid = blockIdx.x;            // ((rb*8+h)*36 + wg)
    const int wg = bid % 36;
    const int rh = bid / 36;
    const int h = rh % NHD, rb = rh / NHD;
    __shared__ __align__(16) float rv[NREF][32];
    __shared__ float sl[4][64 * NREF];
    const int t = threadIdx.x;
    const int wv = t >> 6, n = t & 63;
    const float s0 = st[rh * 2], s1 = st[rh * 2 + 1];
    const float mean = s0 * (1.f / LN_CNT);
    const float var = s1 * (1.f / LN_CNT) - mean * mean;
    const float rsig = rsqrtf(var + LN_EPS);
    const float* rvs = &ref_v[(size_t)rh * NREF * HD];
    for (int u = t; u < NREF * 8; u += 256) {
        const int r = u >> 3, c4 = u & 7;
        *reinterpret_cast<float4*>(&rv[r][c4 * 4]) =
            *reinterpret_cast<const float4*>(&rvs[u * 4]);
    }
    const int w = wg * 4 + wv;
    const size_t base = (size_t)((rb * NHD + h) * IMG_H + w * 64) * NREF;
    for (int u = n; u < 64 * NREF; u += 64) {
        const float uv = bf2f(upd[base + u]);
        sl[wv][u] = scores[base + u] + gelu_f((uv - mean) * rsig);
    }
    __syncthreads();
    float p[NREF];
    float mx = -1e30f;
#pragma unroll
    for (int r = 0; r < NREF; ++r) { p[r] = sl[wv][n * NREF + r]; mx = fmaxf(mx, p[r]); }
    float sum = 0.f;
#pragma unroll
    for (int r = 0; r < NREF; ++r) { p[r] = expf(p[r] - mx); sum += p[r]; }
    const float inv = SCALE / sum;
    float acc[32] = {0.f};
#pragma unroll
    for (int r = 0; r < NREF; ++r) {
        const float pr = p[r] * inv;
#pragma unroll
        for (int d = 0; d < 32; ++d) acc[d] += pr * rv[r][d];
    }
    unsigned short* dst = &qbuf[(size_t)((rb * NWIN + w) * NHD + h) * NTOK * HD + n * 32];
#pragma unroll
    for (int c8 = 0; c8 < 4; ++c8) {
        bf8_t pk;
#pragma unroll
        for (int j = 0; j < 8; ++j) pk[j] = f2bf(acc[c8 * 8 + j]);
        *reinterpret_cast<bf8_t*>(&dst[c8 * 8]) = pk;
    }
}

// ---------------- window attention via MFMA, swapped operands ----------------
__global__ __launch_bounds__(256, 4) void k_wattn_mfma(
    const unsigned short* __restrict__ qbuf, const unsigned short* __restrict__ kbuf,
    const unsigned short* __restrict__ vbuf, const float* __restrict__ bmt,
    unsigned short* __restrict__ pre) {
    const int wh = blockIdx.x;             // w*8 + h
    const int w = wh >> 3, h = wh & 7;
    const int t = threadIdx.x;
    const int rb = t >> 6;                 // wave id = rb
    const int l = t & 63;
    const int lr = l & 15, lg = l >> 4;
    const int b = rb * NWIN + w;
    const int bid = b * NHD + h;
    __shared__ __align__(16) char P[4][64 * 128];

    // ---- C init from bmt[w][h][m][n]
    f4_t acc[4][4];
    const float* bm = &bmt[(size_t)wh * 4096];
#pragma unroll
    for (int mt = 0; mt < 4; ++mt)
#pragma unroll
        for (int nt = 0; nt < 4; ++nt)
#pragma unroll
            for (int j = 0; j < 4; ++j)
                acc[mt][nt][j] = bm[(mt * 16 + lg * 4 + j) * 64 + nt * 16 + lr];

    // ---- K frags (A) and Q frags (B): both bf16, 8 contiguous
    const unsigned short* kp = &kbuf[(size_t)bid * 2048];
    const unsigned short* qp = &qbuf[(size_t)bid * 2048];
    bf8_t kf[4], qf[4];
#pragma unroll
    for (int mt = 0; mt < 4; ++mt) {
        kf[mt] = *reinterpret_cast<const bf8_t*>(&kp[(mt * 16 + lr) * 32 + lg * 8]);
        qf[mt] = *reinterpret_cast<const bf8_t*>(&qp[(mt * 16 + lr) * 32 + lg * 8]);
    }
    // ---- S^T[m][n] = sum_k k[m][kk] q[n][kk] + bm
#pragma unroll
    for (int mt = 0; mt < 4; ++mt)
#pragma unroll
        for (int nt = 0; nt < 4; ++nt)
            acc[mt][nt] = __builtin_amdgcn_mfma_f32_16x16x32_bf16(kf[mt], qf[nt], acc[mt][nt], 0, 0, 0);

    // ---- softmax over m (in-lane mt,j + shfl over lg)
#pragma unroll
    for (int nt = 0; nt < 4; ++nt) {
        float mx = -1e30f;
#pragma unroll
        for (int mt = 0; mt < 4; ++mt)
#pragma unroll
            for (int j = 0; j < 4; ++j) mx = fmaxf(mx, acc[mt][nt][j]);
        mx = fmaxf(mx, __shfl_xor(mx, 16));
        mx = fmaxf(mx, __shfl_xor(mx, 32));
        float s = 0.f;
#pragma unroll
        for (int mt = 0; mt < 4; ++mt)
#pragma unroll
            for (int j = 0; j < 4; ++j) {
                const float e = expf(acc[mt][nt][j] - mx);
                acc[mt][nt][j] = e;
                s += e;
            }
        s += __shfl_xor(s, 16);
        s += __shfl_xor(s, 32);
        const float inv = 1.f / s;
#pragma unroll
        for (int mt = 0; mt < 4; ++mt)
#pragma unroll
            for (int j = 0; j < 4; ++j) acc[mt][nt][j] *= inv;
    }

    // ---- pack P[n][m] bf16 into LDS (row 128B, XOR ((n&7)<<4))
    const int n7 = (lr & 7) << 4;
    char* Pw = P[rb];
#pragma unroll
    for (int nt = 0; nt < 4; ++nt) {
        const int rowb = (nt * 16 + lr) * 128;
#pragma unroll
        for (int mt = 0; mt < 4; ++mt)
#pragma unroll
            for (int jp = 0; jp < 2; ++jp) {
                const unsigned lo = (unsigned short)f2bf(acc[mt][nt][jp * 2]);
                const unsigned hi = (unsigned short)f2bf(acc[mt][nt][jp * 2 + 1]);
                const int mb = (mt * 16 + lg * 4 + jp * 2) * 2;
                *reinterpret_cast<unsigned*>(&Pw[rowb + (mb ^ n7)]) = lo | (hi << 16);
            }
    }
    __syncthreads();

    // ---- V^T frags (A): row hd, k = m (gather u16)
    const unsigned short* vp = &vbuf[(size_t)bid * 2048];
    bf8_t vf[2][2];
#pragma unroll
    for (int ht = 0; ht < 2; ++ht)
#pragma unroll
        for (int ks = 0; ks < 2; ++ks) {
            bf8_t tv;
#pragma unroll
            for (int j = 0; j < 8; ++j)
                tv[j] = (short)vp[(ks * 32 + lg * 8 + j) * 32 + ht * 16 + lr];
            vf[ht][ks] = tv;
        }

    // ---- O^T = V^T @ P^T
    f4_t o[2][4] = {};
#pragma unroll
    for (int ks = 0; ks < 2; ++ks)
#pragma unroll
        for (int nt = 0; nt < 4; ++nt) {
            const int rowb = (nt * 16 + lr) * 128;
            bf8_t pf = *reinterpret_cast<const bf8_t*>(&Pw[rowb + ((ks * 64 + lg * 16) ^ n7)]);
#pragma unroll
            for (int ht = 0; ht < 2; ++ht)
                o[ht][nt] = __builtin_amdgcn_mfma_f32_16x16x32_bf16(vf[ht][ks], pf, o[ht][nt], 0, 0, 0);
        }

    // ---- store O^T as bf16: pre[(b*64+n)*256 + h*32 + hd]
#pragma unroll
    for (int ht = 0; ht < 2; ++ht)
#pragma unroll
        for (int nt = 0; nt < 4; ++nt) {
            ushort4 pk;
            pk.x = (unsigned short)f2bf(o[ht][nt][0]);
            pk.y = (unsigned short)f2bf(o[ht][nt][1]);
            pk.z = (unsigned short)f2bf(o[ht][nt][2]);
            pk.w = (unsigned short)f2bf(o[ht][nt][3]);
            const int n = nt * 16 + lr;
            const int hd = ht * 16 + lg * 4;
            *reinterpret_cast<ushort4*>(&pre[(size_t)(b * 64 + n) * 256 + h * 32 + hd]) = pk;
        }
}

extern "C" void kernel_launch(void* const* d_in, const int* in_sizes, int n_in,
                              void* d_out, int out_size, void* d_ws, size_t ws_size,
                              hipStream_t stream) {
    const float* x          = (const float*)d_in[0];
    const float* mask       = (const float*)d_in[1];
    const float* x_ref      = (const float*)d_in[2];
    const float* qkv_w      = (const float*)d_in[3];
    const float* qkv_b      = (const float*)d_in[4];
    const float* proj_w     = (const float*)d_in[5];
    const float* proj_b     = (const float*)d_in[6];
    const float* bias_table = (const float*)d_in[7];
    const float* diff_mu    = (const float*)d_in[8];
    const float* diff_ls    = (const float*)d_in[9];
    const float* ref_qk_w   = (const float*)d_in[10];
    const float* ref_qk_b   = (const float*)d_in[11];
    const float* conv_w     = (const float*)d_in[12];
    const float* conv_b     = (const float*)d_in[13];
    const int*   rel_index  = (const int*)d_in[14];
    float* out = (float*)d_out;

    unsigned short* xb   = (unsigned short*)d_ws;                // 9437184 u16
    unsigned short* qb16 = xb + 9437184;                         // 9437184 u16
    unsigned short* kb16 = qb16 + 9437184;                       // 9437184 u16
    unsigned short* vb16 = kb16 + 9437184;                       // 9437184 u16
    float* scA           = (float*)(vb16 + 9437184);             // 8847360 f
    unsigned short* updA = (unsigned short*)(scA + 8847360);     // 8847360 u16
    unsigned short* updB = updA + 8847360;                       // 8847360 u16
    float* rq            = (float*)(updB + 8847360);             // 30720 f
    float* rv            = rq + 30720;                           // 30720 f
    float* st            = rv + 30720;                           // 192 f (3 x 64)
    float* bmt           = st + 192;                             // 4718592 f
    unsigned short* wqb  = (unsigned short*)(bmt + 4718592);     // 196608 u16
    unsigned short* wpb  = wqb + 196608;                         // 65536 u16
    float* scB           = (float*)d_ws;                         // reuses xb+qb16 (dead during conv)
    unsigned short* pre  = (unsigned short*)scA;                 // alias: scA dead after k_qnewf

    k_prep<<<2324, 256, 0, stream>>>(x, xb, qkv_w, wqb, proj_w, wpb,
                                     mask, bias_table, rel_index, bmt,
                                     x_ref, ref_qk_w, ref_qk_b, diff_mu, diff_ls,
                                     rq, rv);
    k_qkv_mfma<<<1728, 256, 0, stream>>>(xb, wqb, qkv_b, qb16, kb16, vb16);
    k_scores<<<RB * NHD * 36, 256, 0, stream>>>(qb16, rq, scA);
    hipMemsetAsync(st, 0, 192 * sizeof(float), stream);
    k_conv_mfma<0><<<RB * 288, 256, 0, stream>>>(scA, updA, st, conv_w, conv_b, scB, updA, st);
    k_conv_mfma<1><<<RB * 288, 256, 0, stream>>>(scA, updA, st, conv_w, conv_b, scB, updB, st + 64);
    k_conv_mfma<1><<<RB * 288, 256, 0, stream>>>(scB, updB, st + 64, conv_w, conv_b, scA, updA, st + 128);
    k_qnewf<<<RB * NHD * 36, 256, 0, stream>>>(scA, updA, st + 128, rv, qb16);
    k_wattn_mfma<<<NWIN * NHD, 256, 0, stream>>>(qb16, kb16, vb16, bmt, pre);
    k_proj_mfma<<<576, 256, 0, stream>>>(pre, wpb, proj_b, out);
}